// Round 5
// baseline (46823.611 us; speedup 1.0000x reference)
//
#include <hip/hip_runtime.h>
#include <math.h>

#define T_ 256
#define H_ 512
#define NWG 256

typedef short bf16x8 __attribute__((ext_vector_type(8)));
typedef float f32x4 __attribute__((ext_vector_type(4)));
typedef unsigned short ushort_t;

// ---------- ws byte offsets ----------
// h planes are k-chunk-tiled: [16 chunks][128 b][32 k] bf16 = 131072 B per plane.
#define O_H0HI 0u          // 2 parity bufs
#define O_H0LO 262144u
#define O_H1HI 524288u
#define O_H1LO 786432u
#define O_C0   1048576u    // 128x512 f32 [b][u]
#define O_C1   1310720u
#define O_XIN0 1572864u    // [u*4+g][128 b] f32 = 1 MB
#define O_PK   2621440u    // 5 packs x 2048 f32 (bias, [u*4+g])
#define O_FLAG 2662400u    // 256 flags x 64B

// ---------- LDS byte offsets (128 KB dynamic, weights only) ----------
#define E0HI 0u            // 16 rows x 576 bf16 (x|h0)
#define E0LO 18432u
#define E1HI 36864u        // 16 rows x 1024 bf16 (h0|h1)
#define E1LO 69632u
#define D0HI 0u            // 16 rows x 1024 (Weff|dWhh0)
#define D0LO 32768u
#define D1HI 65536u        // 16 rows x 1024 (dWih1|dWhh1)
#define D1LO 98304u

__device__ __forceinline__ float sigf(float x) { return 1.0f / (1.0f + expf(-x)); }

__device__ __forceinline__ unsigned short f2bf(float f) {   // RNE
    union { float f; unsigned u; } v; v.f = f;
    unsigned r = v.u + 0x7FFFu + ((v.u >> 16) & 1u);
    return (unsigned short)(r >> 16);
}
__device__ __forceinline__ float bf2f(unsigned short h) {
    union { unsigned u; float f; } v; v.u = ((unsigned)h) << 16;
    return v.f;
}

// flag-array grid barrier: WG w sets flags[w*16]=gen; thread t polls flags[t*16].
__device__ __forceinline__ void gbar(int* flags, int w, int gen) {
    __syncthreads();
    __threadfence();   // release
    if (threadIdx.x == 0)
        __hip_atomic_store(flags + w * 16, gen, __ATOMIC_RELAXED, __HIP_MEMORY_SCOPE_AGENT);
    while (__hip_atomic_load(flags + threadIdx.x * 16, __ATOMIC_RELAXED, __HIP_MEMORY_SCOPE_AGENT) < gen)
        __builtin_amdgcn_s_sleep(1);
    __threadfence();   // acquire
    __syncthreads();
}

// store one weight element as hi/lo bf16 into swizzled LDS planes
__device__ __forceinline__ void st_w(char* smem, unsigned hiB, unsigned loB, unsigned K2,
                                     unsigned m, unsigned k, float v) {
    unsigned short hh = f2bf(v);
    unsigned short ll = f2bf(v - bf2f(hh));
    unsigned off = (m * K2 + k * 2) ^ ((m & 7) << 4);
    *(unsigned short*)(smem + hiB + off) = hh;
    *(unsigned short*)(smem + loB + off) = ll;
}

// One K-segment from a tiled activation plane. Chunk i = k-range [wk0+i*32, +32).
// B load: contiguous 1KB per chunk per wave (perfectly coalesced).
template <int NCH>
__device__ __forceinline__ void seg_tiled(
    const char* smem, unsigned whiB, unsigned wloB, unsigned K2, unsigned wk0,
    const ushort_t* __restrict__ bh, const ushort_t* __restrict__ bl,
    unsigned bt, int lane, f32x4& acc0, f32x4& acc1) {
    const unsigned m = lane & 15, q = lane >> 4;
    const unsigned swz = (m & 7) << 4;
    const unsigned wbyte0 = m * K2 + (wk0 + q * 8) * 2;
    const ushort_t* pbh = bh + (size_t)(bt + m) * 32 + q * 8;
    const ushort_t* pbl = bl + (size_t)(bt + m) * 32 + q * 8;
    #pragma unroll 4
    for (int i = 0; i < NCH; ++i) {
        bf16x8 bhi = *(const bf16x8*)(pbh + (size_t)i * 4096);
        bf16x8 blo = *(const bf16x8*)(pbl + (size_t)i * 4096);
        bf16x8 ahi = *(const bf16x8*)(smem + whiB + ((wbyte0 + i * 64) ^ swz));
        bf16x8 alo = *(const bf16x8*)(smem + wloB + ((wbyte0 + i * 64) ^ swz));
        acc0 = __builtin_amdgcn_mfma_f32_16x16x32_bf16(ahi, bhi, acc0, 0, 0, 0);
        acc1 = __builtin_amdgcn_mfma_f32_16x16x32_bf16(ahi, blo, acc1, 0, 0, 0);
        acc1 = __builtin_amdgcn_mfma_f32_16x16x32_bf16(alo, bhi, acc1, 0, 0, 0);
    }
}

// encoder cell-A x-segment (K=64): B built on the fly from fp32 x rows (coalesced 128B/row)
__device__ __forceinline__ void seg_x(
    const char* smem, unsigned whiB, unsigned wloB, unsigned K2,
    const float* __restrict__ x, int t, unsigned bt, int lane,
    f32x4& acc0, f32x4& acc1) {
    const unsigned m = lane & 15, q = lane >> 4;
    const unsigned swz = (m & 7) << 4;
    const float* xp = x + ((size_t)(bt + m) * T_ + t) * 64 + q * 8;
    #pragma unroll
    for (int i = 0; i < 2; ++i) {
        float4 f0 = *(const float4*)(xp + i * 32);
        float4 f1 = *(const float4*)(xp + i * 32 + 4);
        float fs[8] = { f0.x, f0.y, f0.z, f0.w, f1.x, f1.y, f1.z, f1.w };
        bf16x8 bhi, blo;
        #pragma unroll
        for (int j = 0; j < 8; ++j) {
            unsigned short hh = f2bf(fs[j]);
            bhi[j] = (short)hh;
            blo[j] = (short)f2bf(fs[j] - bf2f(hh));
        }
        unsigned wb = (m * K2 + (q * 8 + i * 32) * 2) ^ swz;
        bf16x8 ahi = *(const bf16x8*)(smem + whiB + wb);
        bf16x8 alo = *(const bf16x8*)(smem + wloB + wb);
        acc0 = __builtin_amdgcn_mfma_f32_16x16x32_bf16(ahi, bhi, acc0, 0, 0, 0);
        acc1 = __builtin_amdgcn_mfma_f32_16x16x32_bf16(ahi, blo, acc1, 0, 0, 0);
        acc1 = __builtin_amdgcn_mfma_f32_16x16x32_bf16(alo, bhi, acc1, 0, 0, 0);
    }
}

// LSTM epilogue: lane owns 4 gate preacts of one (u,b); h written tiled, c stays [b][u]
__device__ __forceinline__ void epilogue(f32x4 acc, const float* pkb, int u, int b,
                                         float* cArr, ushort_t* hhi, ushort_t* hlo) {
    const float4 bz = *(const float4*)(pkb + (size_t)u * 4);
    float gi = sigf(acc[0] + bz.x);
    float gf = sigf(acc[1] + bz.y);
    float gt = tanhf(acc[2] + bz.z);
    float go = sigf(acc[3] + bz.w);
    const unsigned ci = (unsigned)b * H_ + u;
    float cn = gf * cArr[ci] + gi * gt;
    cArr[ci] = cn;
    float hv = go * tanhf(cn);
    unsigned short hh = f2bf(hv);
    const unsigned hidx = (unsigned)(u >> 5) * 4096 + (unsigned)b * 32 + (u & 31);
    hhi[hidx] = hh;
    hlo[hidx] = f2bf(hv - bf2f(hh));
}

// out(t) = h1 @ linW.T + linb ; h1 read from tiled hi/lo planes
__device__ __forceinline__ void linear_out(const ushort_t* __restrict__ h1h,
                                           const ushort_t* __restrict__ h1l,
                                           const float* __restrict__ linW,
                                           const float* __restrict__ linb,
                                           float* __restrict__ out, int w, int tid, int t) {
    const int bl = w >> 1;
    const int kq = tid & 7;
    const int f = (w & 1) * 32 + (tid >> 3);
    float s = 0.f;
    #pragma unroll
    for (int c2 = 0; c2 < 2; ++c2) {
        const unsigned base = (unsigned)(kq * 2 + c2) * 4096 + (unsigned)bl * 32;
        const float* wp = linW + (size_t)f * H_ + kq * 64 + c2 * 32;
        #pragma unroll
        for (int i4 = 0; i4 < 8; ++i4) {
            ushort4 hh = *(const ushort4*)(h1h + base + i4 * 4);
            ushort4 ll = *(const ushort4*)(h1l + base + i4 * 4);
            float4 wf = *(const float4*)(wp + i4 * 4);
            s += (bf2f(hh.x) + bf2f(ll.x)) * wf.x;
            s += (bf2f(hh.y) + bf2f(ll.y)) * wf.y;
            s += (bf2f(hh.z) + bf2f(ll.z)) * wf.z;
            s += (bf2f(hh.w) + bf2f(ll.w)) * wf.w;
        }
    }
    s += __shfl_xor(s, 1);
    s += __shfl_xor(s, 2);
    s += __shfl_xor(s, 4);
    if (kq == 0)
        out[((size_t)bl * T_ + (255 - t)) * 64 + f] = s + linb[f];
}

__global__ __launch_bounds__(256, 1) void lstm_persist(
    const float* __restrict__ x,
    const float* __restrict__ eWih0, const float* __restrict__ eWhh0,
    const float* __restrict__ ebih0, const float* __restrict__ ebhh0,
    const float* __restrict__ eWih1, const float* __restrict__ eWhh1,
    const float* __restrict__ ebih1, const float* __restrict__ ebhh1,
    const float* __restrict__ dWih0, const float* __restrict__ dWhh0,
    const float* __restrict__ dbih0, const float* __restrict__ dbhh0,
    const float* __restrict__ dWih1, const float* __restrict__ dWhh1,
    const float* __restrict__ dbih1, const float* __restrict__ dbhh1,
    const float* __restrict__ linW,  const float* __restrict__ linb,
    float* __restrict__ out, char* __restrict__ wsb, int* __restrict__ flags) {
    extern __shared__ char smem[];
    const int w = blockIdx.x, tid = threadIdx.x;
    const int lane = tid & 63, wave = tid >> 6;
    const int gid = w * 256 + tid;

    const int u_base = (w >> 1) * 4;
    const unsigned bt = (unsigned)(((w & 1) * 4 + wave) * 16);
    const int u = u_base + (lane >> 4);
    const int b = (int)bt + (lane & 15);

    ushort_t* h0hi[2] = { (ushort_t*)(wsb + O_H0HI), (ushort_t*)(wsb + O_H0HI + 131072u) };
    ushort_t* h0lo[2] = { (ushort_t*)(wsb + O_H0LO), (ushort_t*)(wsb + O_H0LO + 131072u) };
    ushort_t* h1hi[2] = { (ushort_t*)(wsb + O_H1HI), (ushort_t*)(wsb + O_H1HI + 131072u) };
    ushort_t* h1lo[2] = { (ushort_t*)(wsb + O_H1LO), (ushort_t*)(wsb + O_H1LO + 131072u) };
    float* c0 = (float*)(wsb + O_C0);
    float* c1 = (float*)(wsb + O_C1);
    float* xin0p = (float*)(wsb + O_XIN0);
    float* pk = (float*)(wsb + O_PK);
    int gen = 0;

    // ================= INIT =================
    h0hi[1][gid] = 0; h0lo[1][gid] = 0; h1hi[1][gid] = 0; h1lo[1][gid] = 0;
    c0[gid] = 0.f; c1[gid] = 0.f;

    if (gid < 10240) {   // bias packs [u*4+g], 5 packs: e0,e1,d0,d0+beff,d1
        int p = gid >> 11, r = gid & 2047;
        int uu = r >> 2, g = r & 3, gr = g * H_ + uu;
        float v;
        if (p == 0)      v = ebih0[gr] + ebhh0[gr];
        else if (p == 1) v = ebih1[gr] + ebhh1[gr];
        else if (p == 2) v = dbih0[gr] + dbhh0[gr];
        else if (p == 3) {
            v = dbih0[gr] + dbhh0[gr];
            float s = 0.f;
            for (int f = 0; f < 64; ++f) s += dWih0[(size_t)gr * 64 + f] * linb[f];
            v += s;
        } else           v = dbih1[gr] + dbhh1[gr];
        pk[gid] = v;
    }
    // xin0p[(u*4+g)*128+b] = dot(dWih0[g*512+u], x[b][255])
    for (int e = gid; e < 262144; e += 65536) {
        int r = e >> 7, bb = e & 127;
        int uu = r >> 2, g = r & 3, gr = g * H_ + uu;
        const float* xr = x + ((size_t)bb * T_ + (T_ - 1)) * 64;
        const float* wr = dWih0 + (size_t)gr * 64;
        float s = 0.f;
        for (int f = 0; f < 64; ++f) s += wr[f] * xr[f];
        xin0p[e] = s;
    }
    // encoder weights -> swizzled LDS hi/lo
    for (int m = 0; m < 16; ++m) {
        const int gr = (m & 3) * H_ + u_base + (m >> 2);
        for (int k = tid; k < 576; k += 256) {
            float v = (k < 64) ? eWih0[(size_t)gr * 64 + k] : eWhh0[(size_t)gr * H_ + (k - 64)];
            st_w(smem, E0HI, E0LO, 1152, m, k, v);
        }
        for (int k = tid; k < 1024; k += 256) {
            float v = (k < 512) ? eWih1[(size_t)gr * H_ + k] : eWhh1[(size_t)gr * H_ + (k - 512)];
            st_w(smem, E1HI, E1LO, 2048, m, k, v);
        }
    }
    gbar(flags, w, ++gen);

    // ================= ENCODER =================
    for (int t = 0; t < T_; ++t) {
        const unsigned cp = t & 1, pp = (t + 1) & 1;
        {   // cell A: [x_t | h0_{t-1}]
            f32x4 acc0 = { 0, 0, 0, 0 }, acc1 = { 0, 0, 0, 0 };
            seg_x(smem, E0HI, E0LO, 1152, x, t, bt, lane, acc0, acc1);
            seg_tiled<16>(smem, E0HI, E0LO, 1152, 64, h0hi[pp], h0lo[pp], bt, lane, acc0, acc1);
            epilogue(acc0 + acc1, pk, u, b, c0, h0hi[cp], h0lo[cp]);
        }
        gbar(flags, w, ++gen);
        {   // cell B: [h0_t | h1_{t-1}]
            f32x4 acc0 = { 0, 0, 0, 0 }, acc1 = { 0, 0, 0, 0 };
            seg_tiled<16>(smem, E1HI, E1LO, 2048, 0,   h0hi[cp], h0lo[cp], bt, lane, acc0, acc1);
            seg_tiled<16>(smem, E1HI, E1LO, 2048, 512, h1hi[pp], h1lo[pp], bt, lane, acc0, acc1);
            epilogue(acc0 + acc1, pk + 2048, u, b, c1, h1hi[cp], h1lo[cp]);
        }
        gbar(flags, w, ++gen);
    }

    // ================= TRANSITION: decoder weights -> LDS (WG-private) =================
    __syncthreads();
    for (int m = 0; m < 16; ++m) {
        const int gr = (m & 3) * H_ + u_base + (m >> 2);
        const float* wr = dWih0 + (size_t)gr * 64;
        for (int k = tid; k < 1024; k += 256) {
            float v;
            if (k < 512) {   // Weff = dWih0 @ linW
                float s = 0.f;
                for (int f = 0; f < 64; ++f) s += wr[f] * linW[(size_t)f * H_ + k];
                v = s;
            } else v = dWhh0[(size_t)gr * H_ + (k - 512)];
            st_w(smem, D0HI, D0LO, 2048, m, k, v);
            float v1 = (k < 512) ? dWih1[(size_t)gr * H_ + k] : dWhh1[(size_t)gr * H_ + (k - 512)];
            st_w(smem, D1HI, D1LO, 2048, m, k, v1);
        }
    }
    __syncthreads();

    // ================= DECODER =================
    for (int t = 0; t < T_; ++t) {
        const unsigned cp = t & 1, pp = (t + 1) & 1;
        {   // dec0: Weff.h1_{t-1} (or xin0 at t=0) + dWhh0.h0_{t-1}; fold linear(t-1)
            f32x4 acc0 = { 0, 0, 0, 0 }, acc1 = { 0, 0, 0, 0 };
            if (t > 0) {
                seg_tiled<16>(smem, D0HI, D0LO, 2048, 0, h1hi[pp], h1lo[pp], bt, lane, acc0, acc1);
            } else {
                #pragma unroll
                for (int j = 0; j < 4; ++j) acc0[j] = xin0p[(size_t)(u * 4 + j) * 128 + b];
            }
            seg_tiled<16>(smem, D0HI, D0LO, 2048, 512, h0hi[pp], h0lo[pp], bt, lane, acc0, acc1);
            epilogue(acc0 + acc1, pk + (t > 0 ? 6144 : 4096), u, b, c0, h0hi[cp], h0lo[cp]);
            if (t > 0) linear_out(h1hi[pp], h1lo[pp], linW, linb, out, w, tid, t - 1);
        }
        gbar(flags, w, ++gen);
        {   // dec1: dWih1.h0_t + dWhh1.h1_{t-1}
            f32x4 acc0 = { 0, 0, 0, 0 }, acc1 = { 0, 0, 0, 0 };
            seg_tiled<16>(smem, D1HI, D1LO, 2048, 0,   h0hi[cp], h0lo[cp], bt, lane, acc0, acc1);
            seg_tiled<16>(smem, D1HI, D1LO, 2048, 512, h1hi[pp], h1lo[pp], bt, lane, acc0, acc1);
            epilogue(acc0 + acc1, pk + 8192, u, b, c1, h1hi[cp], h1lo[cp]);
        }
        gbar(flags, w, ++gen);
    }
    // final output (t=255): h1_255 lives in parity buf 1
    linear_out(h1hi[1], h1lo[1], linW, linb, out, w, tid, 255);
}

extern "C" void kernel_launch(void* const* d_in, const int* in_sizes, int n_in,
                              void* d_out, int out_size, void* d_ws, size_t ws_size,
                              hipStream_t stream) {
    (void)in_sizes; (void)n_in; (void)out_size; (void)ws_size;
    const float* x     = (const float*)d_in[0];
    const float* eWih0 = (const float*)d_in[1];
    const float* eWhh0 = (const float*)d_in[2];
    const float* ebih0 = (const float*)d_in[3];
    const float* ebhh0 = (const float*)d_in[4];
    const float* eWih1 = (const float*)d_in[5];
    const float* eWhh1 = (const float*)d_in[6];
    const float* ebih1 = (const float*)d_in[7];
    const float* ebhh1 = (const float*)d_in[8];
    const float* dWih0 = (const float*)d_in[9];
    const float* dWhh0 = (const float*)d_in[10];
    const float* dbih0 = (const float*)d_in[11];
    const float* dbhh0 = (const float*)d_in[12];
    const float* dWih1 = (const float*)d_in[13];
    const float* dWhh1 = (const float*)d_in[14];
    const float* dbih1 = (const float*)d_in[15];
    const float* dbhh1 = (const float*)d_in[16];
    const float* linW  = (const float*)d_in[17];
    const float* linb  = (const float*)d_in[18];

    char* wsb  = (char*)d_ws;
    int* flags = (int*)(wsb + O_FLAG);

    static const int lds_bytes = 131072;
    hipFuncSetAttribute((const void*)lstm_persist,
                        hipFuncAttributeMaxDynamicSharedMemorySize, lds_bytes);

    hipMemsetAsync(flags, 0, 16384, stream);

    hipLaunchKernelGGL(lstm_persist, dim3(NWG), dim3(256), lds_bytes, stream,
                       x, eWih0, eWhh0, ebih0, ebhh0, eWih1, eWhh1, ebih1, ebhh1,
                       dWih0, dWhh0, dbih0, dbhh0, dWih1, dWhh1, dbih1, dbhh1,
                       linW, linb, (float*)d_out, wsb, flags);
}

// Round 6
// 29632.422 us; speedup vs baseline: 1.5801x; 1.5801x over previous
//
#include <hip/hip_runtime.h>
#include <math.h>

#define T_ 256
#define H_ 512
#define NWG 128
#define NTHR 512

typedef short bf16x8 __attribute__((ext_vector_type(8)));
typedef float f32x4 __attribute__((ext_vector_type(4)));
typedef unsigned short u16;
typedef unsigned int u32;
typedef unsigned long long u64;

// ---- ws byte offsets: h planes hold hi|lo<<16 packed u32, tiled [kchunk16][b128][k32] ----
#define O_H0   0u          // 2 parities x 262144 B
#define O_H1   524288u
#define O_FLAG 1048576u    // 128 flags x 64 B

// ---- LDS byte offsets (131072 dynamic, weights only, hi/lo bf16 planes) ----
#define E0HI 0u            // 16 rows x 576  (x|h0)
#define E0LO 18432u
#define E1HI 36864u        // 16 rows x 1024 (h0|h1)
#define E1LO 69632u
#define D0HI 0u            // 16 rows x 1024 (Weff|dWhh0)
#define D0LO 32768u
#define D1HI 65536u        // 16 rows x 1024 (dWih1|dWhh1)
#define D1LO 98304u

__device__ __forceinline__ float sigf(float x) { return 1.0f / (1.0f + expf(-x)); }

__device__ __forceinline__ u16 f2bf(float f) {   // RNE
    union { float f; unsigned u; } v; v.f = f;
    unsigned r = v.u + 0x7FFFu + ((v.u >> 16) & 1u);
    return (u16)(r >> 16);
}
__device__ __forceinline__ float bf2f(u16 h) {
    union { unsigned u; float f; } v; v.u = ((unsigned)h) << 16;
    return v.f;
}

// LLC-coherent (agent-scope, sc1) accesses: bypass per-XCD L2, served by Infinity Cache.
__device__ __forceinline__ u64 llc_load64(const u64* p) {
    return __hip_atomic_load((u64*)p, __ATOMIC_RELAXED, __HIP_MEMORY_SCOPE_AGENT);
}
__device__ __forceinline__ void llc_store64(u64* p, u64 v) {
    __hip_atomic_store(p, v, __ATOMIC_RELAXED, __HIP_MEMORY_SCOPE_AGENT);
}
__device__ __forceinline__ void llc_store32(u32* p, u32 v) {
    __hip_atomic_store(p, v, __ATOMIC_RELAXED, __HIP_MEMORY_SCOPE_AGENT);
}

// Grid barrier with NO cache-maintenance ops: vmcnt(0) drains own sc1 stores to LLC,
// flag store/poll are LLC-coherent atomics. Monotonic generations.
__device__ __forceinline__ void gbar(int* flags, int w, int gen) {
    asm volatile("s_waitcnt vmcnt(0)" ::: "memory");
    __syncthreads();
    if (threadIdx.x == 0)
        __hip_atomic_store(flags + w * 16, gen, __ATOMIC_RELAXED, __HIP_MEMORY_SCOPE_AGENT);
    if (threadIdx.x < NWG) {
        while (__hip_atomic_load(flags + threadIdx.x * 16, __ATOMIC_RELAXED,
                                 __HIP_MEMORY_SCOPE_AGENT) < gen)
            __builtin_amdgcn_s_sleep(1);
    }
    __syncthreads();
}

// store one weight element as hi/lo bf16 into swizzled LDS planes
__device__ __forceinline__ void st_w(char* smem, unsigned hiB, unsigned loB, unsigned K2,
                                     unsigned m, unsigned k, float v) {
    u16 hh = f2bf(v);
    u16 ll = f2bf(v - bf2f(hh));
    unsigned off = (m * K2 + k * 2) ^ ((m & 7) << 4);
    *(u16*)(smem + hiB + off) = hh;
    *(u16*)(smem + loB + off) = ll;
}

// One K-segment: A (16 rows) from swizzled LDS hi/lo; B from packed u32 plane via
// 8B LLC loads (4 per chunk, contiguous 32B/lane). 3 MFMAs per 32-k chunk.
template <int NCH>
__device__ __forceinline__ void seg_tiled(
    const char* smem, unsigned hiB, unsigned loB, unsigned K2, unsigned wk0,
    const u32* __restrict__ hp, unsigned bt, int lane, f32x4& acc0, f32x4& acc1) {
    const unsigned mm = lane & 15, qq = lane >> 4;
    const unsigned swz = (mm & 7) << 4;
    const unsigned wb0 = mm * K2 + (wk0 + qq * 8) * 2;
    const u64* pb = (const u64*)(hp + (size_t)(bt + mm) * 32 + qq * 8);
    #pragma unroll 4
    for (int i = 0; i < NCH; ++i) {
        union { u64 q[4]; u16 s[16]; } t;
        t.q[0] = llc_load64(pb + (size_t)i * 2048);
        t.q[1] = llc_load64(pb + (size_t)i * 2048 + 1);
        t.q[2] = llc_load64(pb + (size_t)i * 2048 + 2);
        t.q[3] = llc_load64(pb + (size_t)i * 2048 + 3);
        bf16x8 bhi, blo;
        #pragma unroll
        for (int j = 0; j < 8; ++j) { bhi[j] = (short)t.s[2 * j]; blo[j] = (short)t.s[2 * j + 1]; }
        bf16x8 ahi = *(const bf16x8*)(smem + hiB + ((wb0 + i * 64) ^ swz));
        bf16x8 alo = *(const bf16x8*)(smem + loB + ((wb0 + i * 64) ^ swz));
        acc0 = __builtin_amdgcn_mfma_f32_16x16x32_bf16(ahi, bhi, acc0, 0, 0, 0);
        acc1 = __builtin_amdgcn_mfma_f32_16x16x32_bf16(ahi, blo, acc1, 0, 0, 0);
        acc1 = __builtin_amdgcn_mfma_f32_16x16x32_bf16(alo, bhi, acc1, 0, 0, 0);
    }
}

// encoder cell-A x-segment (K=64): B built on the fly from fp32 x rows (read-only input)
__device__ __forceinline__ void seg_x(
    const char* smem, unsigned hiB, unsigned loB, unsigned K2,
    const float* __restrict__ x, int t, unsigned bt, int lane, f32x4& acc0, f32x4& acc1) {
    const unsigned mm = lane & 15, qq = lane >> 4;
    const unsigned swz = (mm & 7) << 4;
    const float* xp = x + ((size_t)(bt + mm) * T_ + t) * 64 + qq * 8;
    #pragma unroll
    for (int i = 0; i < 2; ++i) {
        float4 f0 = *(const float4*)(xp + i * 32);
        float4 f1 = *(const float4*)(xp + i * 32 + 4);
        float fs[8] = { f0.x, f0.y, f0.z, f0.w, f1.x, f1.y, f1.z, f1.w };
        bf16x8 bhi, blo;
        #pragma unroll
        for (int j = 0; j < 8; ++j) {
            u16 hh = f2bf(fs[j]);
            bhi[j] = (short)hh;
            blo[j] = (short)f2bf(fs[j] - bf2f(hh));
        }
        unsigned wb = (mm * K2 + (qq * 8 + i * 32) * 2) ^ swz;
        bf16x8 ahi = *(const bf16x8*)(smem + hiB + wb);
        bf16x8 alo = *(const bf16x8*)(smem + loB + wb);
        acc0 = __builtin_amdgcn_mfma_f32_16x16x32_bf16(ahi, bhi, acc0, 0, 0, 0);
        acc1 = __builtin_amdgcn_mfma_f32_16x16x32_bf16(ahi, blo, acc1, 0, 0, 0);
        acc1 = __builtin_amdgcn_mfma_f32_16x16x32_bf16(alo, bhi, acc1, 0, 0, 0);
    }
}

// LSTM epilogue: lane owns 4 gate preacts of one (u,b); c lives in a register;
// h stored as one packed u32 (hi | lo<<16) LLC store.
__device__ __forceinline__ void epilogue_reg(f32x4 acc, const float* bz, int u, int b,
                                             float& cr, u32* hw) {
    float gi = sigf(acc[0] + bz[0]);
    float gf = sigf(acc[1] + bz[1]);
    float gt = tanhf(acc[2] + bz[2]);
    float go = sigf(acc[3] + bz[3]);
    float cn = gf * cr + gi * gt;
    cr = cn;
    float hv = go * tanhf(cn);
    u16 hh = f2bf(hv);
    u16 ll = f2bf(hv - bf2f(hh));
    unsigned hidx = (unsigned)(u >> 5) * 4096 + (unsigned)b * 32 + (u & 31);
    llc_store32(hw + hidx, (u32)hh | ((u32)ll << 16));
}

// out(t) = h1 @ linW.T + linb; WG w handles batch b=w, 512 threads = 64 f x 8 kq.
__device__ __forceinline__ void linear_out(const u32* __restrict__ h1p,
                                           const float* __restrict__ linW,
                                           const float* __restrict__ linb,
                                           float* __restrict__ out, int w, int tid, int t) {
    const int kq = tid & 7;
    const int f  = tid >> 3;     // 0..63
    float s = 0.f;
    #pragma unroll
    for (int c2 = 0; c2 < 2; ++c2) {
        const int ch = kq * 2 + c2;   // k chunk = k>>5
        const u64* ph = (const u64*)(h1p + (size_t)ch * 4096 + (size_t)w * 32);
        const float* wp = linW + (size_t)f * H_ + ch * 32;
        #pragma unroll
        for (int j = 0; j < 16; ++j) {     // each u64 = 2 packed elements
            u64 r = llc_load64(ph + j);
            float h0 = bf2f((u16)r) + bf2f((u16)(r >> 16));
            float h1 = bf2f((u16)(r >> 32)) + bf2f((u16)(r >> 48));
            s += h0 * wp[2 * j] + h1 * wp[2 * j + 1];
        }
    }
    s += __shfl_xor(s, 1);
    s += __shfl_xor(s, 2);
    s += __shfl_xor(s, 4);
    if (kq == 0)
        out[((size_t)w * T_ + (255 - t)) * 64 + f] = s + linb[f];
}

__global__ __launch_bounds__(NTHR, 2) void lstm_persist(
    const float* __restrict__ x,
    const float* __restrict__ eWih0, const float* __restrict__ eWhh0,
    const float* __restrict__ ebih0, const float* __restrict__ ebhh0,
    const float* __restrict__ eWih1, const float* __restrict__ eWhh1,
    const float* __restrict__ ebih1, const float* __restrict__ ebhh1,
    const float* __restrict__ dWih0, const float* __restrict__ dWhh0,
    const float* __restrict__ dbih0, const float* __restrict__ dbhh0,
    const float* __restrict__ dWih1, const float* __restrict__ dWhh1,
    const float* __restrict__ dbih1, const float* __restrict__ dbhh1,
    const float* __restrict__ linW,  const float* __restrict__ linb,
    float* __restrict__ out, char* __restrict__ wsb, int* __restrict__ flags) {
    extern __shared__ char smem[];
    const int w = blockIdx.x, tid = threadIdx.x;
    const int lane = tid & 63, wave = tid >> 6;
    const int gid = w * NTHR + tid;

    const int u_base = w * 4;                  // WG = u-quad
    const int u = u_base + (lane >> 4);
    const unsigned bt = (unsigned)wave * 16;   // wave = b-tile
    const int b = (int)bt + (lane & 15);

    u32* h0p[2] = { (u32*)(wsb + O_H0), (u32*)(wsb + O_H0 + 262144u) };
    u32* h1p[2] = { (u32*)(wsb + O_H1), (u32*)(wsb + O_H1 + 262144u) };
    int gen = 0;

    // ================= INIT =================
    {   // zero all h planes (1 MB) via LLC stores
        u64* hz = (u64*)wsb;
        for (unsigned i = gid; i < 131072u; i += NWG * NTHR) llc_store64(hz + i, 0ULL);
    }
    // per-lane bias registers (incl. beff fold); c in registers
    float bzA[4], bzB[4], bzD0[4], bzD0b[4], bzD1[4];
    #pragma unroll
    for (int g = 0; g < 4; ++g) {
        const int gr = g * H_ + u;
        bzA[g] = ebih0[gr] + ebhh0[gr];
        bzB[g] = ebih1[gr] + ebhh1[gr];
        float d0 = dbih0[gr] + dbhh0[gr];
        bzD0[g] = d0;
        float s = 0.f;
        for (int f = 0; f < 64; ++f) s += dWih0[(size_t)gr * 64 + f] * linb[f];
        bzD0b[g] = d0 + s;
        bzD1[g] = dbih1[gr] + dbhh1[gr];
    }
    float c0r = 0.f, c1r = 0.f;

    // encoder weights -> swizzled LDS hi/lo (WG-local slice: 16 M-rows)
    for (int mr = 0; mr < 16; ++mr) {
        const int gr = (mr & 3) * H_ + u_base + (mr >> 2);
        for (int k = tid; k < 576; k += NTHR) {
            float v = (k < 64) ? eWih0[(size_t)gr * 64 + k] : eWhh0[(size_t)gr * H_ + (k - 64)];
            st_w(smem, E0HI, E0LO, 1152, mr, k, v);
        }
        for (int k = tid; k < 1024; k += NTHR) {
            float v = (k < 512) ? eWih1[(size_t)gr * H_ + k] : eWhh1[(size_t)gr * H_ + (k - 512)];
            st_w(smem, E1HI, E1LO, 2048, mr, k, v);
        }
    }
    gbar(flags, w, ++gen);

    // ================= ENCODER: pipelined, 257 phases =================
    // phase p: cellA(t=p) || cellB(t=p-1), one barrier per phase.
    for (int p = 0; p <= T_; ++p) {
        f32x4 a0 = {0,0,0,0}, a1 = {0,0,0,0}, e0 = {0,0,0,0}, e1 = {0,0,0,0};
        if (p < T_) {   // cellA(p): [x_p | h0(p-1)] -> h0[p&1]
            seg_x(smem, E0HI, E0LO, 1152, x, p, bt, lane, a0, a1);
            seg_tiled<16>(smem, E0HI, E0LO, 1152, 64, h0p[(p + 1) & 1], bt, lane, a0, a1);
        }
        if (p >= 1) {   // cellB(p-1): [h0(p-1) | h1(p-2)] -> h1[(p+1)&1]
            seg_tiled<16>(smem, E1HI, E1LO, 2048, 0,   h0p[(p + 1) & 1], bt, lane, e0, e1);
            seg_tiled<16>(smem, E1HI, E1LO, 2048, 512, h1p[p & 1],       bt, lane, e0, e1);
        }
        if (p < T_)  epilogue_reg(a0 + a1, bzA, u, b, c0r, h0p[p & 1]);
        if (p >= 1)  epilogue_reg(e0 + e1, bzB, u, b, c1r, h1p[(p + 1) & 1]);
        gbar(flags, w, ++gen);
    }

    // ================= TRANSITION: decoder weights -> LDS (WG-local) =================
    for (int mr = 0; mr < 16; ++mr) {
        const int gr = (mr & 3) * H_ + u_base + (mr >> 2);
        const float* wr = dWih0 + (size_t)gr * 64;
        const int c = tid;   // 512 cols, one per thread
        float s = 0.f;
        #pragma unroll 8
        for (int f = 0; f < 64; ++f) s += wr[f] * linW[(size_t)f * H_ + c];   // Weff = dWih0 @ linW
        st_w(smem, D0HI, D0LO, 2048, mr, c, s);
        st_w(smem, D0HI, D0LO, 2048, mr, 512 + c, dWhh0[(size_t)gr * H_ + c]);
        st_w(smem, D1HI, D1LO, 2048, mr, c,       dWih1[(size_t)gr * H_ + c]);
        st_w(smem, D1HI, D1LO, 2048, mr, 512 + c, dWhh1[(size_t)gr * H_ + c]);
    }
    __syncthreads();

    // ================= DECODER: 512 phases =================
    for (int t = 0; t < T_; ++t) {
        const int cp = t & 1, pp = (t + 1) & 1;
        {   // dec0(t): Weff.h1(t-1) (or direct x-projection at t=0) + dWhh0.h0(t-1)
            f32x4 a0 = {0,0,0,0}, a1 = {0,0,0,0};
            if (t > 0) {
                seg_tiled<16>(smem, D0HI, D0LO, 2048, 0, h1p[pp], bt, lane, a0, a1);
            } else {
                const float* xr = x + ((size_t)b * T_ + (T_ - 1)) * 64;
                #pragma unroll
                for (int g = 0; g < 4; ++g) {
                    const float* wr = dWih0 + (size_t)(g * H_ + u) * 64;
                    float s = 0.f;
                    for (int f = 0; f < 64; ++f) s += wr[f] * xr[f];
                    a0[g] = s;
                }
            }
            seg_tiled<16>(smem, D0HI, D0LO, 2048, 512, h0p[pp], bt, lane, a0, a1);
            epilogue_reg(a0 + a1, (t > 0) ? bzD0b : bzD0, u, b, c0r, h0p[cp]);
            if (t > 0) linear_out(h1p[pp], linW, linb, out, w, tid, t - 1);  // folded linear(t-1)
        }
        gbar(flags, w, ++gen);
        {   // dec1(t): dWih1.h0(t) + dWhh1.h1(t-1)
            f32x4 a0 = {0,0,0,0}, a1 = {0,0,0,0};
            seg_tiled<16>(smem, D1HI, D1LO, 2048, 0,   h0p[cp], bt, lane, a0, a1);
            seg_tiled<16>(smem, D1HI, D1LO, 2048, 512, h1p[pp], bt, lane, a0, a1);
            epilogue_reg(a0 + a1, bzD1, u, b, c1r, h1p[cp]);
        }
        gbar(flags, w, ++gen);
    }
    // final output (t=255): h1(255) lives in parity plane 1
    linear_out(h1p[1], linW, linb, out, w, tid, 255);
}

extern "C" void kernel_launch(void* const* d_in, const int* in_sizes, int n_in,
                              void* d_out, int out_size, void* d_ws, size_t ws_size,
                              hipStream_t stream) {
    (void)in_sizes; (void)n_in; (void)out_size; (void)ws_size;
    const float* x     = (const float*)d_in[0];
    const float* eWih0 = (const float*)d_in[1];
    const float* eWhh0 = (const float*)d_in[2];
    const float* ebih0 = (const float*)d_in[3];
    const float* ebhh0 = (const float*)d_in[4];
    const float* eWih1 = (const float*)d_in[5];
    const float* eWhh1 = (const float*)d_in[6];
    const float* ebih1 = (const float*)d_in[7];
    const float* ebhh1 = (const float*)d_in[8];
    const float* dWih0 = (const float*)d_in[9];
    const float* dWhh0 = (const float*)d_in[10];
    const float* dbih0 = (const float*)d_in[11];
    const float* dbhh0 = (const float*)d_in[12];
    const float* dWih1 = (const float*)d_in[13];
    const float* dWhh1 = (const float*)d_in[14];
    const float* dbih1 = (const float*)d_in[15];
    const float* dbhh1 = (const float*)d_in[16];
    const float* linW  = (const float*)d_in[17];
    const float* linb  = (const float*)d_in[18];

    char* wsb  = (char*)d_ws;
    int* flags = (int*)(wsb + O_FLAG);

    static const int lds_bytes = 131072;
    hipFuncSetAttribute((const void*)lstm_persist,
                        hipFuncAttributeMaxDynamicSharedMemorySize, lds_bytes);

    hipMemsetAsync(flags, 0, NWG * 64, stream);

    hipLaunchKernelGGL(lstm_persist, dim3(NWG), dim3(NTHR), lds_bytes, stream,
                       x, eWih0, eWhh0, ebih0, ebhh0, eWih1, eWhh1, ebih1, ebhh1,
                       dWih0, dWhh0, dbih0, dbhh0, dWih1, dWhh1, dbih1, dbhh1,
                       linW, linb, (float*)d_out, wsb, flags);
}

// Round 7
// 19747.079 us; speedup vs baseline: 2.3712x; 1.5006x over previous
//
#include <hip/hip_runtime.h>
#include <math.h>

#define T_ 256
#define H_ 512
#define NWG 128
#define NTHR 512

typedef short bf16x8 __attribute__((ext_vector_type(8)));
typedef float f32x4 __attribute__((ext_vector_type(4)));
typedef unsigned short u16;
typedef unsigned int u32;
typedef unsigned long long u64;

// ---- ws byte offsets: h planes hold hi|lo<<16 packed u32, tiled [kchunk16][b128][k32] ----
#define O_H0   0u          // 2 parities x 262144 B
#define O_H1   524288u
#define O_FLAG 1048576u    // 128 flags x 64 B

// ---- LDS byte offsets (131072 dynamic, weights only, hi/lo bf16 planes) ----
#define E0HI 0u            // 16 rows x 576  (x|h0)
#define E0LO 18432u
#define E1HI 36864u        // 16 rows x 1024 (h0|h1)
#define E1LO 69632u
#define D0HI 0u            // 16 rows x 1024 (Weff|dWhh0)
#define D0LO 32768u
#define D1HI 65536u        // 16 rows x 1024 (dWih1|dWhh1)
#define D1LO 98304u

__device__ __forceinline__ float sigf(float x) { return 1.0f / (1.0f + expf(-x)); }

__device__ __forceinline__ u16 f2bf(float f) {   // RNE
    union { float f; unsigned u; } v; v.f = f;
    unsigned r = v.u + 0x7FFFu + ((v.u >> 16) & 1u);
    return (u16)(r >> 16);
}
__device__ __forceinline__ float bf2f(u16 h) {
    union { unsigned u; float f; } v; v.u = ((unsigned)h) << 16;
    return v.f;
}

// Producer-side stores: agent-scope write-through (visible at MALL, no dirty L2 lines).
__device__ __forceinline__ void llc_store64(u64* p, u64 v) {
    __hip_atomic_store(p, v, __ATOMIC_RELAXED, __HIP_MEMORY_SCOPE_AGENT);
}
__device__ __forceinline__ void llc_store32(u32* p, u32 v) {
    __hip_atomic_store(p, v, __ATOMIC_RELAXED, __HIP_MEMORY_SCOPE_AGENT);
}

// Grid barrier. Release: per-wave vmcnt(0) drains sc1 stores to MALL, then flag store.
// Acquire: after flag poll succeeds, one agent acquire fence (waitcnt + L2 clean-line
// invalidate) so subsequent PLAIN cached loads refill fresh data from the MALL.
__device__ __forceinline__ void gbar(int* flags, int w, int gen) {
    asm volatile("s_waitcnt vmcnt(0)" ::: "memory");
    __syncthreads();
    if (threadIdx.x == 0)
        __hip_atomic_store(flags + w * 16, gen, __ATOMIC_RELAXED, __HIP_MEMORY_SCOPE_AGENT);
    if (threadIdx.x < NWG) {
        while (__hip_atomic_load(flags + threadIdx.x * 16, __ATOMIC_RELAXED,
                                 __HIP_MEMORY_SCOPE_AGENT) < gen)
            __builtin_amdgcn_s_sleep(1);
    }
    __builtin_amdgcn_fence(__ATOMIC_ACQUIRE, "agent");   // inv stale L2 lines (post-poll)
    __syncthreads();
}

// store one weight element as hi/lo bf16 into swizzled LDS planes
__device__ __forceinline__ void st_w(char* smem, unsigned hiB, unsigned loB, unsigned K2,
                                     unsigned m, unsigned k, float v) {
    u16 hh = f2bf(v);
    u16 ll = f2bf(v - bf2f(hh));
    unsigned off = (m * K2 + k * 2) ^ ((m & 7) << 4);
    *(u16*)(smem + hiB + off) = hh;
    *(u16*)(smem + loB + off) = ll;
}

// One K-segment: A (16 rows) from swizzled LDS hi/lo; B from packed u32 plane via
// PLAIN cached 32B/lane loads (L2-shared across the XCD). 3 MFMAs per 32-k chunk.
template <int NCH>
__device__ __forceinline__ void seg_tiled(
    const char* smem, unsigned hiB, unsigned loB, unsigned K2, unsigned wk0,
    const u32* __restrict__ hp, unsigned bt, int lane, f32x4& acc0, f32x4& acc1) {
    const unsigned mm = lane & 15, qq = lane >> 4;
    const unsigned swz = (mm & 7) << 4;
    const unsigned wb0 = mm * K2 + (wk0 + qq * 8) * 2;
    const u64* pb = (const u64*)(hp + (size_t)(bt + mm) * 32 + qq * 8);
    #pragma unroll 4
    for (int i = 0; i < NCH; ++i) {
        union { u64 q[4]; u16 s[16]; } t;
        t.q[0] = pb[(size_t)i * 2048];
        t.q[1] = pb[(size_t)i * 2048 + 1];
        t.q[2] = pb[(size_t)i * 2048 + 2];
        t.q[3] = pb[(size_t)i * 2048 + 3];
        bf16x8 bhi, blo;
        #pragma unroll
        for (int j = 0; j < 8; ++j) { bhi[j] = (short)t.s[2 * j]; blo[j] = (short)t.s[2 * j + 1]; }
        bf16x8 ahi = *(const bf16x8*)(smem + hiB + ((wb0 + i * 64) ^ swz));
        bf16x8 alo = *(const bf16x8*)(smem + loB + ((wb0 + i * 64) ^ swz));
        acc0 = __builtin_amdgcn_mfma_f32_16x16x32_bf16(ahi, bhi, acc0, 0, 0, 0);
        acc1 = __builtin_amdgcn_mfma_f32_16x16x32_bf16(ahi, blo, acc1, 0, 0, 0);
        acc1 = __builtin_amdgcn_mfma_f32_16x16x32_bf16(alo, bhi, acc1, 0, 0, 0);
    }
}

// encoder cell-A x-segment (K=64): B built on the fly from fp32 x rows (read-only input)
__device__ __forceinline__ void seg_x(
    const char* smem, unsigned hiB, unsigned loB, unsigned K2,
    const float* __restrict__ x, int t, unsigned bt, int lane, f32x4& acc0, f32x4& acc1) {
    const unsigned mm = lane & 15, qq = lane >> 4;
    const unsigned swz = (mm & 7) << 4;
    const float* xp = x + ((size_t)(bt + mm) * T_ + t) * 64 + qq * 8;
    #pragma unroll
    for (int i = 0; i < 2; ++i) {
        float4 f0 = *(const float4*)(xp + i * 32);
        float4 f1 = *(const float4*)(xp + i * 32 + 4);
        float fs[8] = { f0.x, f0.y, f0.z, f0.w, f1.x, f1.y, f1.z, f1.w };
        bf16x8 bhi, blo;
        #pragma unroll
        for (int j = 0; j < 8; ++j) {
            u16 hh = f2bf(fs[j]);
            bhi[j] = (short)hh;
            blo[j] = (short)f2bf(fs[j] - bf2f(hh));
        }
        unsigned wb = (mm * K2 + (qq * 8 + i * 32) * 2) ^ swz;
        bf16x8 ahi = *(const bf16x8*)(smem + hiB + wb);
        bf16x8 alo = *(const bf16x8*)(smem + loB + wb);
        acc0 = __builtin_amdgcn_mfma_f32_16x16x32_bf16(ahi, bhi, acc0, 0, 0, 0);
        acc1 = __builtin_amdgcn_mfma_f32_16x16x32_bf16(ahi, blo, acc1, 0, 0, 0);
        acc1 = __builtin_amdgcn_mfma_f32_16x16x32_bf16(alo, bhi, acc1, 0, 0, 0);
    }
}

// LSTM epilogue: lane owns 4 gate preacts of one (u,b); c lives in a register;
// h stored as one packed u32 (hi | lo<<16) write-through store.
__device__ __forceinline__ void epilogue_reg(f32x4 acc, const float* bz, int u, int b,
                                             float& cr, u32* hw) {
    float gi = sigf(acc[0] + bz[0]);
    float gf = sigf(acc[1] + bz[1]);
    float gt = tanhf(acc[2] + bz[2]);
    float go = sigf(acc[3] + bz[3]);
    float cn = gf * cr + gi * gt;
    cr = cn;
    float hv = go * tanhf(cn);
    u16 hh = f2bf(hv);
    u16 ll = f2bf(hv - bf2f(hh));
    unsigned hidx = (unsigned)(u >> 5) * 4096 + (unsigned)b * 32 + (u & 31);
    llc_store32(hw + hidx, (u32)hh | ((u32)ll << 16));
}

// out(t) = h1 @ linW.T + linb; WG w handles batch b=w, 512 threads = 64 f x 8 kq.
__device__ __forceinline__ void linear_out(const u32* __restrict__ h1p,
                                           const float* __restrict__ linW,
                                           const float* __restrict__ linb,
                                           float* __restrict__ out, int w, int tid, int t) {
    const int kq = tid & 7;
    const int f  = tid >> 3;     // 0..63
    float s = 0.f;
    #pragma unroll
    for (int c2 = 0; c2 < 2; ++c2) {
        const int ch = kq * 2 + c2;   // k chunk = k>>5
        const u64* ph = (const u64*)(h1p + (size_t)ch * 4096 + (size_t)w * 32);
        const float* wp = linW + (size_t)f * H_ + ch * 32;
        #pragma unroll
        for (int j = 0; j < 16; ++j) {     // each u64 = 2 packed elements
            u64 r = ph[j];
            float h0 = bf2f((u16)r) + bf2f((u16)(r >> 16));
            float h1 = bf2f((u16)(r >> 32)) + bf2f((u16)(r >> 48));
            s += h0 * wp[2 * j] + h1 * wp[2 * j + 1];
        }
    }
    s += __shfl_xor(s, 1);
    s += __shfl_xor(s, 2);
    s += __shfl_xor(s, 4);
    if (kq == 0)
        out[((size_t)w * T_ + (255 - t)) * 64 + f] = s + linb[f];
}

__global__ __launch_bounds__(NTHR, 2) void lstm_persist(
    const float* __restrict__ x,
    const float* __restrict__ eWih0, const float* __restrict__ eWhh0,
    const float* __restrict__ ebih0, const float* __restrict__ ebhh0,
    const float* __restrict__ eWih1, const float* __restrict__ eWhh1,
    const float* __restrict__ ebih1, const float* __restrict__ ebhh1,
    const float* __restrict__ dWih0, const float* __restrict__ dWhh0,
    const float* __restrict__ dbih0, const float* __restrict__ dbhh0,
    const float* __restrict__ dWih1, const float* __restrict__ dWhh1,
    const float* __restrict__ dbih1, const float* __restrict__ dbhh1,
    const float* __restrict__ linW,  const float* __restrict__ linb,
    float* __restrict__ out, char* __restrict__ wsb, int* __restrict__ flags) {
    extern __shared__ char smem[];
    const int w = blockIdx.x, tid = threadIdx.x;
    const int lane = tid & 63, wave = tid >> 6;
    const int gid = w * NTHR + tid;

    const int u_base = w * 4;                  // WG = u-quad
    const int u = u_base + (lane >> 4);
    const unsigned bt = (unsigned)wave * 16;   // wave = b-tile
    const int b = (int)bt + (lane & 15);

    u32* h0p[2] = { (u32*)(wsb + O_H0), (u32*)(wsb + O_H0 + 262144u) };
    u32* h1p[2] = { (u32*)(wsb + O_H1), (u32*)(wsb + O_H1 + 262144u) };
    int gen = 0;

    // ================= INIT =================
    {   // zero all h planes (1 MB) via write-through stores
        u64* hz = (u64*)wsb;
        for (unsigned i = gid; i < 131072u; i += NWG * NTHR) llc_store64(hz + i, 0ULL);
    }
    // per-lane bias registers (incl. beff fold); c in registers
    float bzA[4], bzB[4], bzD0[4], bzD0b[4], bzD1[4];
    #pragma unroll
    for (int g = 0; g < 4; ++g) {
        const int gr = g * H_ + u;
        bzA[g] = ebih0[gr] + ebhh0[gr];
        bzB[g] = ebih1[gr] + ebhh1[gr];
        float d0 = dbih0[gr] + dbhh0[gr];
        bzD0[g] = d0;
        float s = 0.f;
        for (int f = 0; f < 64; ++f) s += dWih0[(size_t)gr * 64 + f] * linb[f];
        bzD0b[g] = d0 + s;
        bzD1[g] = dbih1[gr] + dbhh1[gr];
    }
    float c0r = 0.f, c1r = 0.f;

    // encoder weights -> swizzled LDS hi/lo (WG-local slice: 16 M-rows)
    for (int mr = 0; mr < 16; ++mr) {
        const int gr = (mr & 3) * H_ + u_base + (mr >> 2);
        for (int k = tid; k < 576; k += NTHR) {
            float v = (k < 64) ? eWih0[(size_t)gr * 64 + k] : eWhh0[(size_t)gr * H_ + (k - 64)];
            st_w(smem, E0HI, E0LO, 1152, mr, k, v);
        }
        for (int k = tid; k < 1024; k += NTHR) {
            float v = (k < 512) ? eWih1[(size_t)gr * H_ + k] : eWhh1[(size_t)gr * H_ + (k - 512)];
            st_w(smem, E1HI, E1LO, 2048, mr, k, v);
        }
    }
    gbar(flags, w, ++gen);

    // ================= ENCODER: pipelined, 257 phases =================
    // phase p: cellA(t=p) || cellB(t=p-1), one barrier per phase.
    for (int p = 0; p <= T_; ++p) {
        f32x4 a0 = {0,0,0,0}, a1 = {0,0,0,0}, e0 = {0,0,0,0}, e1 = {0,0,0,0};
        if (p < T_) {   // cellA(p): [x_p | h0(p-1)] -> h0[p&1]
            seg_x(smem, E0HI, E0LO, 1152, x, p, bt, lane, a0, a1);
            seg_tiled<16>(smem, E0HI, E0LO, 1152, 64, h0p[(p + 1) & 1], bt, lane, a0, a1);
        }
        if (p >= 1) {   // cellB(p-1): [h0(p-1) | h1(p-2)] -> h1[(p+1)&1]
            seg_tiled<16>(smem, E1HI, E1LO, 2048, 0,   h0p[(p + 1) & 1], bt, lane, e0, e1);
            seg_tiled<16>(smem, E1HI, E1LO, 2048, 512, h1p[p & 1],       bt, lane, e0, e1);
        }
        if (p < T_)  epilogue_reg(a0 + a1, bzA, u, b, c0r, h0p[p & 1]);
        if (p >= 1)  epilogue_reg(e0 + e1, bzB, u, b, c1r, h1p[(p + 1) & 1]);
        gbar(flags, w, ++gen);
    }

    // ================= TRANSITION: decoder weights -> LDS (WG-local) =================
    for (int mr = 0; mr < 16; ++mr) {
        const int gr = (mr & 3) * H_ + u_base + (mr >> 2);
        const float* wr = dWih0 + (size_t)gr * 64;
        const int c = tid;   // 512 cols, one per thread
        float s = 0.f;
        #pragma unroll 8
        for (int f = 0; f < 64; ++f) s += wr[f] * linW[(size_t)f * H_ + c];   // Weff = dWih0 @ linW
        st_w(smem, D0HI, D0LO, 2048, mr, c, s);
        st_w(smem, D0HI, D0LO, 2048, mr, 512 + c, dWhh0[(size_t)gr * H_ + c]);
        st_w(smem, D1HI, D1LO, 2048, mr, c,       dWih1[(size_t)gr * H_ + c]);
        st_w(smem, D1HI, D1LO, 2048, mr, 512 + c, dWhh1[(size_t)gr * H_ + c]);
    }
    __syncthreads();

    // ================= DECODER: 512 phases =================
    for (int t = 0; t < T_; ++t) {
        const int cp = t & 1, pp = (t + 1) & 1;
        {   // dec0(t): Weff.h1(t-1) (or direct x-projection at t=0) + dWhh0.h0(t-1)
            f32x4 a0 = {0,0,0,0}, a1 = {0,0,0,0};
            if (t > 0) {
                seg_tiled<16>(smem, D0HI, D0LO, 2048, 0, h1p[pp], bt, lane, a0, a1);
            } else {
                const float* xr = x + ((size_t)b * T_ + (T_ - 1)) * 64;
                #pragma unroll
                for (int g = 0; g < 4; ++g) {
                    const float* wr = dWih0 + (size_t)(g * H_ + u) * 64;
                    float s = 0.f;
                    for (int f = 0; f < 64; ++f) s += wr[f] * xr[f];
                    a0[g] = s;
                }
            }
            seg_tiled<16>(smem, D0HI, D0LO, 2048, 512, h0p[pp], bt, lane, a0, a1);
            epilogue_reg(a0 + a1, (t > 0) ? bzD0b : bzD0, u, b, c0r, h0p[cp]);
            if (t > 0) linear_out(h1p[pp], linW, linb, out, w, tid, t - 1);  // folded linear(t-1)
        }
        gbar(flags, w, ++gen);
        {   // dec1(t): dWih1.h0(t) + dWhh1.h1(t-1)
            f32x4 a0 = {0,0,0,0}, a1 = {0,0,0,0};
            seg_tiled<16>(smem, D1HI, D1LO, 2048, 0,   h0p[cp], bt, lane, a0, a1);
            seg_tiled<16>(smem, D1HI, D1LO, 2048, 512, h1p[pp], bt, lane, a0, a1);
            epilogue_reg(a0 + a1, bzD1, u, b, c1r, h1p[cp]);
        }
        gbar(flags, w, ++gen);
    }
    // final output (t=255): h1(255) lives in parity plane 1
    linear_out(h1p[1], linW, linb, out, w, tid, 255);
}

extern "C" void kernel_launch(void* const* d_in, const int* in_sizes, int n_in,
                              void* d_out, int out_size, void* d_ws, size_t ws_size,
                              hipStream_t stream) {
    (void)in_sizes; (void)n_in; (void)out_size; (void)ws_size;
    const float* x     = (const float*)d_in[0];
    const float* eWih0 = (const float*)d_in[1];
    const float* eWhh0 = (const float*)d_in[2];
    const float* ebih0 = (const float*)d_in[3];
    const float* ebhh0 = (const float*)d_in[4];
    const float* eWih1 = (const float*)d_in[5];
    const float* eWhh1 = (const float*)d_in[6];
    const float* ebih1 = (const float*)d_in[7];
    const float* ebhh1 = (const float*)d_in[8];
    const float* dWih0 = (const float*)d_in[9];
    const float* dWhh0 = (const float*)d_in[10];
    const float* dbih0 = (const float*)d_in[11];
    const float* dbhh0 = (const float*)d_in[12];
    const float* dWih1 = (const float*)d_in[13];
    const float* dWhh1 = (const float*)d_in[14];
    const float* dbih1 = (const float*)d_in[15];
    const float* dbhh1 = (const float*)d_in[16];
    const float* linW  = (const float*)d_in[17];
    const float* linb  = (const float*)d_in[18];

    char* wsb  = (char*)d_ws;
    int* flags = (int*)(wsb + O_FLAG);

    static const int lds_bytes = 131072;
    hipFuncSetAttribute((const void*)lstm_persist,
                        hipFuncAttributeMaxDynamicSharedMemorySize, lds_bytes);

    hipMemsetAsync(flags, 0, NWG * 64, stream);

    hipLaunchKernelGGL(lstm_persist, dim3(NWG), dim3(NTHR), lds_bytes, stream,
                       x, eWih0, eWhh0, ebih0, ebhh0, eWih1, eWhh1, ebih1, ebhh1,
                       dWih0, dWhh0, dbih0, dbhh0, dWih1, dWhh1, dbih1, dbhh1,
                       linW, linb, (float*)d_out, wsb, flags);
}

// Round 8
// 19645.738 us; speedup vs baseline: 2.3834x; 1.0052x over previous
//
#include <hip/hip_runtime.h>
#include <math.h>

#define T_ 256
#define H_ 512
#define NWG 128
#define NTHR 512

typedef short bf16x8 __attribute__((ext_vector_type(8)));
typedef float f32x4 __attribute__((ext_vector_type(4)));
typedef unsigned short u16;
typedef unsigned int u32;
typedef unsigned long long u64;

// ---- ws byte offsets: h planes hold hi|lo<<16 packed u32, tiled [kchunk16][b128][k32] ----
#define O_H0   0u          // 2 parities x 262144 B
#define O_H1   524288u
#define O_FLAG 1048576u    // 128 flags x 64 B

// ---- LDS byte offsets (131072 dynamic, weights only, hi/lo bf16 planes) ----
#define E0HI 0u            // 16 rows x 576  (x|h0)
#define E0LO 18432u
#define E1HI 36864u        // 16 rows x 1024 (h0|h1)
#define E1LO 69632u
#define D0HI 0u            // 16 rows x 1024 (Weff|dWhh0)
#define D0LO 32768u
#define D1HI 65536u        // 16 rows x 1024 (dWih1|dWhh1)
#define D1LO 98304u

__device__ __forceinline__ float sigf(float x) { return 1.0f / (1.0f + expf(-x)); }

__device__ __forceinline__ u16 f2bf(float f) {   // RNE
    union { float f; unsigned u; } v; v.f = f;
    unsigned r = v.u + 0x7FFFu + ((v.u >> 16) & 1u);
    return (u16)(r >> 16);
}
__device__ __forceinline__ float bf2f(u16 h) {
    union { unsigned u; float f; } v; v.u = ((unsigned)h) << 16;
    return v.f;
}

// Producer-side stores: agent-scope write-through (visible at MALL, no dirty L2 lines).
__device__ __forceinline__ void llc_store64(u64* p, u64 v) {
    __hip_atomic_store(p, v, __ATOMIC_RELAXED, __HIP_MEMORY_SCOPE_AGENT);
}
__device__ __forceinline__ void llc_store32(u32* p, u32 v) {
    __hip_atomic_store(p, v, __ATOMIC_RELAXED, __HIP_MEMORY_SCOPE_AGENT);
}

// Grid barrier (round-7 proven): release = vmcnt(0) drain + sc1 flag store;
// acquire = poll + agent acquire fence (inv stale lines) + syncthreads.
__device__ __forceinline__ void gbar(int* flags, int w, int gen) {
    asm volatile("s_waitcnt vmcnt(0)" ::: "memory");
    __syncthreads();
    if (threadIdx.x == 0)
        __hip_atomic_store(flags + w * 16, gen, __ATOMIC_RELAXED, __HIP_MEMORY_SCOPE_AGENT);
    if (threadIdx.x < NWG) {
        while (__hip_atomic_load(flags + threadIdx.x * 16, __ATOMIC_RELAXED,
                                 __HIP_MEMORY_SCOPE_AGENT) < gen)
            __builtin_amdgcn_s_sleep(1);
    }
    __builtin_amdgcn_fence(__ATOMIC_ACQUIRE, "agent");
    __syncthreads();
}

// store one weight element as hi/lo bf16 into swizzled LDS planes
__device__ __forceinline__ void st_w(char* smem, unsigned hiB, unsigned loB, unsigned K2,
                                     unsigned m, unsigned k, float v) {
    u16 hh = f2bf(v);
    u16 ll = f2bf(v - bf2f(hh));
    unsigned off = (m * K2 + k * 2) ^ ((m & 7) << 4);
    *(u16*)(smem + hiB + off) = hh;
    *(u16*)(smem + loB + off) = ll;
}

// ---- deep-pipelined B loads: one group = 8 chunks x 32B/lane = 16 uint4 loads ----
__device__ __forceinline__ void load_g(uint4 (&buf)[8][2], const u32* __restrict__ plane,
                                       unsigned chunk0, unsigned loff) {
    #pragma unroll
    for (int i = 0; i < 8; ++i) {
        const uint4* p = (const uint4*)(plane + ((size_t)(chunk0 + i) << 12) + loff);
        buf[i][0] = p[0];
        buf[i][1] = p[1];
    }
}

// consume one group: unpack packed hi|lo u32s -> bf16x8 pair, 3 MFMAs per chunk.
__device__ __forceinline__ void cons_g(const uint4 (&buf)[8][2], const char* __restrict__ smem,
                                       unsigned hiB, unsigned loB, unsigned K2, unsigned k0,
                                       unsigned mm, unsigned qq, f32x4& acc0, f32x4& acc1) {
    const unsigned swz = (mm & 7) << 4;
    #pragma unroll
    for (int i = 0; i < 8; ++i) {
        const unsigned wb = mm * K2 + (k0 + (unsigned)i * 32 + qq * 8) * 2;
        bf16x8 ahi = *(const bf16x8*)(smem + hiB + (wb ^ swz));
        bf16x8 alo = *(const bf16x8*)(smem + loB + (wb ^ swz));
        u32 w0 = buf[i][0].x, w1 = buf[i][0].y, w2 = buf[i][0].z, w3 = buf[i][0].w;
        u32 w4 = buf[i][1].x, w5 = buf[i][1].y, w6 = buf[i][1].z, w7 = buf[i][1].w;
        bf16x8 bhi = { (short)(w0 & 0xFFFFu), (short)(w1 & 0xFFFFu),
                       (short)(w2 & 0xFFFFu), (short)(w3 & 0xFFFFu),
                       (short)(w4 & 0xFFFFu), (short)(w5 & 0xFFFFu),
                       (short)(w6 & 0xFFFFu), (short)(w7 & 0xFFFFu) };
        bf16x8 blo = { (short)(w0 >> 16), (short)(w1 >> 16),
                       (short)(w2 >> 16), (short)(w3 >> 16),
                       (short)(w4 >> 16), (short)(w5 >> 16),
                       (short)(w6 >> 16), (short)(w7 >> 16) };
        acc0 = __builtin_amdgcn_mfma_f32_16x16x32_bf16(ahi, bhi, acc0, 0, 0, 0);
        acc1 = __builtin_amdgcn_mfma_f32_16x16x32_bf16(ahi, blo, acc1, 0, 0, 0);
        acc1 = __builtin_amdgcn_mfma_f32_16x16x32_bf16(alo, bhi, acc1, 0, 0, 0);
    }
}

// encoder cell-A x-segment (K=64): B built on the fly from fp32 x rows
__device__ __forceinline__ void seg_x(
    const char* smem, unsigned hiB, unsigned loB, unsigned K2,
    const float* __restrict__ x, int t, unsigned bt, int lane, f32x4& acc0, f32x4& acc1) {
    const unsigned mm = lane & 15, qq = lane >> 4;
    const unsigned swz = (mm & 7) << 4;
    const float* xp = x + ((size_t)(bt + mm) * T_ + t) * 64 + qq * 8;
    #pragma unroll
    for (int i = 0; i < 2; ++i) {
        float4 f0 = *(const float4*)(xp + i * 32);
        float4 f1 = *(const float4*)(xp + i * 32 + 4);
        float fs[8] = { f0.x, f0.y, f0.z, f0.w, f1.x, f1.y, f1.z, f1.w };
        bf16x8 bhi, blo;
        #pragma unroll
        for (int j = 0; j < 8; ++j) {
            u16 hh = f2bf(fs[j]);
            bhi[j] = (short)hh;
            blo[j] = (short)f2bf(fs[j] - bf2f(hh));
        }
        unsigned wb = (mm * K2 + (qq * 8 + i * 32) * 2) ^ swz;
        bf16x8 ahi = *(const bf16x8*)(smem + hiB + wb);
        bf16x8 alo = *(const bf16x8*)(smem + loB + wb);
        acc0 = __builtin_amdgcn_mfma_f32_16x16x32_bf16(ahi, bhi, acc0, 0, 0, 0);
        acc1 = __builtin_amdgcn_mfma_f32_16x16x32_bf16(ahi, blo, acc1, 0, 0, 0);
        acc1 = __builtin_amdgcn_mfma_f32_16x16x32_bf16(alo, bhi, acc1, 0, 0, 0);
    }
}

// LSTM epilogue: lane owns 4 gate preacts of one (u,b); c in register; packed u32 h store.
__device__ __forceinline__ void epilogue_reg(f32x4 acc, const float* bz, int u, int b,
                                             float& cr, u32* hw) {
    float gi = sigf(acc[0] + bz[0]);
    float gf = sigf(acc[1] + bz[1]);
    float gt = tanhf(acc[2] + bz[2]);
    float go = sigf(acc[3] + bz[3]);
    float cn = gf * cr + gi * gt;
    cr = cn;
    float hv = go * tanhf(cn);
    u16 hh = f2bf(hv);
    u16 ll = f2bf(hv - bf2f(hh));
    unsigned hidx = (unsigned)(u >> 5) * 4096 + (unsigned)b * 32 + (u & 31);
    llc_store32(hw + hidx, (u32)hh | ((u32)ll << 16));
}

// out(t) = h1 @ linW.T + linb; WG w handles batch b=w, 512 threads = 64 f x 8 kq.
__device__ __forceinline__ void linear_out(const u32* __restrict__ h1p,
                                           const float* __restrict__ linW,
                                           const float* __restrict__ linb,
                                           float* __restrict__ out, int w, int tid, int t) {
    const int kq = tid & 7;
    const int f  = tid >> 3;     // 0..63
    float s = 0.f;
    #pragma unroll
    for (int c2 = 0; c2 < 2; ++c2) {
        const int ch = kq * 2 + c2;   // k chunk = k>>5
        const u64* ph = (const u64*)(h1p + (size_t)ch * 4096 + (size_t)w * 32);
        const float* wp = linW + (size_t)f * H_ + ch * 32;
        #pragma unroll
        for (int j = 0; j < 16; ++j) {     // each u64 = 2 packed elements
            u64 r = ph[j];
            float h0 = bf2f((u16)r) + bf2f((u16)(r >> 16));
            float h1 = bf2f((u16)(r >> 32)) + bf2f((u16)(r >> 48));
            s += h0 * wp[2 * j] + h1 * wp[2 * j + 1];
        }
    }
    s += __shfl_xor(s, 1);
    s += __shfl_xor(s, 2);
    s += __shfl_xor(s, 4);
    if (kq == 0)
        out[((size_t)w * T_ + (255 - t)) * 64 + f] = s + linb[f];
}

__global__ __launch_bounds__(NTHR, 2) void lstm_persist(
    const float* __restrict__ x,
    const float* __restrict__ eWih0, const float* __restrict__ eWhh0,
    const float* __restrict__ ebih0, const float* __restrict__ ebhh0,
    const float* __restrict__ eWih1, const float* __restrict__ eWhh1,
    const float* __restrict__ ebih1, const float* __restrict__ ebhh1,
    const float* __restrict__ dWih0, const float* __restrict__ dWhh0,
    const float* __restrict__ dbih0, const float* __restrict__ dbhh0,
    const float* __restrict__ dWih1, const float* __restrict__ dWhh1,
    const float* __restrict__ dbih1, const float* __restrict__ dbhh1,
    const float* __restrict__ linW,  const float* __restrict__ linb,
    float* __restrict__ out, char* __restrict__ wsb, int* __restrict__ flags) {
    extern __shared__ char smem[];
    const int w = blockIdx.x, tid = threadIdx.x;
    const int lane = tid & 63, wave = tid >> 6;
    const int gid = w * NTHR + tid;

    const int u_base = w * 4;                  // WG = u-quad
    const int u = u_base + (lane >> 4);
    const unsigned bt = (unsigned)wave * 16;   // wave = b-tile
    const int b = (int)bt + (lane & 15);
    const unsigned mm = (unsigned)(lane & 15), qq = (unsigned)(lane >> 4);
    const unsigned loff = (bt + mm) * 32 + qq * 8;   // u32 units into a chunk

    u32* h0p[2] = { (u32*)(wsb + O_H0), (u32*)(wsb + O_H0 + 262144u) };
    u32* h1p[2] = { (u32*)(wsb + O_H1), (u32*)(wsb + O_H1 + 262144u) };
    int gen = 0;

    // ================= INIT =================
    {   // zero all h planes (1 MB) via write-through stores
        u64* hz = (u64*)wsb;
        for (unsigned i = gid; i < 131072u; i += NWG * NTHR) llc_store64(hz + i, 0ULL);
    }
    // per-lane bias registers (incl. beff fold); c in registers
    float bzA[4], bzB[4], bzD0[4], bzD0b[4], bzD1[4];
    #pragma unroll
    for (int g = 0; g < 4; ++g) {
        const int gr = g * H_ + u;
        bzA[g] = ebih0[gr] + ebhh0[gr];
        bzB[g] = ebih1[gr] + ebhh1[gr];
        float d0 = dbih0[gr] + dbhh0[gr];
        bzD0[g] = d0;
        float s = 0.f;
        for (int f = 0; f < 64; ++f) s += dWih0[(size_t)gr * 64 + f] * linb[f];
        bzD0b[g] = d0 + s;
        bzD1[g] = dbih1[gr] + dbhh1[gr];
    }
    float c0r = 0.f, c1r = 0.f;

    // encoder weights -> swizzled LDS hi/lo (WG-local slice: 16 M-rows)
    for (int mr = 0; mr < 16; ++mr) {
        const int gr = (mr & 3) * H_ + u_base + (mr >> 2);
        for (int k = tid; k < 576; k += NTHR) {
            float v = (k < 64) ? eWih0[(size_t)gr * 64 + k] : eWhh0[(size_t)gr * H_ + (k - 64)];
            st_w(smem, E0HI, E0LO, 1152, mr, k, v);
        }
        for (int k = tid; k < 1024; k += NTHR) {
            float v = (k < 512) ? eWih1[(size_t)gr * H_ + k] : eWhh1[(size_t)gr * H_ + (k - 512)];
            st_w(smem, E1HI, E1LO, 2048, mr, k, v);
        }
    }
    gbar(flags, w, ++gen);

    uint4 X[8][2], Y[8][2];

    // ================= ENCODER: pipelined, 257 phases =================
    // phase p: cellA(t=p) || cellB(t=p-1). Both consume h0(p-1): B-fragments shared.
    for (int p = 0; p <= T_; ++p) {
        f32x4 a0 = {0,0,0,0}, a1 = {0,0,0,0}, e0 = {0,0,0,0}, e1 = {0,0,0,0};
        const u32* hA  = h0p[(p + 1) & 1];   // h0(p-1)
        const u32* hB1 = h1p[p & 1];         // h1(p-2)
        load_g(X, hA, 0, loff);
        load_g(Y, hA, 8, loff);
        if (p < T_) seg_x(smem, E0HI, E0LO, 1152, x, p, bt, lane, a0, a1);
        if (p < T_) cons_g(X, smem, E0HI, E0LO, 1152, 64,  mm, qq, a0, a1);
        if (p >= 1) cons_g(X, smem, E1HI, E1LO, 2048, 0,   mm, qq, e0, e1);
        if (p >= 1) load_g(X, hB1, 0, loff);
        if (p < T_) cons_g(Y, smem, E0HI, E0LO, 1152, 64 + 256, mm, qq, a0, a1);
        if (p >= 1) cons_g(Y, smem, E1HI, E1LO, 2048, 256, mm, qq, e0, e1);
        if (p >= 1) load_g(Y, hB1, 8, loff);
        if (p >= 1) cons_g(X, smem, E1HI, E1LO, 2048, 512, mm, qq, e0, e1);
        if (p >= 1) cons_g(Y, smem, E1HI, E1LO, 2048, 512 + 256, mm, qq, e0, e1);
        if (p < T_)  epilogue_reg(a0 + a1, bzA, u, b, c0r, h0p[p & 1]);
        if (p >= 1)  epilogue_reg(e0 + e1, bzB, u, b, c1r, h1p[(p + 1) & 1]);
        gbar(flags, w, ++gen);
    }

    // ================= TRANSITION: decoder weights -> LDS (WG-local) =================
    for (int mr = 0; mr < 16; ++mr) {
        const int gr = (mr & 3) * H_ + u_base + (mr >> 2);
        const float* wr = dWih0 + (size_t)gr * 64;
        const int c = tid;   // 512 cols, one per thread
        float s = 0.f;
        #pragma unroll 8
        for (int f = 0; f < 64; ++f) s += wr[f] * linW[(size_t)f * H_ + c];   // Weff = dWih0 @ linW
        st_w(smem, D0HI, D0LO, 2048, mr, c, s);
        st_w(smem, D0HI, D0LO, 2048, mr, 512 + c, dWhh0[(size_t)gr * H_ + c]);
        st_w(smem, D1HI, D1LO, 2048, mr, c,       dWih1[(size_t)gr * H_ + c]);
        st_w(smem, D1HI, D1LO, 2048, mr, 512 + c, dWhh1[(size_t)gr * H_ + c]);
    }
    __syncthreads();

    // ================= DECODER: 512 phases =================
    for (int t = 0; t < T_; ++t) {
        const int cp = t & 1, pp = (t + 1) & 1;
        {   // dec0(t): Weff.h1(t-1) (or x-projection at t=0) + dWhh0.h0(t-1)
            f32x4 a0 = {0,0,0,0}, a1 = {0,0,0,0};
            if (t > 0) {
                load_g(X, h1p[pp], 0, loff);
                load_g(Y, h1p[pp], 8, loff);
                cons_g(X, smem, D0HI, D0LO, 2048, 0, mm, qq, a0, a1);
                load_g(X, h0p[pp], 0, loff);
                cons_g(Y, smem, D0HI, D0LO, 2048, 256, mm, qq, a0, a1);
                load_g(Y, h0p[pp], 8, loff);
                cons_g(X, smem, D0HI, D0LO, 2048, 512, mm, qq, a0, a1);
                cons_g(Y, smem, D0HI, D0LO, 2048, 512 + 256, mm, qq, a0, a1);
            } else {
                load_g(X, h0p[pp], 0, loff);
                load_g(Y, h0p[pp], 8, loff);
                const float* xr = x + ((size_t)b * T_ + (T_ - 1)) * 64;
                #pragma unroll
                for (int g = 0; g < 4; ++g) {
                    const float* wr = dWih0 + (size_t)(g * H_ + u) * 64;
                    float s = 0.f;
                    for (int f = 0; f < 64; ++f) s += wr[f] * xr[f];
                    a0[g] = s;
                }
                cons_g(X, smem, D0HI, D0LO, 2048, 512, mm, qq, a0, a1);
                cons_g(Y, smem, D0HI, D0LO, 2048, 512 + 256, mm, qq, a0, a1);
            }
            epilogue_reg(a0 + a1, (t > 0) ? bzD0b : bzD0, u, b, c0r, h0p[cp]);
            if (t > 0) linear_out(h1p[pp], linW, linb, out, w, tid, t - 1);  // folded linear(t-1)
        }
        gbar(flags, w, ++gen);
        {   // dec1(t): dWih1.h0(t) + dWhh1.h1(t-1)
            f32x4 a0 = {0,0,0,0}, a1 = {0,0,0,0};
            load_g(X, h0p[cp], 0, loff);
            load_g(Y, h0p[cp], 8, loff);
            cons_g(X, smem, D1HI, D1LO, 2048, 0, mm, qq, a0, a1);
            load_g(X, h1p[pp], 0, loff);
            cons_g(Y, smem, D1HI, D1LO, 2048, 256, mm, qq, a0, a1);
            load_g(Y, h1p[pp], 8, loff);
            cons_g(X, smem, D1HI, D1LO, 2048, 512, mm, qq, a0, a1);
            cons_g(Y, smem, D1HI, D1LO, 2048, 512 + 256, mm, qq, a0, a1);
            epilogue_reg(a0 + a1, bzD1, u, b, c1r, h1p[cp]);
        }
        gbar(flags, w, ++gen);
    }
    // final output (t=255): h1(255) lives in parity plane 1
    linear_out(h1p[1], linW, linb, out, w, tid, 255);
}

extern "C" void kernel_launch(void* const* d_in, const int* in_sizes, int n_in,
                              void* d_out, int out_size, void* d_ws, size_t ws_size,
                              hipStream_t stream) {
    (void)in_sizes; (void)n_in; (void)out_size; (void)ws_size;
    const float* x     = (const float*)d_in[0];
    const float* eWih0 = (const float*)d_in[1];
    const float* eWhh0 = (const float*)d_in[2];
    const float* ebih0 = (const float*)d_in[3];
    const float* ebhh0 = (const float*)d_in[4];
    const float* eWih1 = (const float*)d_in[5];
    const float* eWhh1 = (const float*)d_in[6];
    const float* ebih1 = (const float*)d_in[7];
    const float* ebhh1 = (const float*)d_in[8];
    const float* dWih0 = (const float*)d_in[9];
    const float* dWhh0 = (const float*)d_in[10];
    const float* dbih0 = (const float*)d_in[11];
    const float* dbhh0 = (const float*)d_in[12];
    const float* dWih1 = (const float*)d_in[13];
    const float* dWhh1 = (const float*)d_in[14];
    const float* dbih1 = (const float*)d_in[15];
    const float* dbhh1 = (const float*)d_in[16];
    const float* linW  = (const float*)d_in[17];
    const float* linb  = (const float*)d_in[18];

    char* wsb  = (char*)d_ws;
    int* flags = (int*)(wsb + O_FLAG);

    static const int lds_bytes = 131072;
    hipFuncSetAttribute((const void*)lstm_persist,
                        hipFuncAttributeMaxDynamicSharedMemorySize, lds_bytes);

    hipMemsetAsync(flags, 0, NWG * 64, stream);

    hipLaunchKernelGGL(lstm_persist, dim3(NWG), dim3(NTHR), lds_bytes, stream,
                       x, eWih0, eWhh0, ebih0, ebhh0, eWih1, eWhh1, ebih1, ebhh1,
                       dWih0, dWhh0, dbih0, dbhh0, dWih1, dWhh1, dbih1, dbhh1,
                       linW, linb, (float*)d_out, wsb, flags);
}

// Round 9
// 18117.160 us; speedup vs baseline: 2.5845x; 1.0844x over previous
//
#include <hip/hip_runtime.h>
#include <math.h>

#define T_ 256
#define H_ 512
#define NWG 128
#define NTHR 512

typedef short bf16x8 __attribute__((ext_vector_type(8)));
typedef float f32x4 __attribute__((ext_vector_type(4)));
typedef unsigned short u16;
typedef unsigned int u32;
typedef unsigned long long u64;

// ---- ws byte offsets: h planes hold hi|lo<<16 packed u32, tiled [kchunk16][b128][k32] ----
#define O_H0   0u          // 2 parities x 262144 B
#define O_H1   524288u
#define O_BAR  1048576u    // single arrival counter

// ---- LDS byte offsets (131072 dynamic, weights only, hi/lo bf16 planes) ----
#define E0HI 0u            // 16 rows x 576  (x|h0)
#define E0LO 18432u
#define E1HI 36864u        // 16 rows x 1024 (h0|h1)
#define E1LO 69632u
#define D0HI 0u            // 16 rows x 1024 (Weff|dWhh0)
#define D0LO 32768u
#define D1HI 65536u        // 16 rows x 1024 (dWih1|dWhh1)
#define D1LO 98304u

__device__ __forceinline__ float sigf(float x) { return 1.0f / (1.0f + expf(-x)); }

__device__ __forceinline__ u16 f2bf(float f) {   // RNE
    union { float f; unsigned u; } v; v.f = f;
    unsigned r = v.u + 0x7FFFu + ((v.u >> 16) & 1u);
    return (u16)(r >> 16);
}
__device__ __forceinline__ float bf2f(u16 h) {
    union { unsigned u; float f; } v; v.u = ((unsigned)h) << 16;
    return v.f;
}

// Producer-side stores: agent-scope write-through (visible at MALL, no dirty L2 lines).
__device__ __forceinline__ void llc_store64(u64* p, u64 v) {
    __hip_atomic_store(p, v, __ATOMIC_RELAXED, __HIP_MEMORY_SCOPE_AGENT);
}
__device__ __forceinline__ void llc_store32(u32* p, u32 v) {
    __hip_atomic_store(p, v, __ATOMIC_RELAXED, __HIP_MEMORY_SCOPE_AGENT);
}

// Minimal-traffic grid barrier:
//  release: per-wave vmcnt(0) drains sc1 h-stores; __syncthreads collects the WG.
//  arrival: ONE atomicAdd per WG to a single MALL line.
//  poll:    ONE thread per WG, s_sleep backoff, single line.
//  acquire: ONE buffer_inv per WG (thread 0) -- covers the WG's CU L1 + XCD L2;
//           closing __syncthreads publishes to the other waves.
__device__ __forceinline__ void gbar(int* cnt, int gen) {
    asm volatile("s_waitcnt vmcnt(0)" ::: "memory");
    __syncthreads();
    if (threadIdx.x == 0) {
        __hip_atomic_fetch_add(cnt, 1, __ATOMIC_RELAXED, __HIP_MEMORY_SCOPE_AGENT);
        while (__hip_atomic_load(cnt, __ATOMIC_RELAXED, __HIP_MEMORY_SCOPE_AGENT) < gen * NWG)
            __builtin_amdgcn_s_sleep(2);
        __builtin_amdgcn_fence(__ATOMIC_ACQUIRE, "agent");   // single inv per WG
    }
    __syncthreads();
}

// store one weight element as hi/lo bf16 into swizzled LDS planes
__device__ __forceinline__ void st_w(char* smem, unsigned hiB, unsigned loB, unsigned K2,
                                     unsigned m, unsigned k, float v) {
    u16 hh = f2bf(v);
    u16 ll = f2bf(v - bf2f(hh));
    unsigned off = (m * K2 + k * 2) ^ ((m & 7) << 4);
    *(u16*)(smem + hiB + off) = hh;
    *(u16*)(smem + loB + off) = ll;
}

// ---- deep-pipelined B loads: one group = 8 chunks x 32B/lane = 16 uint4 loads ----
__device__ __forceinline__ void load_g(uint4 (&buf)[8][2], const u32* __restrict__ plane,
                                       unsigned chunk0, unsigned loff) {
    #pragma unroll
    for (int i = 0; i < 8; ++i) {
        const uint4* p = (const uint4*)(plane + ((size_t)(chunk0 + i) << 12) + loff);
        buf[i][0] = p[0];
        buf[i][1] = p[1];
    }
}

// consume one group: unpack packed hi|lo u32s -> bf16x8 pair, 3 MFMAs per chunk.
__device__ __forceinline__ void cons_g(const uint4 (&buf)[8][2], const char* __restrict__ smem,
                                       unsigned hiB, unsigned loB, unsigned K2, unsigned k0,
                                       unsigned mm, unsigned qq, f32x4& acc0, f32x4& acc1) {
    const unsigned swz = (mm & 7) << 4;
    #pragma unroll
    for (int i = 0; i < 8; ++i) {
        const unsigned wb = mm * K2 + (k0 + (unsigned)i * 32 + qq * 8) * 2;
        bf16x8 ahi = *(const bf16x8*)(smem + hiB + (wb ^ swz));
        bf16x8 alo = *(const bf16x8*)(smem + loB + (wb ^ swz));
        u32 w0 = buf[i][0].x, w1 = buf[i][0].y, w2 = buf[i][0].z, w3 = buf[i][0].w;
        u32 w4 = buf[i][1].x, w5 = buf[i][1].y, w6 = buf[i][1].z, w7 = buf[i][1].w;
        bf16x8 bhi = { (short)(w0 & 0xFFFFu), (short)(w1 & 0xFFFFu),
                       (short)(w2 & 0xFFFFu), (short)(w3 & 0xFFFFu),
                       (short)(w4 & 0xFFFFu), (short)(w5 & 0xFFFFu),
                       (short)(w6 & 0xFFFFu), (short)(w7 & 0xFFFFu) };
        bf16x8 blo = { (short)(w0 >> 16), (short)(w1 >> 16),
                       (short)(w2 >> 16), (short)(w3 >> 16),
                       (short)(w4 >> 16), (short)(w5 >> 16),
                       (short)(w6 >> 16), (short)(w7 >> 16) };
        acc0 = __builtin_amdgcn_mfma_f32_16x16x32_bf16(ahi, bhi, acc0, 0, 0, 0);
        acc1 = __builtin_amdgcn_mfma_f32_16x16x32_bf16(ahi, blo, acc1, 0, 0, 0);
        acc1 = __builtin_amdgcn_mfma_f32_16x16x32_bf16(alo, bhi, acc1, 0, 0, 0);
    }
}

// encoder cell-A x-segment (K=64): B built on the fly from fp32 x rows
__device__ __forceinline__ void seg_x(
    const char* smem, unsigned hiB, unsigned loB, unsigned K2,
    const float* __restrict__ x, int t, unsigned bt, int lane, f32x4& acc0, f32x4& acc1) {
    const unsigned mm = lane & 15, qq = lane >> 4;
    const unsigned swz = (mm & 7) << 4;
    const float* xp = x + ((size_t)(bt + mm) * T_ + t) * 64 + qq * 8;
    #pragma unroll
    for (int i = 0; i < 2; ++i) {
        float4 f0 = *(const float4*)(xp + i * 32);
        float4 f1 = *(const float4*)(xp + i * 32 + 4);
        float fs[8] = { f0.x, f0.y, f0.z, f0.w, f1.x, f1.y, f1.z, f1.w };
        bf16x8 bhi, blo;
        #pragma unroll
        for (int j = 0; j < 8; ++j) {
            u16 hh = f2bf(fs[j]);
            bhi[j] = (short)hh;
            blo[j] = (short)f2bf(fs[j] - bf2f(hh));
        }
        unsigned wb = (mm * K2 + (qq * 8 + i * 32) * 2) ^ swz;
        bf16x8 ahi = *(const bf16x8*)(smem + hiB + wb);
        bf16x8 alo = *(const bf16x8*)(smem + loB + wb);
        acc0 = __builtin_amdgcn_mfma_f32_16x16x32_bf16(ahi, bhi, acc0, 0, 0, 0);
        acc1 = __builtin_amdgcn_mfma_f32_16x16x32_bf16(ahi, blo, acc1, 0, 0, 0);
        acc1 = __builtin_amdgcn_mfma_f32_16x16x32_bf16(alo, bhi, acc1, 0, 0, 0);
    }
}

// LSTM epilogue: lane owns 4 gate preacts of one (u,b); c in register; packed u32 h store.
__device__ __forceinline__ void epilogue_reg(f32x4 acc, const float* bz, int u, int b,
                                             float& cr, u32* hw) {
    float gi = sigf(acc[0] + bz[0]);
    float gf = sigf(acc[1] + bz[1]);
    float gt = tanhf(acc[2] + bz[2]);
    float go = sigf(acc[3] + bz[3]);
    float cn = gf * cr + gi * gt;
    cr = cn;
    float hv = go * tanhf(cn);
    u16 hh = f2bf(hv);
    u16 ll = f2bf(hv - bf2f(hh));
    unsigned hidx = (unsigned)(u >> 5) * 4096 + (unsigned)b * 32 + (u & 31);
    llc_store32(hw + hidx, (u32)hh | ((u32)ll << 16));
}

// out(t) = h1 @ linW.T + linb; WG w handles batch b=w, 512 threads = 64 f x 8 kq.
__device__ __forceinline__ void linear_out(const u32* __restrict__ h1p,
                                           const float* __restrict__ linW,
                                           const float* __restrict__ linb,
                                           float* __restrict__ out, int w, int tid, int t) {
    const int kq = tid & 7;
    const int f  = tid >> 3;     // 0..63
    float s = 0.f;
    #pragma unroll
    for (int c2 = 0; c2 < 2; ++c2) {
        const int ch = kq * 2 + c2;   // k chunk = k>>5
        const u64* ph = (const u64*)(h1p + (size_t)ch * 4096 + (size_t)w * 32);
        const float* wp = linW + (size_t)f * H_ + ch * 32;
        #pragma unroll
        for (int j = 0; j < 16; ++j) {     // each u64 = 2 packed elements
            u64 r = ph[j];
            float h0 = bf2f((u16)r) + bf2f((u16)(r >> 16));
            float h1 = bf2f((u16)(r >> 32)) + bf2f((u16)(r >> 48));
            s += h0 * wp[2 * j] + h1 * wp[2 * j + 1];
        }
    }
    s += __shfl_xor(s, 1);
    s += __shfl_xor(s, 2);
    s += __shfl_xor(s, 4);
    if (kq == 0)
        out[((size_t)w * T_ + (255 - t)) * 64 + f] = s + linb[f];
}

__global__ __launch_bounds__(NTHR, 1) void lstm_persist(
    const float* __restrict__ x,
    const float* __restrict__ eWih0, const float* __restrict__ eWhh0,
    const float* __restrict__ ebih0, const float* __restrict__ ebhh0,
    const float* __restrict__ eWih1, const float* __restrict__ eWhh1,
    const float* __restrict__ ebih1, const float* __restrict__ ebhh1,
    const float* __restrict__ dWih0, const float* __restrict__ dWhh0,
    const float* __restrict__ dbih0, const float* __restrict__ dbhh0,
    const float* __restrict__ dWih1, const float* __restrict__ dWhh1,
    const float* __restrict__ dbih1, const float* __restrict__ dbhh1,
    const float* __restrict__ linW,  const float* __restrict__ linb,
    float* __restrict__ out, char* __restrict__ wsb, int* __restrict__ bar) {
    extern __shared__ char smem[];
    const int w = blockIdx.x, tid = threadIdx.x;
    const int lane = tid & 63, wave = tid >> 6;
    const int gid = w * NTHR + tid;

    const int u_base = w * 4;                  // WG = u-quad
    const int u = u_base + (lane >> 4);
    const unsigned bt = (unsigned)wave * 16;   // wave = b-tile
    const int b = (int)bt + (lane & 15);
    const unsigned mm = (unsigned)(lane & 15), qq = (unsigned)(lane >> 4);
    const unsigned loff = (bt + mm) * 32 + qq * 8;   // u32 units into a chunk

    u32* h0p[2] = { (u32*)(wsb + O_H0), (u32*)(wsb + O_H0 + 262144u) };
    u32* h1p[2] = { (u32*)(wsb + O_H1), (u32*)(wsb + O_H1 + 262144u) };
    int gen = 0;

    // ================= INIT =================
    {   // zero all h planes (1 MB) via write-through stores
        u64* hz = (u64*)wsb;
        for (unsigned i = gid; i < 131072u; i += NWG * NTHR) llc_store64(hz + i, 0ULL);
    }
    // per-lane bias registers (incl. beff fold); c in registers
    float bzA[4], bzB[4], bzD0[4], bzD0b[4], bzD1[4];
    #pragma unroll
    for (int g = 0; g < 4; ++g) {
        const int gr = g * H_ + u;
        bzA[g] = ebih0[gr] + ebhh0[gr];
        bzB[g] = ebih1[gr] + ebhh1[gr];
        float d0 = dbih0[gr] + dbhh0[gr];
        bzD0[g] = d0;
        float s = 0.f;
        for (int f = 0; f < 64; ++f) s += dWih0[(size_t)gr * 64 + f] * linb[f];
        bzD0b[g] = d0 + s;
        bzD1[g] = dbih1[gr] + dbhh1[gr];
    }
    float c0r = 0.f, c1r = 0.f;

    // encoder weights -> swizzled LDS hi/lo (WG-local slice: 16 M-rows)
    for (int mr = 0; mr < 16; ++mr) {
        const int gr = (mr & 3) * H_ + u_base + (mr >> 2);
        for (int k = tid; k < 576; k += NTHR) {
            float v = (k < 64) ? eWih0[(size_t)gr * 64 + k] : eWhh0[(size_t)gr * H_ + (k - 64)];
            st_w(smem, E0HI, E0LO, 1152, mr, k, v);
        }
        for (int k = tid; k < 1024; k += NTHR) {
            float v = (k < 512) ? eWih1[(size_t)gr * H_ + k] : eWhh1[(size_t)gr * H_ + (k - 512)];
            st_w(smem, E1HI, E1LO, 2048, mr, k, v);
        }
    }
    gbar(bar, ++gen);

    uint4 X[8][2], Y[8][2];

    // ================= ENCODER: pipelined, 257 phases =================
    // phase p: cellA(t=p) || cellB(t=p-1). Both consume h0(p-1): B-fragments shared.
    for (int p = 0; p <= T_; ++p) {
        f32x4 a0 = {0,0,0,0}, a1 = {0,0,0,0}, e0 = {0,0,0,0}, e1 = {0,0,0,0};
        const u32* hA  = h0p[(p + 1) & 1];   // h0(p-1)
        const u32* hB1 = h1p[p & 1];         // h1(p-2)
        load_g(X, hA, 0, loff);
        load_g(Y, hA, 8, loff);
        if (p < T_) seg_x(smem, E0HI, E0LO, 1152, x, p, bt, lane, a0, a1);
        if (p < T_) cons_g(X, smem, E0HI, E0LO, 1152, 64,  mm, qq, a0, a1);
        if (p >= 1) cons_g(X, smem, E1HI, E1LO, 2048, 0,   mm, qq, e0, e1);
        if (p >= 1) load_g(X, hB1, 0, loff);
        if (p < T_) cons_g(Y, smem, E0HI, E0LO, 1152, 64 + 256, mm, qq, a0, a1);
        if (p >= 1) cons_g(Y, smem, E1HI, E1LO, 2048, 256, mm, qq, e0, e1);
        if (p >= 1) load_g(Y, hB1, 8, loff);
        if (p >= 1) cons_g(X, smem, E1HI, E1LO, 2048, 512, mm, qq, e0, e1);
        if (p >= 1) cons_g(Y, smem, E1HI, E1LO, 2048, 512 + 256, mm, qq, e0, e1);
        if (p < T_)  epilogue_reg(a0 + a1, bzA, u, b, c0r, h0p[p & 1]);
        if (p >= 1)  epilogue_reg(e0 + e1, bzB, u, b, c1r, h1p[(p + 1) & 1]);
        gbar(bar, ++gen);
    }

    // ================= TRANSITION: decoder weights -> LDS (WG-local) =================
    for (int mr = 0; mr < 16; ++mr) {
        const int gr = (mr & 3) * H_ + u_base + (mr >> 2);
        const float* wr = dWih0 + (size_t)gr * 64;
        const int c = tid;   // 512 cols, one per thread
        float s = 0.f;
        #pragma unroll 8
        for (int f = 0; f < 64; ++f) s += wr[f] * linW[(size_t)f * H_ + c];   // Weff = dWih0 @ linW
        st_w(smem, D0HI, D0LO, 2048, mr, c, s);
        st_w(smem, D0HI, D0LO, 2048, mr, 512 + c, dWhh0[(size_t)gr * H_ + c]);
        st_w(smem, D1HI, D1LO, 2048, mr, c,       dWih1[(size_t)gr * H_ + c]);
        st_w(smem, D1HI, D1LO, 2048, mr, 512 + c, dWhh1[(size_t)gr * H_ + c]);
    }
    __syncthreads();

    // ================= DECODER: 512 phases =================
    for (int t = 0; t < T_; ++t) {
        const int cp = t & 1, pp = (t + 1) & 1;
        {   // dec0(t): Weff.h1(t-1) (or x-projection at t=0) + dWhh0.h0(t-1)
            f32x4 a0 = {0,0,0,0}, a1 = {0,0,0,0};
            if (t > 0) {
                load_g(X, h1p[pp], 0, loff);
                load_g(Y, h1p[pp], 8, loff);
                cons_g(X, smem, D0HI, D0LO, 2048, 0, mm, qq, a0, a1);
                load_g(X, h0p[pp], 0, loff);
                cons_g(Y, smem, D0HI, D0LO, 2048, 256, mm, qq, a0, a1);
                load_g(Y, h0p[pp], 8, loff);
                cons_g(X, smem, D0HI, D0LO, 2048, 512, mm, qq, a0, a1);
                cons_g(Y, smem, D0HI, D0LO, 2048, 512 + 256, mm, qq, a0, a1);
            } else {
                load_g(X, h0p[pp], 0, loff);
                load_g(Y, h0p[pp], 8, loff);
                const float* xr = x + ((size_t)b * T_ + (T_ - 1)) * 64;
                #pragma unroll
                for (int g = 0; g < 4; ++g) {
                    const float* wr = dWih0 + (size_t)(g * H_ + u) * 64;
                    float s = 0.f;
                    for (int f = 0; f < 64; ++f) s += wr[f] * xr[f];
                    a0[g] = s;
                }
                cons_g(X, smem, D0HI, D0LO, 2048, 512, mm, qq, a0, a1);
                cons_g(Y, smem, D0HI, D0LO, 2048, 512 + 256, mm, qq, a0, a1);
            }
            epilogue_reg(a0 + a1, (t > 0) ? bzD0b : bzD0, u, b, c0r, h0p[cp]);
            if (t > 0) linear_out(h1p[pp], linW, linb, out, w, tid, t - 1);  // folded linear(t-1)
        }
        gbar(bar, ++gen);
        {   // dec1(t): dWih1.h0(t) + dWhh1.h1(t-1)
            f32x4 a0 = {0,0,0,0}, a1 = {0,0,0,0};
            load_g(X, h0p[cp], 0, loff);
            load_g(Y, h0p[cp], 8, loff);
            cons_g(X, smem, D1HI, D1LO, 2048, 0, mm, qq, a0, a1);
            load_g(X, h1p[pp], 0, loff);
            cons_g(Y, smem, D1HI, D1LO, 2048, 256, mm, qq, a0, a1);
            load_g(Y, h1p[pp], 8, loff);
            cons_g(X, smem, D1HI, D1LO, 2048, 512, mm, qq, a0, a1);
            cons_g(Y, smem, D1HI, D1LO, 2048, 512 + 256, mm, qq, a0, a1);
            epilogue_reg(a0 + a1, bzD1, u, b, c1r, h1p[cp]);
        }
        gbar(bar, ++gen);
    }
    // final output (t=255): h1(255) lives in parity plane 1
    linear_out(h1p[1], linW, linb, out, w, tid, 255);
}

extern "C" void kernel_launch(void* const* d_in, const int* in_sizes, int n_in,
                              void* d_out, int out_size, void* d_ws, size_t ws_size,
                              hipStream_t stream) {
    (void)in_sizes; (void)n_in; (void)out_size; (void)ws_size;
    const float* x     = (const float*)d_in[0];
    const float* eWih0 = (const float*)d_in[1];
    const float* eWhh0 = (const float*)d_in[2];
    const float* ebih0 = (const float*)d_in[3];
    const float* ebhh0 = (const float*)d_in[4];
    const float* eWih1 = (const float*)d_in[5];
    const float* eWhh1 = (const float*)d_in[6];
    const float* ebih1 = (const float*)d_in[7];
    const float* ebhh1 = (const float*)d_in[8];
    const float* dWih0 = (const float*)d_in[9];
    const float* dWhh0 = (const float*)d_in[10];
    const float* dbih0 = (const float*)d_in[11];
    const float* dbhh0 = (const float*)d_in[12];
    const float* dWih1 = (const float*)d_in[13];
    const float* dWhh1 = (const float*)d_in[14];
    const float* dbih1 = (const float*)d_in[15];
    const float* dbhh1 = (const float*)d_in[16];
    const float* linW  = (const float*)d_in[17];
    const float* linb  = (const float*)d_in[18];

    char* wsb = (char*)d_ws;
    int* bar  = (int*)(wsb + O_BAR);

    static const int lds_bytes = 131072;
    hipFuncSetAttribute((const void*)lstm_persist,
                        hipFuncAttributeMaxDynamicSharedMemorySize, lds_bytes);

    hipMemsetAsync(bar, 0, 64, stream);

    hipLaunchKernelGGL(lstm_persist, dim3(NWG), dim3(NTHR), lds_bytes, stream,
                       x, eWih0, eWhh0, ebih0, ebhh0, eWih1, eWhh1, ebih1, ebhh1,
                       dWih0, dWhh0, dbih0, dbhh0, dWih1, dWhh1, dbih1, dbhh1,
                       linW, linb, (float*)d_out, wsb, bar);
}

// Round 10
// 18019.646 us; speedup vs baseline: 2.5985x; 1.0054x over previous
//
#include <hip/hip_runtime.h>
#include <math.h>

#define T_ 256
#define H_ 512
#define NWG 128
#define NTHR 512

typedef short bf16x8 __attribute__((ext_vector_type(8)));
typedef float f32x4 __attribute__((ext_vector_type(4)));
typedef unsigned short u16;
typedef unsigned int u32;
typedef unsigned long long u64;

// ---- ws byte offsets ----
// h planes: rings of 16 slots (slot = step & 15), each slot 256 KB
// packed u32 (hi|lo<<16), tiled [kchunk16][b128][k32].
#define O_H0R  0u           // 16 x 262144 = 4 MB
#define O_H1R  4194304u     // 16 x 262144 = 4 MB
#define O_BAR  8388608u     // single arrival counter

// ---- LDS byte offsets (131072 dynamic, weights only, hi/lo bf16 planes) ----
#define E0HI 0u            // 16 rows x 576  (x|h0)
#define E0LO 18432u
#define E1HI 36864u        // 16 rows x 1024 (h0|h1)
#define E1LO 69632u
#define D0HI 0u            // 16 rows x 1024 (Weff|dWhh0)
#define D0LO 32768u
#define D1HI 65536u        // 16 rows x 1024 (dWih1|dWhh1)
#define D1LO 98304u

__device__ __forceinline__ float sigf(float x) { return 1.0f / (1.0f + expf(-x)); }

__device__ __forceinline__ u16 f2bf(float f) {   // RNE
    union { float f; unsigned u; } v; v.f = f;
    unsigned r = v.u + 0x7FFFu + ((v.u >> 16) & 1u);
    return (u16)(r >> 16);
}
__device__ __forceinline__ float bf2f(u16 h) {
    union { unsigned u; float f; } v; v.u = ((unsigned)h) << 16;
    return v.f;
}

// Producer-side stores: agent-scope write-through (visible at MALL, no dirty L2 lines).
__device__ __forceinline__ void llc_store64(u64* p, u64 v) {
    __hip_atomic_store(p, v, __ATOMIC_RELAXED, __HIP_MEMORY_SCOPE_AGENT);
}
__device__ __forceinline__ void llc_store32(u32* p, u32 v) {
    __hip_atomic_store(p, v, __ATOMIC_RELAXED, __HIP_MEMORY_SCOPE_AGENT);
}

// Grid barrier. Release: vmcnt(0) drains sc1 h-stores; one atomicAdd/WG; one
// poller/WG with sleep backoff. Acquire fence (full L2 inv walk) ONLY when
// `inv` is set -- once per 16-step ring lap instead of every phase.
__device__ __forceinline__ void gbar(int* cnt, int gen, bool inv) {
    asm volatile("s_waitcnt vmcnt(0)" ::: "memory");
    __syncthreads();
    if (threadIdx.x == 0) {
        __hip_atomic_fetch_add(cnt, 1, __ATOMIC_RELAXED, __HIP_MEMORY_SCOPE_AGENT);
        while (__hip_atomic_load(cnt, __ATOMIC_RELAXED, __HIP_MEMORY_SCOPE_AGENT) < gen * NWG)
            __builtin_amdgcn_s_sleep(2);
        if (inv)
            __builtin_amdgcn_fence(__ATOMIC_ACQUIRE, "agent");   // lap-boundary inv
    }
    __syncthreads();
}

// store one weight element as hi/lo bf16 into swizzled LDS planes
__device__ __forceinline__ void st_w(char* smem, unsigned hiB, unsigned loB, unsigned K2,
                                     unsigned m, unsigned k, float v) {
    u16 hh = f2bf(v);
    u16 ll = f2bf(v - bf2f(hh));
    unsigned off = (m * K2 + k * 2) ^ ((m & 7) << 4);
    *(u16*)(smem + hiB + off) = hh;
    *(u16*)(smem + loB + off) = ll;
}

// ---- deep-pipelined B loads: one group = 8 chunks x 32B/lane = 16 uint4 loads ----
__device__ __forceinline__ void load_g(uint4 (&buf)[8][2], const u32* __restrict__ plane,
                                       unsigned chunk0, unsigned loff) {
    #pragma unroll
    for (int i = 0; i < 8; ++i) {
        const uint4* p = (const uint4*)(plane + ((size_t)(chunk0 + i) << 12) + loff);
        buf[i][0] = p[0];
        buf[i][1] = p[1];
    }
}

// consume one group: unpack packed hi|lo u32s -> bf16x8 pair, 3 MFMAs per chunk.
__device__ __forceinline__ void cons_g(const uint4 (&buf)[8][2], const char* __restrict__ smem,
                                       unsigned hiB, unsigned loB, unsigned K2, unsigned k0,
                                       unsigned mm, unsigned qq, f32x4& acc0, f32x4& acc1) {
    const unsigned swz = (mm & 7) << 4;
    #pragma unroll
    for (int i = 0; i < 8; ++i) {
        const unsigned wb = mm * K2 + (k0 + (unsigned)i * 32 + qq * 8) * 2;
        bf16x8 ahi = *(const bf16x8*)(smem + hiB + (wb ^ swz));
        bf16x8 alo = *(const bf16x8*)(smem + loB + (wb ^ swz));
        u32 w0 = buf[i][0].x, w1 = buf[i][0].y, w2 = buf[i][0].z, w3 = buf[i][0].w;
        u32 w4 = buf[i][1].x, w5 = buf[i][1].y, w6 = buf[i][1].z, w7 = buf[i][1].w;
        bf16x8 bhi = { (short)(w0 & 0xFFFFu), (short)(w1 & 0xFFFFu),
                       (short)(w2 & 0xFFFFu), (short)(w3 & 0xFFFFu),
                       (short)(w4 & 0xFFFFu), (short)(w5 & 0xFFFFu),
                       (short)(w6 & 0xFFFFu), (short)(w7 & 0xFFFFu) };
        bf16x8 blo = { (short)(w0 >> 16), (short)(w1 >> 16),
                       (short)(w2 >> 16), (short)(w3 >> 16),
                       (short)(w4 >> 16), (short)(w5 >> 16),
                       (short)(w6 >> 16), (short)(w7 >> 16) };
        acc0 = __builtin_amdgcn_mfma_f32_16x16x32_bf16(ahi, bhi, acc0, 0, 0, 0);
        acc1 = __builtin_amdgcn_mfma_f32_16x16x32_bf16(ahi, blo, acc1, 0, 0, 0);
        acc1 = __builtin_amdgcn_mfma_f32_16x16x32_bf16(alo, bhi, acc1, 0, 0, 0);
    }
}

// encoder cell-A x-segment (K=64): B built on the fly from fp32 x rows
__device__ __forceinline__ void seg_x(
    const char* smem, unsigned hiB, unsigned loB, unsigned K2,
    const float* __restrict__ x, int t, unsigned bt, int lane, f32x4& acc0, f32x4& acc1) {
    const unsigned mm = lane & 15, qq = lane >> 4;
    const unsigned swz = (mm & 7) << 4;
    const float* xp = x + ((size_t)(bt + mm) * T_ + t) * 64 + qq * 8;
    #pragma unroll
    for (int i = 0; i < 2; ++i) {
        float4 f0 = *(const float4*)(xp + i * 32);
        float4 f1 = *(const float4*)(xp + i * 32 + 4);
        float fs[8] = { f0.x, f0.y, f0.z, f0.w, f1.x, f1.y, f1.z, f1.w };
        bf16x8 bhi, blo;
        #pragma unroll
        for (int j = 0; j < 8; ++j) {
            u16 hh = f2bf(fs[j]);
            bhi[j] = (short)hh;
            blo[j] = (short)f2bf(fs[j] - bf2f(hh));
        }
        unsigned wb = (mm * K2 + (qq * 8 + i * 32) * 2) ^ swz;
        bf16x8 ahi = *(const bf16x8*)(smem + hiB + wb);
        bf16x8 alo = *(const bf16x8*)(smem + loB + wb);
        acc0 = __builtin_amdgcn_mfma_f32_16x16x32_bf16(ahi, bhi, acc0, 0, 0, 0);
        acc1 = __builtin_amdgcn_mfma_f32_16x16x32_bf16(ahi, blo, acc1, 0, 0, 0);
        acc1 = __builtin_amdgcn_mfma_f32_16x16x32_bf16(alo, bhi, acc1, 0, 0, 0);
    }
}

// LSTM epilogue: lane owns 4 gate preacts of one (u,b); c in register; packed u32 h store.
__device__ __forceinline__ void epilogue_reg(f32x4 acc, const float* bz, int u, int b,
                                             float& cr, u32* hw) {
    float gi = sigf(acc[0] + bz[0]);
    float gf = sigf(acc[1] + bz[1]);
    float gt = tanhf(acc[2] + bz[2]);
    float go = sigf(acc[3] + bz[3]);
    float cn = gf * cr + gi * gt;
    cr = cn;
    float hv = go * tanhf(cn);
    u16 hh = f2bf(hv);
    u16 ll = f2bf(hv - bf2f(hh));
    unsigned hidx = (unsigned)(u >> 5) * 4096 + (unsigned)b * 32 + (u & 31);
    llc_store32(hw + hidx, (u32)hh | ((u32)ll << 16));
}

// out(t) = h1 @ linW.T + linb; WG w handles batch b=w, 512 threads = 64 f x 8 kq.
__device__ __forceinline__ void linear_out(const u32* __restrict__ h1p,
                                           const float* __restrict__ linW,
                                           const float* __restrict__ linb,
                                           float* __restrict__ out, int w, int tid, int t) {
    const int kq = tid & 7;
    const int f  = tid >> 3;     // 0..63
    float s = 0.f;
    #pragma unroll
    for (int c2 = 0; c2 < 2; ++c2) {
        const int ch = kq * 2 + c2;   // k chunk = k>>5
        const u64* ph = (const u64*)(h1p + (size_t)ch * 4096 + (size_t)w * 32);
        const float* wp = linW + (size_t)f * H_ + ch * 32;
        #pragma unroll
        for (int j = 0; j < 16; ++j) {     // each u64 = 2 packed elements
            u64 r = ph[j];
            float h0 = bf2f((u16)r) + bf2f((u16)(r >> 16));
            float h1 = bf2f((u16)(r >> 32)) + bf2f((u16)(r >> 48));
            s += h0 * wp[2 * j] + h1 * wp[2 * j + 1];
        }
    }
    s += __shfl_xor(s, 1);
    s += __shfl_xor(s, 2);
    s += __shfl_xor(s, 4);
    if (kq == 0)
        out[((size_t)w * T_ + (255 - t)) * 64 + f] = s + linb[f];
}

__global__ __launch_bounds__(NTHR, 1) void lstm_persist(
    const float* __restrict__ x,
    const float* __restrict__ eWih0, const float* __restrict__ eWhh0,
    const float* __restrict__ ebih0, const float* __restrict__ ebhh0,
    const float* __restrict__ eWih1, const float* __restrict__ eWhh1,
    const float* __restrict__ ebih1, const float* __restrict__ ebhh1,
    const float* __restrict__ dWih0, const float* __restrict__ dWhh0,
    const float* __restrict__ dbih0, const float* __restrict__ dbhh0,
    const float* __restrict__ dWih1, const float* __restrict__ dWhh1,
    const float* __restrict__ dbih1, const float* __restrict__ dbhh1,
    const float* __restrict__ linW,  const float* __restrict__ linb,
    float* __restrict__ out, char* __restrict__ wsb, int* __restrict__ bar) {
    extern __shared__ char smem[];
    const int w = blockIdx.x, tid = threadIdx.x;
    const int lane = tid & 63, wave = tid >> 6;
    const int gid = w * NTHR + tid;

    const int u_base = w * 4;                  // WG = u-quad
    const int u = u_base + (lane >> 4);
    const unsigned bt = (unsigned)wave * 16;   // wave = b-tile
    const int b = (int)bt + (lane & 15);
    const unsigned mm = (unsigned)(lane & 15), qq = (unsigned)(lane >> 4);
    const unsigned loff = (bt + mm) * 32 + qq * 8;   // u32 units into a chunk

    // ring-slot accessors: slot = step & 15; step -1/-2 wrap to 15/14.
    #define H0S(t) ((u32*)(wsb + O_H0R + (unsigned)((t) & 15) * 262144u))
    #define H1S(t) ((u32*)(wsb + O_H1R + (unsigned)((t) & 15) * 262144u))
    int gen = 0;

    // ================= INIT =================
    {   // zero initial-state slots: h0 slot 15 (h0(-1)) and h1 slots 15,14 (h1(-1),h1(-2))
        u64* z0 = (u64*)(wsb + O_H0R + 15u * 262144u);
        u64* z1 = (u64*)(wsb + O_H1R + 14u * 262144u);   // slots 14 and 15 contiguous
        if (gid < 32768) z0[gid] = 0ULL;
        else             z1[gid - 32768] = 0ULL;         // covers 512 KB = slots 14+15
    }
    // per-lane bias registers (incl. beff fold); c in registers
    float bzA[4], bzB[4], bzD0[4], bzD0b[4], bzD1[4];
    #pragma unroll
    for (int g = 0; g < 4; ++g) {
        const int gr = g * H_ + u;
        bzA[g] = ebih0[gr] + ebhh0[gr];
        bzB[g] = ebih1[gr] + ebhh1[gr];
        float d0 = dbih0[gr] + dbhh0[gr];
        bzD0[g] = d0;
        float s = 0.f;
        for (int f = 0; f < 64; ++f) s += dWih0[(size_t)gr * 64 + f] * linb[f];
        bzD0b[g] = d0 + s;
        bzD1[g] = dbih1[gr] + dbhh1[gr];
    }
    float c0r = 0.f, c1r = 0.f;

    // encoder weights -> swizzled LDS hi/lo (WG-local slice: 16 M-rows)
    for (int mr = 0; mr < 16; ++mr) {
        const int gr = (mr & 3) * H_ + u_base + (mr >> 2);
        for (int k = tid; k < 576; k += NTHR) {
            float v = (k < 64) ? eWih0[(size_t)gr * 64 + k] : eWhh0[(size_t)gr * H_ + (k - 64)];
            st_w(smem, E0HI, E0LO, 1152, mr, k, v);
        }
        for (int k = tid; k < 1024; k += NTHR) {
            float v = (k < 512) ? eWih1[(size_t)gr * H_ + k] : eWhh1[(size_t)gr * H_ + (k - 512)];
            st_w(smem, E1HI, E1LO, 2048, mr, k, v);
        }
    }
    gbar(bar, ++gen, false);

    uint4 X[8][2], Y[8][2];

    // ================= ENCODER: pipelined, 257 phases =================
    // phase p: cellA(t=p) || cellB(t=p-1). Both consume h0(p-1): B-fragments shared.
    for (int p = 0; p <= T_; ++p) {
        f32x4 a0 = {0,0,0,0}, a1 = {0,0,0,0}, e0 = {0,0,0,0}, e1 = {0,0,0,0};
        const u32* hA  = H0S(p - 1);   // h0(p-1)
        const u32* hB1 = H1S(p - 2);   // h1(p-2)
        load_g(X, hA, 0, loff);
        load_g(Y, hA, 8, loff);
        if (p < T_) seg_x(smem, E0HI, E0LO, 1152, x, p, bt, lane, a0, a1);
        if (p < T_) cons_g(X, smem, E0HI, E0LO, 1152, 64,  mm, qq, a0, a1);
        if (p >= 1) cons_g(X, smem, E1HI, E1LO, 2048, 0,   mm, qq, e0, e1);
        if (p >= 1) load_g(X, hB1, 0, loff);
        if (p < T_) cons_g(Y, smem, E0HI, E0LO, 1152, 64 + 256, mm, qq, a0, a1);
        if (p >= 1) cons_g(Y, smem, E1HI, E1LO, 2048, 256, mm, qq, e0, e1);
        if (p >= 1) load_g(Y, hB1, 8, loff);
        if (p >= 1) cons_g(X, smem, E1HI, E1LO, 2048, 512, mm, qq, e0, e1);
        if (p >= 1) cons_g(Y, smem, E1HI, E1LO, 2048, 512 + 256, mm, qq, e0, e1);
        if (p < T_)  epilogue_reg(a0 + a1, bzA, u, b, c0r, H0S(p));
        if (p >= 1)  epilogue_reg(e0 + e1, bzB, u, b, c1r, H1S(p - 1));
        gbar(bar, ++gen, (p & 15) == 15);   // lap-boundary inv every 16 steps
    }

    // ================= TRANSITION: decoder weights -> LDS (WG-local) =================
    for (int mr = 0; mr < 16; ++mr) {
        const int gr = (mr & 3) * H_ + u_base + (mr >> 2);
        const float* wr = dWih0 + (size_t)gr * 64;
        const int c = tid;   // 512 cols, one per thread
        float s = 0.f;
        #pragma unroll 8
        for (int f = 0; f < 64; ++f) s += wr[f] * linW[(size_t)f * H_ + c];   // Weff = dWih0 @ linW
        st_w(smem, D0HI, D0LO, 2048, mr, c, s);
        st_w(smem, D0HI, D0LO, 2048, mr, 512 + c, dWhh0[(size_t)gr * H_ + c]);
        st_w(smem, D1HI, D1LO, 2048, mr, c,       dWih1[(size_t)gr * H_ + c]);
        st_w(smem, D1HI, D1LO, 2048, mr, 512 + c, dWhh1[(size_t)gr * H_ + c]);
    }
    __syncthreads();

    // ================= DECODER: 512 phases =================
    // decoder step t continues the global ring: dec h0(t)/h1(t) -> slot t&15.
    // dec h0(-1)/h1(-1) == encoder h0(255)/h1(255) == slot 15 -- seamless.
    for (int t = 0; t < T_; ++t) {
        {   // dec0(t): Weff.h1(t-1) (or x-projection at t=0) + dWhh0.h0(t-1)
            f32x4 a0 = {0,0,0,0}, a1 = {0,0,0,0};
            if (t > 0) {
                load_g(X, H1S(t - 1), 0, loff);
                load_g(Y, H1S(t - 1), 8, loff);
                cons_g(X, smem, D0HI, D0LO, 2048, 0, mm, qq, a0, a1);
                load_g(X, H0S(t - 1), 0, loff);
                cons_g(Y, smem, D0HI, D0LO, 2048, 256, mm, qq, a0, a1);
                load_g(Y, H0S(t - 1), 8, loff);
                cons_g(X, smem, D0HI, D0LO, 2048, 512, mm, qq, a0, a1);
                cons_g(Y, smem, D0HI, D0LO, 2048, 512 + 256, mm, qq, a0, a1);
            } else {
                load_g(X, H0S(t - 1), 0, loff);
                load_g(Y, H0S(t - 1), 8, loff);
                const float* xr = x + ((size_t)b * T_ + (T_ - 1)) * 64;
                #pragma unroll
                for (int g = 0; g < 4; ++g) {
                    const float* wr = dWih0 + (size_t)(g * H_ + u) * 64;
                    float s = 0.f;
                    for (int f = 0; f < 64; ++f) s += wr[f] * xr[f];
                    a0[g] = s;
                }
                cons_g(X, smem, D0HI, D0LO, 2048, 512, mm, qq, a0, a1);
                cons_g(Y, smem, D0HI, D0LO, 2048, 512 + 256, mm, qq, a0, a1);
            }
            epilogue_reg(a0 + a1, (t > 0) ? bzD0b : bzD0, u, b, c0r, H0S(t));
            if (t > 0) linear_out(H1S(t - 1), linW, linb, out, w, tid, t - 1);  // folded linear
        }
        gbar(bar, ++gen, false);
        {   // dec1(t): dWih1.h0(t) + dWhh1.h1(t-1)
            f32x4 a0 = {0,0,0,0}, a1 = {0,0,0,0};
            load_g(X, H0S(t), 0, loff);
            load_g(Y, H0S(t), 8, loff);
            cons_g(X, smem, D1HI, D1LO, 2048, 0, mm, qq, a0, a1);
            load_g(X, H1S(t - 1), 0, loff);
            cons_g(Y, smem, D1HI, D1LO, 2048, 256, mm, qq, a0, a1);
            load_g(Y, H1S(t - 1), 8, loff);
            cons_g(X, smem, D1HI, D1LO, 2048, 512, mm, qq, a0, a1);
            cons_g(Y, smem, D1HI, D1LO, 2048, 512 + 256, mm, qq, a0, a1);
            epilogue_reg(a0 + a1, bzD1, u, b, c1r, H1S(t));
        }
        gbar(bar, ++gen, (t & 15) == 15);   // lap-boundary inv every 16 steps
    }
    // final output (t=255): dec h1(255) -> slot 15
    linear_out(H1S(255), linW, linb, out, w, tid, 255);
}

extern "C" void kernel_launch(void* const* d_in, const int* in_sizes, int n_in,
                              void* d_out, int out_size, void* d_ws, size_t ws_size,
                              hipStream_t stream) {
    (void)in_sizes; (void)n_in; (void)out_size; (void)ws_size;
    const float* x     = (const float*)d_in[0];
    const float* eWih0 = (const float*)d_in[1];
    const float* eWhh0 = (const float*)d_in[2];
    const float* ebih0 = (const float*)d_in[3];
    const float* ebhh0 = (const float*)d_in[4];
    const float* eWih1 = (const float*)d_in[5];
    const float* eWhh1 = (const float*)d_in[6];
    const float* ebih1 = (const float*)d_in[7];
    const float* ebhh1 = (const float*)d_in[8];
    const float* dWih0 = (const float*)d_in[9];
    const float* dWhh0 = (const float*)d_in[10];
    const float* dbih0 = (const float*)d_in[11];
    const float* dbhh0 = (const float*)d_in[12];
    const float* dWih1 = (const float*)d_in[13];
    const float* dWhh1 = (const float*)d_in[14];
    const float* dbih1 = (const float*)d_in[15];
    const float* dbhh1 = (const float*)d_in[16];
    const float* linW  = (const float*)d_in[17];
    const float* linb  = (const float*)d_in[18];

    char* wsb = (char*)d_ws;
    int* bar  = (int*)(wsb + O_BAR);

    static const int lds_bytes = 131072;
    hipFuncSetAttribute((const void*)lstm_persist,
                        hipFuncAttributeMaxDynamicSharedMemorySize, lds_bytes);

    hipMemsetAsync(bar, 0, 64, stream);

    hipLaunchKernelGGL(lstm_persist, dim3(NWG), dim3(NTHR), lds_bytes, stream,
                       x, eWih0, eWhh0, ebih0, ebhh0, eWih1, eWhh1, ebih1, ebhh1,
                       dWih0, dWhh0, dbih0, dbhh0, dWih1, dWhh1, dbih1, dbhh1,
                       linW, linb, (float*)d_out, wsb, bar);
}

// Round 11
// 9078.807 us; speedup vs baseline: 5.1575x; 1.9848x over previous
//
#include <hip/hip_runtime.h>
#include <math.h>

#define T_ 256
#define H_ 512
#define NWG 128
#define NTHR 512

typedef _Float16 half8 __attribute__((ext_vector_type(8)));
typedef float f32x4 __attribute__((ext_vector_type(4)));
typedef unsigned short u16;
typedef unsigned int u32;
typedef unsigned long long u64;

// ---- ws byte offsets ----
// h planes: fp16, rings of 16 slots (slot = step & 15), each slot 128 KB,
// tiled [kchunk16][b128][k32] f16.
#define O_H0R  0u           // 16 x 131072 = 2 MB
#define O_H1R  2097152u     // 16 x 131072 = 2 MB
#define O_BAR  4194304u     // single arrival counter

// ---- LDS byte offsets (131072 dynamic, weights only, f16 hi/lo planes) ----
// (byte layout identical to bf16 era: 2 B/elem)
#define E0HI 0u            // 16 rows x 576  (x|h0), row 1152 B
#define E0LO 18432u
#define E1HI 36864u        // 16 rows x 1024 (h0|h1), row 2048 B
#define E1LO 69632u
#define D0HI 0u            // 16 rows x 1024 (Weff|dWhh0)
#define D0LO 32768u
#define D1HI 65536u        // 16 rows x 1024 (dWih1|dWhh1)
#define D1LO 98304u

__device__ __forceinline__ float sigf(float x) { return 1.0f / (1.0f + expf(-x)); }

__device__ __forceinline__ u16 f2h_bits(float f) {
    _Float16 h = (_Float16)f;
    return __builtin_bit_cast(u16, h);
}
__device__ __forceinline__ float h2f(u16 x) {
    return (float)__builtin_bit_cast(_Float16, x);
}

// Producer-side stores: agent-scope write-through (visible at MALL, no dirty L2 lines).
__device__ __forceinline__ void llc_store64(u64* p, u64 v) {
    __hip_atomic_store(p, v, __ATOMIC_RELAXED, __HIP_MEMORY_SCOPE_AGENT);
}
__device__ __forceinline__ void llc_store32(u32* p, u32 v) {
    __hip_atomic_store(p, v, __ATOMIC_RELAXED, __HIP_MEMORY_SCOPE_AGENT);
}

// Grid barrier (round-9/10 proven): vmcnt(0) drain; one atomicAdd + one poller
// per WG; acquire fence (L2 inv) only at 16-step ring lap boundaries.
__device__ __forceinline__ void gbar(int* cnt, int gen, bool inv) {
    asm volatile("s_waitcnt vmcnt(0)" ::: "memory");
    __syncthreads();
    if (threadIdx.x == 0) {
        __hip_atomic_fetch_add(cnt, 1, __ATOMIC_RELAXED, __HIP_MEMORY_SCOPE_AGENT);
        while (__hip_atomic_load(cnt, __ATOMIC_RELAXED, __HIP_MEMORY_SCOPE_AGENT) < gen * NWG)
            __builtin_amdgcn_s_sleep(2);
        if (inv)
            __builtin_amdgcn_fence(__ATOMIC_ACQUIRE, "agent");
    }
    __syncthreads();
}

// store one weight element as f16 hi/lo into swizzled LDS planes
__device__ __forceinline__ void st_w(char* smem, unsigned hiB, unsigned loB, unsigned K2,
                                     unsigned m, unsigned k, float v) {
    _Float16 hh = (_Float16)v;
    _Float16 ll = (_Float16)(v - (float)hh);
    unsigned off = (m * K2 + k * 2) ^ ((m & 7) << 4);
    *(u16*)(smem + hiB + off) = __builtin_bit_cast(u16, hh);
    *(u16*)(smem + loB + off) = __builtin_bit_cast(u16, ll);
}

// Issue ALL 16 chunk-loads of one f16 plane (one uint4 = 8 f16 per lane per chunk).
__device__ __forceinline__ void load_plane(uint4 (&buf)[16], const u32* __restrict__ plane,
                                           unsigned loff) {
    #pragma unroll
    for (int i = 0; i < 16; ++i)
        buf[i] = *(const uint4*)(plane + (size_t)i * 2048 + loff);
}

// Consume one plane: B direct from registers (no unpack), A from swizzled LDS
// f16 hi/lo -> 2 MFMAs per 32-k chunk.
__device__ __forceinline__ void cons_plane(const uint4 (&buf)[16], const char* __restrict__ smem,
                                           unsigned hiB, unsigned loB, unsigned K2, unsigned wk0,
                                           unsigned mm, unsigned qq, f32x4& acc0, f32x4& acc1) {
    const unsigned swz = (mm & 7) << 4;
    #pragma unroll
    for (int i = 0; i < 16; ++i) {
        const unsigned wb = mm * K2 + (wk0 + (unsigned)i * 32 + qq * 8) * 2;
        half8 ahi = *(const half8*)(smem + hiB + (wb ^ swz));
        half8 alo = *(const half8*)(smem + loB + (wb ^ swz));
        half8 bv  = __builtin_bit_cast(half8, buf[i]);
        acc0 = __builtin_amdgcn_mfma_f32_16x16x32_f16(ahi, bv, acc0, 0, 0, 0);
        acc1 = __builtin_amdgcn_mfma_f32_16x16x32_f16(alo, bv, acc1, 0, 0, 0);
    }
}

// encoder cell-A x-segment (K=64): B built on the fly from fp32 x rows
__device__ __forceinline__ void seg_x(
    const char* smem, unsigned hiB, unsigned loB, unsigned K2,
    const float* __restrict__ x, int t, unsigned bt, int lane, f32x4& acc0, f32x4& acc1) {
    const unsigned mm = lane & 15, qq = lane >> 4;
    const unsigned swz = (mm & 7) << 4;
    const float* xp = x + ((size_t)(bt + mm) * T_ + t) * 64 + qq * 8;
    #pragma unroll
    for (int i = 0; i < 2; ++i) {
        float4 f0 = *(const float4*)(xp + i * 32);
        float4 f1 = *(const float4*)(xp + i * 32 + 4);
        float fs[8] = { f0.x, f0.y, f0.z, f0.w, f1.x, f1.y, f1.z, f1.w };
        half8 bv;
        #pragma unroll
        for (int j = 0; j < 8; ++j) bv[j] = (_Float16)fs[j];
        unsigned wb = (mm * K2 + (qq * 8 + i * 32) * 2) ^ swz;
        half8 ahi = *(const half8*)(smem + hiB + wb);
        half8 alo = *(const half8*)(smem + loB + wb);
        acc0 = __builtin_amdgcn_mfma_f32_16x16x32_f16(ahi, bv, acc0, 0, 0, 0);
        acc1 = __builtin_amdgcn_mfma_f32_16x16x32_f16(alo, bv, acc1, 0, 0, 0);
    }
}

// LSTM epilogue: lane owns 4 gate preacts of one (u,b); c in register.
// h value -> f16; pair-pack with lane^16 (u and u+1) -> one u32 sc1 store per pair.
__device__ __forceinline__ void epilogue_reg(f32x4 acc, const float* bz, int u, int b,
                                             float& cr, u32* hw, int lane) {
    float gi = sigf(acc[0] + bz[0]);
    float gf = sigf(acc[1] + bz[1]);
    float gt = tanhf(acc[2] + bz[2]);
    float go = sigf(acc[3] + bz[3]);
    float cn = gf * cr + gi * gt;
    cr = cn;
    float hv = go * tanhf(cn);
    u16 mybits = f2h_bits(hv);
    int other = __shfl_xor((int)(u32)mybits, 16);
    if (((lane >> 4) & 1) == 0) {   // even-u member of the pair stores
        u32 pk = (u32)mybits | (((u32)other & 0xFFFFu) << 16);
        unsigned idx = (unsigned)(u >> 5) * 2048 + (unsigned)b * 16 + ((unsigned)(u & 31) >> 1);
        llc_store32(hw + idx, pk);
    }
}

// out(t) = h1 @ linW.T + linb; WG w handles batch b=w, 512 threads = 64 f x 8 kq.
__device__ __forceinline__ void linear_out(const u32* __restrict__ h1p,
                                           const float* __restrict__ linW,
                                           const float* __restrict__ linb,
                                           float* __restrict__ out, int w, int tid, int t) {
    const int kq = tid & 7;
    const int f  = tid >> 3;     // 0..63
    float s = 0.f;
    #pragma unroll
    for (int c2 = 0; c2 < 2; ++c2) {
        const int ch = kq * 2 + c2;   // k chunk = k>>5
        const u64* ph = (const u64*)h1p + (size_t)ch * 1024 + (size_t)w * 8;
        const float* wp = linW + (size_t)f * H_ + ch * 32;
        #pragma unroll
        for (int j = 0; j < 8; ++j) {     // each u64 = 4 f16
            u64 r = ph[j];
            s += h2f((u16)r)         * wp[4 * j + 0];
            s += h2f((u16)(r >> 16)) * wp[4 * j + 1];
            s += h2f((u16)(r >> 32)) * wp[4 * j + 2];
            s += h2f((u16)(r >> 48)) * wp[4 * j + 3];
        }
    }
    s += __shfl_xor(s, 1);
    s += __shfl_xor(s, 2);
    s += __shfl_xor(s, 4);
    if (kq == 0)
        out[((size_t)w * T_ + (255 - t)) * 64 + f] = s + linb[f];
}

__global__ __launch_bounds__(NTHR, 1) void lstm_persist(
    const float* __restrict__ x,
    const float* __restrict__ eWih0, const float* __restrict__ eWhh0,
    const float* __restrict__ ebih0, const float* __restrict__ ebhh0,
    const float* __restrict__ eWih1, const float* __restrict__ eWhh1,
    const float* __restrict__ ebih1, const float* __restrict__ ebhh1,
    const float* __restrict__ dWih0, const float* __restrict__ dWhh0,
    const float* __restrict__ dbih0, const float* __restrict__ dbhh0,
    const float* __restrict__ dWih1, const float* __restrict__ dWhh1,
    const float* __restrict__ dbih1, const float* __restrict__ dbhh1,
    const float* __restrict__ linW,  const float* __restrict__ linb,
    float* __restrict__ out, char* __restrict__ wsb, int* __restrict__ bar) {
    extern __shared__ char smem[];
    const int w = blockIdx.x, tid = threadIdx.x;
    const int lane = tid & 63, wave = tid >> 6;
    const int gid = w * NTHR + tid;

    const int u_base = w * 4;                  // WG = u-quad
    const int u = u_base + (lane >> 4);
    const unsigned bt = (unsigned)wave * 16;   // wave = b-tile
    const int b = (int)bt + (lane & 15);
    const unsigned mm = (unsigned)(lane & 15), qq = (unsigned)(lane >> 4);
    const unsigned loff = (bt + mm) * 16 + qq * 4;   // u32 units into an 8 KB chunk

    // ring-slot accessors: slot = step & 15; step -1/-2 wrap to 15/14.
    #define H0S(t) ((u32*)(wsb + O_H0R + (unsigned)((t) & 15) * 131072u))
    #define H1S(t) ((u32*)(wsb + O_H1R + (unsigned)((t) & 15) * 131072u))
    int gen = 0;

    // ================= INIT =================
    {   // zero initial-state slots: h0 slot 15; h1 slots 14,15 (128 KB each)
        u64* z0 = (u64*)(wsb + O_H0R + 15u * 131072u);
        u64* z1 = (u64*)(wsb + O_H1R + 14u * 131072u);
        if (gid < 16384)       z0[gid] = 0ULL;
        else if (gid < 49152)  z1[gid - 16384] = 0ULL;
    }
    // per-lane bias registers (incl. beff fold); c in registers
    float bzA[4], bzB[4], bzD0[4], bzD0b[4], bzD1[4];
    #pragma unroll
    for (int g = 0; g < 4; ++g) {
        const int gr = g * H_ + u;
        bzA[g] = ebih0[gr] + ebhh0[gr];
        bzB[g] = ebih1[gr] + ebhh1[gr];
        float d0 = dbih0[gr] + dbhh0[gr];
        bzD0[g] = d0;
        float s = 0.f;
        for (int f = 0; f < 64; ++f) s += dWih0[(size_t)gr * 64 + f] * linb[f];
        bzD0b[g] = d0 + s;
        bzD1[g] = dbih1[gr] + dbhh1[gr];
    }
    float c0r = 0.f, c1r = 0.f;

    // encoder weights -> swizzled LDS f16 hi/lo (WG-local slice: 16 M-rows)
    for (int mr = 0; mr < 16; ++mr) {
        const int gr = (mr & 3) * H_ + u_base + (mr >> 2);
        for (int k = tid; k < 576; k += NTHR) {
            float v = (k < 64) ? eWih0[(size_t)gr * 64 + k] : eWhh0[(size_t)gr * H_ + (k - 64)];
            st_w(smem, E0HI, E0LO, 1152, mr, k, v);
        }
        for (int k = tid; k < 1024; k += NTHR) {
            float v = (k < 512) ? eWih1[(size_t)gr * H_ + k] : eWhh1[(size_t)gr * H_ + (k - 512)];
            st_w(smem, E1HI, E1LO, 2048, mr, k, v);
        }
    }
    gbar(bar, ++gen, false);

    uint4 P[16], Q[16];

    // ================= ENCODER: pipelined, 257 phases =================
    // phase p: cellA(t=p) || cellB(t=p-1). Both consume h0(p-1): plane P shared.
    for (int p = 0; p <= T_; ++p) {
        f32x4 a0 = {0,0,0,0}, a1 = {0,0,0,0}, e0 = {0,0,0,0}, e1 = {0,0,0,0};
        load_plane(P, H0S(p - 1), loff);    // h0(p-1)
        load_plane(Q, H1S(p - 2), loff);    // h1(p-2)
        if (p < T_) seg_x(smem, E0HI, E0LO, 1152, x, p, bt, lane, a0, a1);
        if (p < T_) cons_plane(P, smem, E0HI, E0LO, 1152, 64, mm, qq, a0, a1);
        if (p >= 1) cons_plane(P, smem, E1HI, E1LO, 2048, 0,   mm, qq, e0, e1);
        if (p >= 1) cons_plane(Q, smem, E1HI, E1LO, 2048, 512, mm, qq, e0, e1);
        if (p < T_)  epilogue_reg(a0 + a1, bzA, u, b, c0r, H0S(p), lane);
        if (p >= 1)  epilogue_reg(e0 + e1, bzB, u, b, c1r, H1S(p - 1), lane);
        gbar(bar, ++gen, (p & 15) == 15);
    }

    // ================= TRANSITION: decoder weights -> LDS (WG-local) =================
    for (int mr = 0; mr < 16; ++mr) {
        const int gr = (mr & 3) * H_ + u_base + (mr >> 2);
        const float* wr = dWih0 + (size_t)gr * 64;
        const int c = tid;   // 512 cols, one per thread
        float s = 0.f;
        #pragma unroll 8
        for (int f = 0; f < 64; ++f) s += wr[f] * linW[(size_t)f * H_ + c];   // Weff = dWih0 @ linW
        st_w(smem, D0HI, D0LO, 2048, mr, c, s);
        st_w(smem, D0HI, D0LO, 2048, mr, 512 + c, dWhh0[(size_t)gr * H_ + c]);
        st_w(smem, D1HI, D1LO, 2048, mr, c,       dWih1[(size_t)gr * H_ + c]);
        st_w(smem, D1HI, D1LO, 2048, mr, 512 + c, dWhh1[(size_t)gr * H_ + c]);
    }
    __syncthreads();

    // ================= DECODER: 512 phases =================
    // decoder step t continues the global ring; dec h0(-1)/h1(-1) == slot 15.
    for (int t = 0; t < T_; ++t) {
        {   // dec0(t): Weff.h1(t-1) (or x-projection at t=0) + dWhh0.h0(t-1)
            f32x4 a0 = {0,0,0,0}, a1 = {0,0,0,0};
            if (t > 0) {
                load_plane(P, H1S(t - 1), loff);
                load_plane(Q, H0S(t - 1), loff);
                cons_plane(P, smem, D0HI, D0LO, 2048, 0,   mm, qq, a0, a1);
                cons_plane(Q, smem, D0HI, D0LO, 2048, 512, mm, qq, a0, a1);
            } else {
                load_plane(Q, H0S(t - 1), loff);
                const float* xr = x + ((size_t)b * T_ + (T_ - 1)) * 64;
                #pragma unroll
                for (int g = 0; g < 4; ++g) {
                    const float* wr = dWih0 + (size_t)(g * H_ + u) * 64;
                    float s = 0.f;
                    for (int f = 0; f < 64; ++f) s += wr[f] * xr[f];
                    a0[g] = s;
                }
                cons_plane(Q, smem, D0HI, D0LO, 2048, 512, mm, qq, a0, a1);
            }
            epilogue_reg(a0 + a1, (t > 0) ? bzD0b : bzD0, u, b, c0r, H0S(t), lane);
            if (t > 0) linear_out(H1S(t - 1), linW, linb, out, w, tid, t - 1);  // folded linear
        }
        gbar(bar, ++gen, false);
        {   // dec1(t): dWih1.h0(t) + dWhh1.h1(t-1)
            f32x4 a0 = {0,0,0,0}, a1 = {0,0,0,0};
            load_plane(P, H0S(t), loff);
            load_plane(Q, H1S(t - 1), loff);
            cons_plane(P, smem, D1HI, D1LO, 2048, 0,   mm, qq, a0, a1);
            cons_plane(Q, smem, D1HI, D1LO, 2048, 512, mm, qq, a0, a1);
            epilogue_reg(a0 + a1, bzD1, u, b, c1r, H1S(t), lane);
        }
        gbar(bar, ++gen, (t & 15) == 15);
    }
    // final output (t=255): dec h1(255) -> slot 15
    linear_out(H1S(255), linW, linb, out, w, tid, 255);
}

extern "C" void kernel_launch(void* const* d_in, const int* in_sizes, int n_in,
                              void* d_out, int out_size, void* d_ws, size_t ws_size,
                              hipStream_t stream) {
    (void)in_sizes; (void)n_in; (void)out_size; (void)ws_size;
    const float* x     = (const float*)d_in[0];
    const float* eWih0 = (const float*)d_in[1];
    const float* eWhh0 = (const float*)d_in[2];
    const float* ebih0 = (const float*)d_in[3];
    const float* ebhh0 = (const float*)d_in[4];
    const float* eWih1 = (const float*)d_in[5];
    const float* eWhh1 = (const float*)d_in[6];
    const float* ebih1 = (const float*)d_in[7];
    const float* ebhh1 = (const float*)d_in[8];
    const float* dWih0 = (const float*)d_in[9];
    const float* dWhh0 = (const float*)d_in[10];
    const float* dbih0 = (const float*)d_in[11];
    const float* dbhh0 = (const float*)d_in[12];
    const float* dWih1 = (const float*)d_in[13];
    const float* dWhh1 = (const float*)d_in[14];
    const float* dbih1 = (const float*)d_in[15];
    const float* dbhh1 = (const float*)d_in[16];
    const float* linW  = (const float*)d_in[17];
    const float* linb  = (const float*)d_in[18];

    char* wsb = (char*)d_ws;
    int* bar  = (int*)(wsb + O_BAR);

    static const int lds_bytes = 131072;
    hipFuncSetAttribute((const void*)lstm_persist,
                        hipFuncAttributeMaxDynamicSharedMemorySize, lds_bytes);

    hipMemsetAsync(bar, 0, 64, stream);

    hipLaunchKernelGGL(lstm_persist, dim3(NWG), dim3(NTHR), lds_bytes, stream,
                       x, eWih0, eWhh0, ebih0, ebhh0, eWih1, eWhh1, ebih1, ebhh1,
                       dWih0, dWhh0, dbih0, dbhh0, dWih1, dWhh1, dbih1, dbhh1,
                       linW, linb, (float*)d_out, wsb, bar);
}

// Round 12
// 5571.499 us; speedup vs baseline: 8.4041x; 1.6295x over previous
//
#include <hip/hip_runtime.h>
#include <math.h>

#define T_ 256
#define H_ 512
#define NWG 256
#define NTHR 256

typedef _Float16 half8 __attribute__((ext_vector_type(8)));
typedef float f32x4 __attribute__((ext_vector_type(4)));
typedef unsigned short u16;
typedef unsigned int u32;
typedef unsigned long long u64;

// ---- ws byte offsets ----
// h planes: fp16, rings of 16 slots (slot = step & 15), each slot 128 KB,
// tiled [kchunk16][b128][k32] f16.
#define O_H0R  0u           // 16 x 131072 = 2 MB
#define O_H1R  2097152u     // 16 x 131072 = 2 MB
#define O_BAR  4194304u     // tree barrier: 8 group counters (128B apart) + root

// ---- LDS byte offsets (131072 dynamic, weights only, f16 hi/lo planes) ----
#define E0HI 0u            // 16 rows x 576  (x|h0), row 1152 B
#define E0LO 18432u
#define E1HI 36864u        // 16 rows x 1024 (h0|h1), row 2048 B
#define E1LO 69632u
#define D0HI 0u            // 16 rows x 1024 (Weff|dWhh0)
#define D0LO 32768u
#define D1HI 65536u        // 16 rows x 1024 (dWih1|dWhh1)
#define D1LO 98304u

__device__ __forceinline__ float sigf(float x) { return 1.0f / (1.0f + expf(-x)); }

__device__ __forceinline__ u16 f2h_bits(float f) {
    _Float16 h = (_Float16)f;
    return __builtin_bit_cast(u16, h);
}
__device__ __forceinline__ float h2f(u16 x) {
    return (float)__builtin_bit_cast(_Float16, x);
}

// Producer-side stores: agent-scope write-through (visible at MALL, no dirty L2 lines).
__device__ __forceinline__ void llc_store64(u64* p, u64 v) {
    __hip_atomic_store(p, v, __ATOMIC_RELAXED, __HIP_MEMORY_SCOPE_AGENT);
}
__device__ __forceinline__ void llc_store32(u32* p, u32 v) {
    __hip_atomic_store(p, v, __ATOMIC_RELAXED, __HIP_MEMORY_SCOPE_AGENT);
}

// Tree grid barrier for 256 WGs: 8 groups x 32 arrivals on separate MALL lines
// (parallel), group-completers bump root, everyone polls root. Acquire fence
// (L2 inv) only at 16-step ring lap boundaries (round-10 proven ring protocol).
__device__ __forceinline__ void gbar(int* bar, int w, int gen, bool inv) {
    asm volatile("s_waitcnt vmcnt(0)" ::: "memory");
    __syncthreads();
    if (threadIdx.x == 0) {
        int* grp  = bar + (w & 7) * 32;   // 8 counters, 128 B apart
        int* root = bar + 512;            // root counter
        int old = __hip_atomic_fetch_add(grp, 1, __ATOMIC_RELAXED, __HIP_MEMORY_SCOPE_AGENT);
        if (old == gen * 32 - 1)
            __hip_atomic_fetch_add(root, 1, __ATOMIC_RELAXED, __HIP_MEMORY_SCOPE_AGENT);
        while (__hip_atomic_load(root, __ATOMIC_RELAXED, __HIP_MEMORY_SCOPE_AGENT) < gen * 8)
            __builtin_amdgcn_s_sleep(1);
        if (inv)
            __builtin_amdgcn_fence(__ATOMIC_ACQUIRE, "agent");
    }
    __syncthreads();
}

// store one weight element as f16 hi/lo into swizzled LDS planes
__device__ __forceinline__ void st_w(char* smem, unsigned hiB, unsigned loB, unsigned K2,
                                     unsigned m, unsigned k, float v) {
    _Float16 hh = (_Float16)v;
    _Float16 ll = (_Float16)(v - (float)hh);
    unsigned off = (m * K2 + k * 2) ^ ((m & 7) << 4);
    *(u16*)(smem + hiB + off) = __builtin_bit_cast(u16, hh);
    *(u16*)(smem + loB + off) = __builtin_bit_cast(u16, ll);
}

// Issue ALL 16 chunk-loads of one f16 plane (one uint4 = 8 f16 per lane per chunk).
__device__ __forceinline__ void load_plane(uint4 (&buf)[16], const u32* __restrict__ plane,
                                           unsigned loff) {
    #pragma unroll
    for (int i = 0; i < 16; ++i)
        buf[i] = *(const uint4*)(plane + (size_t)i * 2048 + loff);
}

// Consume one plane: B direct from registers, A from swizzled LDS f16 hi/lo
// -> 2 MFMAs per 32-k chunk.
__device__ __forceinline__ void cons_plane(const uint4 (&buf)[16], const char* __restrict__ smem,
                                           unsigned hiB, unsigned loB, unsigned K2, unsigned wk0,
                                           unsigned mm, unsigned qq, f32x4& acc0, f32x4& acc1) {
    const unsigned swz = (mm & 7) << 4;
    #pragma unroll
    for (int i = 0; i < 16; ++i) {
        const unsigned wb = mm * K2 + (wk0 + (unsigned)i * 32 + qq * 8) * 2;
        half8 ahi = *(const half8*)(smem + hiB + (wb ^ swz));
        half8 alo = *(const half8*)(smem + loB + (wb ^ swz));
        half8 bv  = __builtin_bit_cast(half8, buf[i]);
        acc0 = __builtin_amdgcn_mfma_f32_16x16x32_f16(ahi, bv, acc0, 0, 0, 0);
        acc1 = __builtin_amdgcn_mfma_f32_16x16x32_f16(alo, bv, acc1, 0, 0, 0);
    }
}

// encoder cell-A x-segment (K=64): B built on the fly from fp32 x rows
__device__ __forceinline__ void seg_x(
    const char* smem, unsigned hiB, unsigned loB, unsigned K2,
    const float* __restrict__ x, int t, unsigned bt, int lane, f32x4& acc0, f32x4& acc1) {
    const unsigned mm = lane & 15, qq = lane >> 4;
    const unsigned swz = (mm & 7) << 4;
    const float* xp = x + ((size_t)(bt + mm) * T_ + t) * 64 + qq * 8;
    #pragma unroll
    for (int i = 0; i < 2; ++i) {
        float4 f0 = *(const float4*)(xp + i * 32);
        float4 f1 = *(const float4*)(xp + i * 32 + 4);
        float fs[8] = { f0.x, f0.y, f0.z, f0.w, f1.x, f1.y, f1.z, f1.w };
        half8 bv;
        #pragma unroll
        for (int j = 0; j < 8; ++j) bv[j] = (_Float16)fs[j];
        unsigned wb = (mm * K2 + (qq * 8 + i * 32) * 2) ^ swz;
        half8 ahi = *(const half8*)(smem + hiB + wb);
        half8 alo = *(const half8*)(smem + loB + wb);
        acc0 = __builtin_amdgcn_mfma_f32_16x16x32_f16(ahi, bv, acc0, 0, 0, 0);
        acc1 = __builtin_amdgcn_mfma_f32_16x16x32_f16(alo, bv, acc1, 0, 0, 0);
    }
}

// LSTM epilogue: lane owns 4 gate preacts of one (u,b); c in register.
// h -> f16; pair-pack with lane^16 (u and u+1) -> one u32 sc1 store per pair.
__device__ __forceinline__ void epilogue_reg(f32x4 acc, const float* bz, int u, int b,
                                             float& cr, u32* hw, int lane) {
    float gi = sigf(acc[0] + bz[0]);
    float gf = sigf(acc[1] + bz[1]);
    float gt = tanhf(acc[2] + bz[2]);
    float go = sigf(acc[3] + bz[3]);
    float cn = gf * cr + gi * gt;
    cr = cn;
    float hv = go * tanhf(cn);
    u16 mybits = f2h_bits(hv);
    int other = __shfl_xor((int)(u32)mybits, 16);
    if (((lane >> 4) & 1) == 0) {   // even-u member of the pair stores
        u32 pk = (u32)mybits | (((u32)other & 0xFFFFu) << 16);
        unsigned idx = (unsigned)(u >> 5) * 2048 + (unsigned)b * 16 + ((unsigned)(u & 31) >> 1);
        llc_store32(hw + idx, pk);
    }
}

// out(t) = h1 @ linW.T + linb; WG w handles batch bl = w>>1, f-half = w&1;
// 256 threads = 32 f x 8 kq.
__device__ __forceinline__ void linear_out(const u32* __restrict__ h1p,
                                           const float* __restrict__ linW,
                                           const float* __restrict__ linb,
                                           float* __restrict__ out, int w, int tid, int t) {
    const int bl = w >> 1;
    const int kq = tid & 7;
    const int f  = (w & 1) * 32 + (tid >> 3);   // 0..63 across the WG pair
    float s = 0.f;
    #pragma unroll
    for (int c2 = 0; c2 < 2; ++c2) {
        const int ch = kq * 2 + c2;   // k chunk = k>>5
        const u64* ph = (const u64*)h1p + (size_t)ch * 1024 + (size_t)bl * 8;
        const float* wp = linW + (size_t)f * H_ + ch * 32;
        #pragma unroll
        for (int j = 0; j < 8; ++j) {     // each u64 = 4 f16
            u64 r = ph[j];
            s += h2f((u16)r)         * wp[4 * j + 0];
            s += h2f((u16)(r >> 16)) * wp[4 * j + 1];
            s += h2f((u16)(r >> 32)) * wp[4 * j + 2];
            s += h2f((u16)(r >> 48)) * wp[4 * j + 3];
        }
    }
    s += __shfl_xor(s, 1);
    s += __shfl_xor(s, 2);
    s += __shfl_xor(s, 4);
    if (kq == 0)
        out[((size_t)bl * T_ + (255 - t)) * 64 + f] = s + linb[f];
}

__global__ __launch_bounds__(NTHR, 1) void lstm_persist(
    const float* __restrict__ x,
    const float* __restrict__ eWih0, const float* __restrict__ eWhh0,
    const float* __restrict__ ebih0, const float* __restrict__ ebhh0,
    const float* __restrict__ eWih1, const float* __restrict__ eWhh1,
    const float* __restrict__ ebih1, const float* __restrict__ ebhh1,
    const float* __restrict__ dWih0, const float* __restrict__ dWhh0,
    const float* __restrict__ dbih0, const float* __restrict__ dbhh0,
    const float* __restrict__ dWih1, const float* __restrict__ dWhh1,
    const float* __restrict__ dbih1, const float* __restrict__ dbhh1,
    const float* __restrict__ linW,  const float* __restrict__ linb,
    float* __restrict__ out, char* __restrict__ wsb, int* __restrict__ bar) {
    extern __shared__ char smem[];
    const int w = blockIdx.x, tid = threadIdx.x;
    const int lane = tid & 63, wave = tid >> 6;   // wave 0..3
    const int gid = w * NTHR + tid;               // 0..65535

    // WG = (u-quad, batch-half): uq = w>>1, half = w&1.
    const int u_base = (w >> 1) * 4;
    const int u = u_base + (lane >> 4);
    const unsigned bt = (unsigned)((w & 1) * 64 + wave * 16);   // wave = b-tile in half
    const int b = (int)bt + (lane & 15);
    const unsigned mm = (unsigned)(lane & 15), qq = (unsigned)(lane >> 4);
    const unsigned loff = (bt + mm) * 16 + qq * 4;   // u32 units into an 8 KB chunk

    // ring-slot accessors: slot = step & 15; step -1/-2 wrap to 15/14.
    #define H0S(t) ((u32*)(wsb + O_H0R + (unsigned)((t) & 15) * 131072u))
    #define H1S(t) ((u32*)(wsb + O_H1R + (unsigned)((t) & 15) * 131072u))
    int gen = 0;

    // ================= INIT =================
    {   // zero initial-state slots: h0 slot 15; h1 slots 14,15 (128 KB each)
        u64* z0 = (u64*)(wsb + O_H0R + 15u * 131072u);
        u64* z1 = (u64*)(wsb + O_H1R + 14u * 131072u);
        if (gid < 16384)       z0[gid] = 0ULL;
        else if (gid < 49152)  z1[gid - 16384] = 0ULL;
    }
    // per-lane bias registers (incl. beff fold); c in registers
    float bzA[4], bzB[4], bzD0[4], bzD0b[4], bzD1[4];
    #pragma unroll
    for (int g = 0; g < 4; ++g) {
        const int gr = g * H_ + u;
        bzA[g] = ebih0[gr] + ebhh0[gr];
        bzB[g] = ebih1[gr] + ebhh1[gr];
        float d0 = dbih0[gr] + dbhh0[gr];
        bzD0[g] = d0;
        float s = 0.f;
        for (int f = 0; f < 64; ++f) s += dWih0[(size_t)gr * 64 + f] * linb[f];
        bzD0b[g] = d0 + s;
        bzD1[g] = dbih1[gr] + dbhh1[gr];
    }
    float c0r = 0.f, c1r = 0.f;

    // encoder weights -> swizzled LDS f16 hi/lo (per u-quad; duplicated across halves)
    for (int mr = 0; mr < 16; ++mr) {
        const int gr = (mr & 3) * H_ + u_base + (mr >> 2);
        for (int k = tid; k < 576; k += NTHR) {
            float v = (k < 64) ? eWih0[(size_t)gr * 64 + k] : eWhh0[(size_t)gr * H_ + (k - 64)];
            st_w(smem, E0HI, E0LO, 1152, mr, k, v);
        }
        for (int k = tid; k < 1024; k += NTHR) {
            float v = (k < 512) ? eWih1[(size_t)gr * H_ + k] : eWhh1[(size_t)gr * H_ + (k - 512)];
            st_w(smem, E1HI, E1LO, 2048, mr, k, v);
        }
    }
    gbar(bar, w, ++gen, false);

    uint4 P[16], Q[16];

    // ================= ENCODER: pipelined, 257 phases =================
    // phase p: cellA(t=p) || cellB(t=p-1). Both consume h0(p-1): plane P shared.
    for (int p = 0; p <= T_; ++p) {
        f32x4 a0 = {0,0,0,0}, a1 = {0,0,0,0}, e0 = {0,0,0,0}, e1 = {0,0,0,0};
        load_plane(P, H0S(p - 1), loff);    // h0(p-1), this WG's batch half
        load_plane(Q, H1S(p - 2), loff);    // h1(p-2)
        if (p < T_) seg_x(smem, E0HI, E0LO, 1152, x, p, bt, lane, a0, a1);
        if (p < T_) cons_plane(P, smem, E0HI, E0LO, 1152, 64, mm, qq, a0, a1);
        if (p >= 1) cons_plane(P, smem, E1HI, E1LO, 2048, 0,   mm, qq, e0, e1);
        if (p >= 1) cons_plane(Q, smem, E1HI, E1LO, 2048, 512, mm, qq, e0, e1);
        if (p < T_)  epilogue_reg(a0 + a1, bzA, u, b, c0r, H0S(p), lane);
        if (p >= 1)  epilogue_reg(e0 + e1, bzB, u, b, c1r, H1S(p - 1), lane);
        gbar(bar, w, ++gen, (p & 15) == 15);
    }

    // ================= TRANSITION: decoder weights -> LDS (WG-local) =================
    for (int mr = 0; mr < 16; ++mr) {
        const int gr = (mr & 3) * H_ + u_base + (mr >> 2);
        const float* wr = dWih0 + (size_t)gr * 64;
        for (int c = tid; c < 512; c += NTHR) {
            float s = 0.f;
            #pragma unroll 8
            for (int f = 0; f < 64; ++f) s += wr[f] * linW[(size_t)f * H_ + c];  // Weff
            st_w(smem, D0HI, D0LO, 2048, mr, c, s);
            st_w(smem, D0HI, D0LO, 2048, mr, 512 + c, dWhh0[(size_t)gr * H_ + c]);
            st_w(smem, D1HI, D1LO, 2048, mr, c,       dWih1[(size_t)gr * H_ + c]);
            st_w(smem, D1HI, D1LO, 2048, mr, 512 + c, dWhh1[(size_t)gr * H_ + c]);
        }
    }
    __syncthreads();

    // ================= DECODER: 512 phases =================
    // decoder step t continues the global ring; dec h0(-1)/h1(-1) == slot 15.
    for (int t = 0; t < T_; ++t) {
        {   // dec0(t): Weff.h1(t-1) (or x-projection at t=0) + dWhh0.h0(t-1)
            f32x4 a0 = {0,0,0,0}, a1 = {0,0,0,0};
            if (t > 0) {
                load_plane(P, H1S(t - 1), loff);
                load_plane(Q, H0S(t - 1), loff);
                cons_plane(P, smem, D0HI, D0LO, 2048, 0,   mm, qq, a0, a1);
                cons_plane(Q, smem, D0HI, D0LO, 2048, 512, mm, qq, a0, a1);
            } else {
                load_plane(Q, H0S(t - 1), loff);
                const float* xr = x + ((size_t)b * T_ + (T_ - 1)) * 64;
                #pragma unroll
                for (int g = 0; g < 4; ++g) {
                    const float* wr = dWih0 + (size_t)(g * H_ + u) * 64;
                    float s = 0.f;
                    for (int f = 0; f < 64; ++f) s += wr[f] * xr[f];
                    a0[g] = s;
                }
                cons_plane(Q, smem, D0HI, D0LO, 2048, 512, mm, qq, a0, a1);
            }
            epilogue_reg(a0 + a1, (t > 0) ? bzD0b : bzD0, u, b, c0r, H0S(t), lane);
            if (t > 0) linear_out(H1S(t - 1), linW, linb, out, w, tid, t - 1);  // folded linear
        }
        gbar(bar, w, ++gen, false);
        {   // dec1(t): dWih1.h0(t) + dWhh1.h1(t-1)
            f32x4 a0 = {0,0,0,0}, a1 = {0,0,0,0};
            load_plane(P, H0S(t), loff);
            load_plane(Q, H1S(t - 1), loff);
            cons_plane(P, smem, D1HI, D1LO, 2048, 0,   mm, qq, a0, a1);
            cons_plane(Q, smem, D1HI, D1LO, 2048, 512, mm, qq, a0, a1);
            epilogue_reg(a0 + a1, bzD1, u, b, c1r, H1S(t), lane);
        }
        gbar(bar, w, ++gen, (t & 15) == 15);
    }
    // final output (t=255): dec h1(255) -> slot 15
    linear_out(H1S(255), linW, linb, out, w, tid, 255);
}

extern "C" void kernel_launch(void* const* d_in, const int* in_sizes, int n_in,
                              void* d_out, int out_size, void* d_ws, size_t ws_size,
                              hipStream_t stream) {
    (void)in_sizes; (void)n_in; (void)out_size; (void)ws_size;
    const float* x     = (const float*)d_in[0];
    const float* eWih0 = (const float*)d_in[1];
    const float* eWhh0 = (const float*)d_in[2];
    const float* ebih0 = (const float*)d_in[3];
    const float* ebhh0 = (const float*)d_in[4];
    const float* eWih1 = (const float*)d_in[5];
    const float* eWhh1 = (const float*)d_in[6];
    const float* ebih1 = (const float*)d_in[7];
    const float* ebhh1 = (const float*)d_in[8];
    const float* dWih0 = (const float*)d_in[9];
    const float* dWhh0 = (const float*)d_in[10];
    const float* dbih0 = (const float*)d_in[11];
    const float* dbhh0 = (const float*)d_in[12];
    const float* dWih1 = (const float*)d_in[13];
    const float* dWhh1 = (const float*)d_in[14];
    const float* dbih1 = (const float*)d_in[15];
    const float* dbhh1 = (const float*)d_in[16];
    const float* linW  = (const float*)d_in[17];
    const float* linb  = (const float*)d_in[18];

    char* wsb = (char*)d_ws;
    int* bar  = (int*)(wsb + O_BAR);

    static const int lds_bytes = 131072;
    hipFuncSetAttribute((const void*)lstm_persist,
                        hipFuncAttributeMaxDynamicSharedMemorySize, lds_bytes);

    hipMemsetAsync(bar, 0, 4096, stream);

    hipLaunchKernelGGL(lstm_persist, dim3(NWG), dim3(NTHR), lds_bytes, stream,
                       x, eWih0, eWhh0, ebih0, ebhh0, eWih1, eWhh1, ebih1, ebhh1,
                       dWih0, dWhh0, dbih0, dbhh0, dWih1, dWhh1, dbih1, dbhh1,
                       linW, linb, (float*)d_out, wsb, bar);
}

// Round 13
// 5074.142 us; speedup vs baseline: 9.2279x; 1.0980x over previous
//
#include <hip/hip_runtime.h>
#include <math.h>

#define T_ 256
#define H_ 512
#define NWG 256
#define NTHR 256

typedef _Float16 half8 __attribute__((ext_vector_type(8)));
typedef float f32x4 __attribute__((ext_vector_type(4)));
typedef unsigned short u16;
typedef unsigned int u32;
typedef unsigned long long u64;

// ---- ws byte offsets ----
// h planes: fp16, rings of 16 slots (slot = step & 15), each slot 128 KB,
// tiled [kchunk16][b128][k32] f16.
#define O_H0R  0u           // 16 x 131072 = 2 MB
#define O_H1R  2097152u     // 16 x 131072 = 2 MB
#define O_BAR  4194304u     // tree barrier: 8 group counters (128B apart) + root

// ---- LDS byte offsets (65536 dynamic, single-f16 weight planes) ----
#define E0W 0u             // 16 rows x 576  (x|h0), row 1152 B
#define E1W 18432u         // 16 rows x 1024 (h0|h1), row 2048 B
#define D0W 0u             // 16 rows x 1024 (Weff|dWhh0)
#define D1W 32768u         // 16 rows x 1024 (dWih1|dWhh1)

__device__ __forceinline__ float sigf(float x) { return 1.0f / (1.0f + expf(-x)); }

__device__ __forceinline__ u16 f2h_bits(float f) {
    _Float16 h = (_Float16)f;
    return __builtin_bit_cast(u16, h);
}
__device__ __forceinline__ float h2f(u16 x) {
    return (float)__builtin_bit_cast(_Float16, x);
}

// Producer-side stores: agent-scope write-through (visible at MALL, no dirty L2 lines).
__device__ __forceinline__ void llc_store64(u64* p, u64 v) {
    __hip_atomic_store(p, v, __ATOMIC_RELAXED, __HIP_MEMORY_SCOPE_AGENT);
}
__device__ __forceinline__ void llc_store32(u32* p, u32 v) {
    __hip_atomic_store(p, v, __ATOMIC_RELAXED, __HIP_MEMORY_SCOPE_AGENT);
}

// Tree grid barrier for 256 WGs: 8 groups x 32 arrivals on separate MALL lines,
// group-completers bump root, everyone polls root. Acquire fence (L2 inv) only
// at 16-step ring lap boundaries (ring protocol proven r10-r12).
__device__ __forceinline__ void gbar(int* bar, int w, int gen, bool inv) {
    asm volatile("s_waitcnt vmcnt(0)" ::: "memory");
    __syncthreads();
    if (threadIdx.x == 0) {
        int* grp  = bar + (w & 7) * 32;   // 8 counters, 128 B apart
        int* root = bar + 512;            // root counter
        int old = __hip_atomic_fetch_add(grp, 1, __ATOMIC_RELAXED, __HIP_MEMORY_SCOPE_AGENT);
        if (old == gen * 32 - 1)
            __hip_atomic_fetch_add(root, 1, __ATOMIC_RELAXED, __HIP_MEMORY_SCOPE_AGENT);
        while (__hip_atomic_load(root, __ATOMIC_RELAXED, __HIP_MEMORY_SCOPE_AGENT) < gen * 8)
            __builtin_amdgcn_s_sleep(1);
        if (inv)
            __builtin_amdgcn_fence(__ATOMIC_ACQUIRE, "agent");
    }
    __syncthreads();
}

// store one weight element as single f16 into swizzled LDS plane
__device__ __forceinline__ void st_w(char* smem, unsigned base, unsigned K2,
                                     unsigned m, unsigned k, float v) {
    _Float16 hh = (_Float16)v;
    unsigned off = (m * K2 + k * 2) ^ ((m & 7) << 4);
    *(u16*)(smem + base + off) = __builtin_bit_cast(u16, hh);
}

// Issue ALL 16 chunk-loads of one f16 plane (one uint4 = 8 f16 per lane per chunk).
__device__ __forceinline__ void load_plane(uint4 (&buf)[16], const u32* __restrict__ plane,
                                           unsigned loff) {
    #pragma unroll
    for (int i = 0; i < 16; ++i)
        buf[i] = *(const uint4*)(plane + (size_t)i * 2048 + loff);
}

// Consume one plane: B direct from registers, A from swizzled LDS f16
// -> 1 MFMA per 32-k chunk.
__device__ __forceinline__ void cons_plane(const uint4 (&buf)[16], const char* __restrict__ smem,
                                           unsigned base, unsigned K2, unsigned wk0,
                                           unsigned mm, unsigned qq, f32x4& acc) {
    const unsigned swz = (mm & 7) << 4;
    #pragma unroll
    for (int i = 0; i < 16; ++i) {
        const unsigned wb = mm * K2 + (wk0 + (unsigned)i * 32 + qq * 8) * 2;
        half8 av = *(const half8*)(smem + base + (wb ^ swz));
        half8 bv = __builtin_bit_cast(half8, buf[i]);
        acc = __builtin_amdgcn_mfma_f32_16x16x32_f16(av, bv, acc, 0, 0, 0);
    }
}

// encoder cell-A x-segment (K=64): B built on the fly from fp32 x rows
__device__ __forceinline__ void seg_x(
    const char* smem, unsigned base, unsigned K2,
    const float* __restrict__ x, int t, unsigned bt, int lane, f32x4& acc) {
    const unsigned mm = lane & 15, qq = lane >> 4;
    const unsigned swz = (mm & 7) << 4;
    const float* xp = x + ((size_t)(bt + mm) * T_ + t) * 64 + qq * 8;
    #pragma unroll
    for (int i = 0; i < 2; ++i) {
        float4 f0 = *(const float4*)(xp + i * 32);
        float4 f1 = *(const float4*)(xp + i * 32 + 4);
        float fs[8] = { f0.x, f0.y, f0.z, f0.w, f1.x, f1.y, f1.z, f1.w };
        half8 bv;
        #pragma unroll
        for (int j = 0; j < 8; ++j) bv[j] = (_Float16)fs[j];
        unsigned wb = (mm * K2 + (qq * 8 + i * 32) * 2) ^ swz;
        half8 av = *(const half8*)(smem + base + wb);
        acc = __builtin_amdgcn_mfma_f32_16x16x32_f16(av, bv, acc, 0, 0, 0);
    }
}

// LSTM epilogue: lane owns 4 gate preacts of one (u,b); c in register.
// h -> f16; pair-pack with lane^16 (u and u+1) -> one u32 sc1 store per pair.
__device__ __forceinline__ void epilogue_reg(f32x4 acc, const float* bz, int u, int b,
                                             float& cr, u32* hw, int lane) {
    float gi = sigf(acc[0] + bz[0]);
    float gf = sigf(acc[1] + bz[1]);
    float gt = tanhf(acc[2] + bz[2]);
    float go = sigf(acc[3] + bz[3]);
    float cn = gf * cr + gi * gt;
    cr = cn;
    float hv = go * tanhf(cn);
    u16 mybits = f2h_bits(hv);
    int other = __shfl_xor((int)(u32)mybits, 16);
    if (((lane >> 4) & 1) == 0) {   // even-u member of the pair stores
        u32 pk = (u32)mybits | (((u32)other & 0xFFFFu) << 16);
        unsigned idx = (unsigned)(u >> 5) * 2048 + (unsigned)b * 16 + ((unsigned)(u & 31) >> 1);
        llc_store32(hw + idx, pk);
    }
}

// out(t) = h1 @ linW.T + linb; WG w handles batch bl = w>>1, f-half = w&1;
// 256 threads = 32 f x 8 kq.
__device__ __forceinline__ void linear_out(const u32* __restrict__ h1p,
                                           const float* __restrict__ linW,
                                           const float* __restrict__ linb,
                                           float* __restrict__ out, int w, int tid, int t) {
    const int bl = w >> 1;
    const int kq = tid & 7;
    const int f  = (w & 1) * 32 + (tid >> 3);   // 0..63 across the WG pair
    float s = 0.f;
    #pragma unroll
    for (int c2 = 0; c2 < 2; ++c2) {
        const int ch = kq * 2 + c2;   // k chunk = k>>5
        const u64* ph = (const u64*)h1p + (size_t)ch * 1024 + (size_t)bl * 8;
        const float* wp = linW + (size_t)f * H_ + ch * 32;
        #pragma unroll
        for (int j = 0; j < 8; ++j) {     // each u64 = 4 f16
            u64 r = ph[j];
            s += h2f((u16)r)         * wp[4 * j + 0];
            s += h2f((u16)(r >> 16)) * wp[4 * j + 1];
            s += h2f((u16)(r >> 32)) * wp[4 * j + 2];
            s += h2f((u16)(r >> 48)) * wp[4 * j + 3];
        }
    }
    s += __shfl_xor(s, 1);
    s += __shfl_xor(s, 2);
    s += __shfl_xor(s, 4);
    if (kq == 0)
        out[((size_t)bl * T_ + (255 - t)) * 64 + f] = s + linb[f];
}

__global__ __launch_bounds__(NTHR, 1) void lstm_persist(
    const float* __restrict__ x,
    const float* __restrict__ eWih0, const float* __restrict__ eWhh0,
    const float* __restrict__ ebih0, const float* __restrict__ ebhh0,
    const float* __restrict__ eWih1, const float* __restrict__ eWhh1,
    const float* __restrict__ ebih1, const float* __restrict__ ebhh1,
    const float* __restrict__ dWih0, const float* __restrict__ dWhh0,
    const float* __restrict__ dbih0, const float* __restrict__ dbhh0,
    const float* __restrict__ dWih1, const float* __restrict__ dWhh1,
    const float* __restrict__ dbih1, const float* __restrict__ dbhh1,
    const float* __restrict__ linW,  const float* __restrict__ linb,
    float* __restrict__ out, char* __restrict__ wsb, int* __restrict__ bar) {
    extern __shared__ char smem[];
    const int w = blockIdx.x, tid = threadIdx.x;
    const int lane = tid & 63, wave = tid >> 6;   // wave 0..3
    const int gid = w * NTHR + tid;               // 0..65535

    // WG = (u-quad, batch-half): uq = w>>1, half = w&1.
    const int u_base = (w >> 1) * 4;
    const int u = u_base + (lane >> 4);
    const unsigned bt = (unsigned)((w & 1) * 64 + wave * 16);   // wave = b-tile in half
    const int b = (int)bt + (lane & 15);
    const unsigned mm = (unsigned)(lane & 15), qq = (unsigned)(lane >> 4);
    const unsigned loff = (bt + mm) * 16 + qq * 4;   // u32 units into an 8 KB chunk

    // ring-slot accessors: slot = step & 15; step -1/-2 wrap to 15/14.
    #define H0S(t) ((u32*)(wsb + O_H0R + (unsigned)((t) & 15) * 131072u))
    #define H1S(t) ((u32*)(wsb + O_H1R + (unsigned)((t) & 15) * 131072u))
    int gen = 0;

    // ================= INIT =================
    {   // zero initial-state slots: h0 slot 15; h1 slots 14,15 (128 KB each)
        u64* z0 = (u64*)(wsb + O_H0R + 15u * 131072u);
        u64* z1 = (u64*)(wsb + O_H1R + 14u * 131072u);
        if (gid < 16384)       z0[gid] = 0ULL;
        else if (gid < 49152)  z1[gid - 16384] = 0ULL;
    }
    // per-lane bias registers (incl. beff fold); c in registers
    float bzA[4], bzB[4], bzD0[4], bzD0b[4], bzD1[4];
    #pragma unroll
    for (int g = 0; g < 4; ++g) {
        const int gr = g * H_ + u;
        bzA[g] = ebih0[gr] + ebhh0[gr];
        bzB[g] = ebih1[gr] + ebhh1[gr];
        float d0 = dbih0[gr] + dbhh0[gr];
        bzD0[g] = d0;
        float s = 0.f;
        for (int f = 0; f < 64; ++f) s += dWih0[(size_t)gr * 64 + f] * linb[f];
        bzD0b[g] = d0 + s;
        bzD1[g] = dbih1[gr] + dbhh1[gr];
    }
    float c0r = 0.f, c1r = 0.f;

    // encoder weights -> swizzled LDS f16 (per u-quad; duplicated across halves)
    for (int mr = 0; mr < 16; ++mr) {
        const int gr = (mr & 3) * H_ + u_base + (mr >> 2);
        for (int k = tid; k < 576; k += NTHR) {
            float v = (k < 64) ? eWih0[(size_t)gr * 64 + k] : eWhh0[(size_t)gr * H_ + (k - 64)];
            st_w(smem, E0W, 1152, mr, k, v);
        }
        for (int k = tid; k < 1024; k += NTHR) {
            float v = (k < 512) ? eWih1[(size_t)gr * H_ + k] : eWhh1[(size_t)gr * H_ + (k - 512)];
            st_w(smem, E1W, 2048, mr, k, v);
        }
    }
    gbar(bar, w, ++gen, false);

    uint4 P[16], Q[16];

    // ================= ENCODER: pipelined, 257 phases =================
    // phase p: cellA(t=p) || cellB(t=p-1). Both consume h0(p-1): plane P shared.
    for (int p = 0; p <= T_; ++p) {
        f32x4 a = {0,0,0,0}, e = {0,0,0,0};
        load_plane(P, H0S(p - 1), loff);    // h0(p-1), this WG's batch half
        load_plane(Q, H1S(p - 2), loff);    // h1(p-2)
        if (p < T_) seg_x(smem, E0W, 1152, x, p, bt, lane, a);
        if (p < T_) cons_plane(P, smem, E0W, 1152, 64, mm, qq, a);
        if (p >= 1) cons_plane(P, smem, E1W, 2048, 0,   mm, qq, e);
        if (p >= 1) cons_plane(Q, smem, E1W, 2048, 512, mm, qq, e);
        if (p < T_)  epilogue_reg(a, bzA, u, b, c0r, H0S(p), lane);
        if (p >= 1)  epilogue_reg(e, bzB, u, b, c1r, H1S(p - 1), lane);
        gbar(bar, w, ++gen, (p & 15) == 15);
    }

    // ================= TRANSITION: decoder weights -> LDS (WG-local) =================
    for (int mr = 0; mr < 16; ++mr) {
        const int gr = (mr & 3) * H_ + u_base + (mr >> 2);
        const float* wr = dWih0 + (size_t)gr * 64;
        for (int c = tid; c < 512; c += NTHR) {
            float s = 0.f;
            #pragma unroll 8
            for (int f = 0; f < 64; ++f) s += wr[f] * linW[(size_t)f * H_ + c];  // Weff
            st_w(smem, D0W, 2048, mr, c, s);
            st_w(smem, D0W, 2048, mr, 512 + c, dWhh0[(size_t)gr * H_ + c]);
            st_w(smem, D1W, 2048, mr, c,       dWih1[(size_t)gr * H_ + c]);
            st_w(smem, D1W, 2048, mr, 512 + c, dWhh1[(size_t)gr * H_ + c]);
        }
    }
    __syncthreads();

    // ================= DECODER: 512 phases, 1 plane-load per phase =================
    // Register double-buffer: P carries h1(t-1) from dec0 into dec1; Q carries
    // h0(t-1) from dec1(t-1) into dec0(t). Ring continues; dec h0(-1)/h1(-1)=slot 15.
    for (int t = 0; t < T_; ++t) {
        {   // dec0(t): Weff.h1(t-1) (or x-projection at t=0) + dWhh0.h0(t-1)
            f32x4 a = {0,0,0,0};
            if (t > 0) {
                load_plane(P, H1S(t - 1), loff);        // fresh h1(t-1)
                cons_plane(P, smem, D0W, 2048, 0, mm, qq, a);
            } else {
                load_plane(Q, H0S(-1), loff);           // h0(-1) (enc h0(255), slot 15)
                const float* xr = x + ((size_t)b * T_ + (T_ - 1)) * 64;
                #pragma unroll
                for (int g = 0; g < 4; ++g) {
                    const float* wr = dWih0 + (size_t)(g * H_ + u) * 64;
                    float s = 0.f;
                    for (int f = 0; f < 64; ++f) s += wr[f] * xr[f];
                    a[g] = s;
                }
            }
            cons_plane(Q, smem, D0W, 2048, 512, mm, qq, a);   // h0(t-1) kept in Q
            epilogue_reg(a, (t > 0) ? bzD0b : bzD0, u, b, c0r, H0S(t), lane);
            if (t > 0) linear_out(H1S(t - 1), linW, linb, out, w, tid, t - 1);  // folded linear
        }
        gbar(bar, w, ++gen, false);
        {   // dec1(t): dWih1.h0(t) + dWhh1.h1(t-1)
            f32x4 a = {0,0,0,0};
            load_plane(Q, H0S(t), loff);                // fresh h0(t)
            if (t == 0) load_plane(P, H1S(-1), loff);   // h1(-1) (enc h1(255), slot 15)
            cons_plane(Q, smem, D1W, 2048, 0,   mm, qq, a);
            cons_plane(P, smem, D1W, 2048, 512, mm, qq, a);   // h1(t-1) kept in P
            epilogue_reg(a, bzD1, u, b, c1r, H1S(t), lane);
        }
        gbar(bar, w, ++gen, (t & 15) == 15);
    }
    // final output (t=255): dec h1(255) -> slot 15
    linear_out(H1S(255), linW, linb, out, w, tid, 255);
}

extern "C" void kernel_launch(void* const* d_in, const int* in_sizes, int n_in,
                              void* d_out, int out_size, void* d_ws, size_t ws_size,
                              hipStream_t stream) {
    (void)in_sizes; (void)n_in; (void)out_size; (void)ws_size;
    const float* x     = (const float*)d_in[0];
    const float* eWih0 = (const float*)d_in[1];
    const float* eWhh0 = (const float*)d_in[2];
    const float* ebih0 = (const float*)d_in[3];
    const float* ebhh0 = (const float*)d_in[4];
    const float* eWih1 = (const float*)d_in[5];
    const float* eWhh1 = (const float*)d_in[6];
    const float* ebih1 = (const float*)d_in[7];
    const float* ebhh1 = (const float*)d_in[8];
    const float* dWih0 = (const float*)d_in[9];
    const float* dWhh0 = (const float*)d_in[10];
    const float* dbih0 = (const float*)d_in[11];
    const float* dbhh0 = (const float*)d_in[12];
    const float* dWih1 = (const float*)d_in[13];
    const float* dWhh1 = (const float*)d_in[14];
    const float* dbih1 = (const float*)d_in[15];
    const float* dbhh1 = (const float*)d_in[16];
    const float* linW  = (const float*)d_in[17];
    const float* linb  = (const float*)d_in[18];

    char* wsb = (char*)d_ws;
    int* bar  = (int*)(wsb + O_BAR);

    static const int lds_bytes = 65536;
    hipFuncSetAttribute((const void*)lstm_persist,
                        hipFuncAttributeMaxDynamicSharedMemorySize, lds_bytes);

    hipMemsetAsync(bar, 0, 4096, stream);

    hipLaunchKernelGGL(lstm_persist, dim3(NWG), dim3(NTHR), lds_bytes, stream,
                       x, eWih0, eWhh0, ebih0, ebhh0, eWih1, eWhh1, ebih1, ebhh1,
                       dWih0, dWhh0, dbih0, dbhh0, dWih1, dWhh1, dbih1, dbhh1,
                       linW, linb, (float*)d_out, wsb, bar);
}

// Round 14
// 3716.233 us; speedup vs baseline: 12.5997x; 1.3654x over previous
//
#include <hip/hip_runtime.h>
#include <math.h>

#define T_ 256
#define H_ 512
#define NWG 256
#define NTHR 256
#define WPG 64      // WGs per batch-group (4 groups of 32 batches)

typedef _Float16 half8 __attribute__((ext_vector_type(8)));
typedef float f32x4 __attribute__((ext_vector_type(4)));
typedef unsigned short u16;
typedef unsigned int u32;
typedef unsigned long long u64;

// ---- ws byte offsets ----
// h planes: fp16, rings of 16 slots (slot = step & 15), each slot 128 KB,
// tiled [kchunk16][b128][k32] f16. Groups touch disjoint 64B b-rows.
#define O_H0R  0u           // 16 x 131072 = 2 MB
#define O_H1R  2097152u     // 16 x 131072 = 2 MB
#define O_BAR  4194304u     // 256 flags x 64 B

// ---- LDS byte offsets (131072 dynamic, single-f16 weight planes, 32 rows/WG) ----
#define E0W 0u             // 32 rows x 576  (x|h0), row 1152 B  = 36 KB
#define E1W 36864u         // 32 rows x 1024 (h0|h1), row 2048 B = 64 KB
#define D0W 0u             // 32 rows x 1024 (Weff|dWhh0) = 64 KB
#define D1W 65536u         // 32 rows x 1024 (dWih1|dWhh1) = 64 KB

__device__ __forceinline__ float sigf(float x) { return 1.0f / (1.0f + expf(-x)); }

__device__ __forceinline__ u16 f2h_bits(float f) {
    _Float16 h = (_Float16)f;
    return __builtin_bit_cast(u16, h);
}
__device__ __forceinline__ float h2f(u16 x) {
    return (float)__builtin_bit_cast(_Float16, x);
}

// Producer-side stores: agent-scope write-through (visible at MALL, no dirty L2 lines).
__device__ __forceinline__ void llc_store64(u64* p, u64 v) {
    __hip_atomic_store(p, v, __ATOMIC_RELAXED, __HIP_MEMORY_SCOPE_AGENT);
}
__device__ __forceinline__ void llc_store32(u32* p, u32 v) {
    __hip_atomic_store(p, v, __ATOMIC_RELAXED, __HIP_MEMORY_SCOPE_AGENT);
}

// ---- split-phase group barrier: atomic-free flags + wave-parallel poll ----
// arrive: drain own stores, then ONE sc1 store to this WG's private flag line.
__device__ __forceinline__ void gbar_arrive(int* flags, int w, int gen) {
    asm volatile("s_waitcnt vmcnt(0)" ::: "memory");
    __syncthreads();
    if (threadIdx.x == 0)
        __hip_atomic_store(flags + w * 16, gen, __ATOMIC_RELAXED, __HIP_MEMORY_SCOPE_AGENT);
}
// wait: wave 0's 64 lanes poll the group's 64 flags in parallel; lap-boundary
// fence (single L2 inv per WG) at the same stream positions as r13.
__device__ __forceinline__ void gbar_wait(int* flags, int gbase, int gen, bool inv) {
    if (threadIdx.x < 64) {
        while (__hip_atomic_load(flags + (gbase + threadIdx.x) * 16,
                                 __ATOMIC_RELAXED, __HIP_MEMORY_SCOPE_AGENT) < gen)
            __builtin_amdgcn_s_sleep(1);
    }
    __syncthreads();
    if (inv) {
        if (threadIdx.x == 0) __builtin_amdgcn_fence(__ATOMIC_ACQUIRE, "agent");
        __syncthreads();
    }
}

// store one weight element as single f16 into swizzled LDS plane (32 rows)
__device__ __forceinline__ void st_w(char* smem, unsigned base, unsigned K2,
                                     unsigned m, unsigned k, float v) {
    _Float16 hh = (_Float16)v;
    unsigned off = (m * K2 + k * 2) ^ ((m & 7) << 4);
    *(u16*)(smem + base + off) = __builtin_bit_cast(u16, hh);
}

// Issue ALL 16 chunk-loads of one f16 plane slice (uint4 = 8 f16 per lane per chunk).
__device__ __forceinline__ void load_plane(uint4 (&buf)[16], const u32* __restrict__ plane,
                                           unsigned loff) {
    #pragma unroll
    for (int i = 0; i < 16; ++i)
        buf[i] = *(const uint4*)(plane + (size_t)i * 2048 + loff);
}

// Consume one plane: B direct from registers, A row R from swizzled LDS f16.
__device__ __forceinline__ void cons_plane(const uint4 (&buf)[16], const char* __restrict__ smem,
                                           unsigned base, unsigned K2, unsigned wk0,
                                           unsigned R, unsigned qq, f32x4& acc) {
    const unsigned swz = (R & 7) << 4;
    #pragma unroll
    for (int i = 0; i < 16; ++i) {
        const unsigned wb = R * K2 + (wk0 + (unsigned)i * 32 + qq * 8) * 2;
        half8 av = *(const half8*)(smem + base + (wb ^ swz));
        half8 bv = __builtin_bit_cast(half8, buf[i]);
        acc = __builtin_amdgcn_mfma_f32_16x16x32_f16(av, bv, acc, 0, 0, 0);
    }
}

// encoder cell-A x-segment (K=64): B built on the fly from fp32 x rows (read-only)
__device__ __forceinline__ void seg_x(
    const char* smem, unsigned base, unsigned K2,
    const float* __restrict__ x, int t, unsigned bt, unsigned R, int lane, f32x4& acc) {
    const unsigned mm = lane & 15, qq = lane >> 4;
    const unsigned swz = (R & 7) << 4;
    const float* xp = x + ((size_t)(bt + mm) * T_ + t) * 64 + qq * 8;
    #pragma unroll
    for (int i = 0; i < 2; ++i) {
        float4 f0 = *(const float4*)(xp + i * 32);
        float4 f1 = *(const float4*)(xp + i * 32 + 4);
        float fs[8] = { f0.x, f0.y, f0.z, f0.w, f1.x, f1.y, f1.z, f1.w };
        half8 bv;
        #pragma unroll
        for (int j = 0; j < 8; ++j) bv[j] = (_Float16)fs[j];
        unsigned wb = (R * K2 + (qq * 8 + i * 32) * 2) ^ swz;
        half8 av = *(const half8*)(smem + base + wb);
        acc = __builtin_amdgcn_mfma_f32_16x16x32_f16(av, bv, acc, 0, 0, 0);
    }
}

// LSTM epilogue: lane owns 4 gate preacts of one (u,b); c in register.
// h -> f16; pair-pack with lane^16 (u and u+-1) -> one u32 sc1 store per pair.
__device__ __forceinline__ void epilogue_reg(f32x4 acc, const float* bz, int u, int b,
                                             float& cr, u32* hw, int lane) {
    float gi = sigf(acc[0] + bz[0]);
    float gf = sigf(acc[1] + bz[1]);
    float gt = tanhf(acc[2] + bz[2]);
    float go = sigf(acc[3] + bz[3]);
    float cn = gf * cr + gi * gt;
    cr = cn;
    float hv = go * tanhf(cn);
    u16 mybits = f2h_bits(hv);
    int other = __shfl_xor((int)(u32)mybits, 16);
    if (((lane >> 4) & 1) == 0) {   // even-u member of the pair stores
        u32 pk = (u32)mybits | (((u32)other & 0xFFFFu) << 16);
        unsigned idx = (unsigned)(u >> 5) * 2048 + (unsigned)b * 16 + ((unsigned)(u & 31) >> 1);
        llc_store32(hw + idx, pk);
    }
}

// out(t) = h1 @ linW.T + linb; group WG wl: batch bl = g*32 + (wl>>1), f-half = wl&1.
__device__ __forceinline__ void linear_out(const u32* __restrict__ h1p,
                                           const float* __restrict__ linW,
                                           const float* __restrict__ linb,
                                           float* __restrict__ out, int g, int wl,
                                           int tid, int t) {
    const int bl = g * 32 + (wl >> 1);
    const int kq = tid & 7;
    const int f  = (wl & 1) * 32 + (tid >> 3);
    float s = 0.f;
    #pragma unroll
    for (int c2 = 0; c2 < 2; ++c2) {
        const int ch = kq * 2 + c2;   // k chunk = k>>5
        const u64* ph = (const u64*)h1p + (size_t)ch * 1024 + (size_t)bl * 8;
        const float* wp = linW + (size_t)f * H_ + ch * 32;
        #pragma unroll
        for (int j = 0; j < 8; ++j) {     // each u64 = 4 f16
            u64 r = ph[j];
            s += h2f((u16)r)         * wp[4 * j + 0];
            s += h2f((u16)(r >> 16)) * wp[4 * j + 1];
            s += h2f((u16)(r >> 32)) * wp[4 * j + 2];
            s += h2f((u16)(r >> 48)) * wp[4 * j + 3];
        }
    }
    s += __shfl_xor(s, 1);
    s += __shfl_xor(s, 2);
    s += __shfl_xor(s, 4);
    if (kq == 0)
        out[((size_t)bl * T_ + (255 - t)) * 64 + f] = s + linb[f];
}

__global__ __launch_bounds__(NTHR, 1) void lstm_persist(
    const float* __restrict__ x,
    const float* __restrict__ eWih0, const float* __restrict__ eWhh0,
    const float* __restrict__ ebih0, const float* __restrict__ ebhh0,
    const float* __restrict__ eWih1, const float* __restrict__ eWhh1,
    const float* __restrict__ ebih1, const float* __restrict__ ebhh1,
    const float* __restrict__ dWih0, const float* __restrict__ dWhh0,
    const float* __restrict__ dbih0, const float* __restrict__ dbhh0,
    const float* __restrict__ dWih1, const float* __restrict__ dWhh1,
    const float* __restrict__ dbih1, const float* __restrict__ dbhh1,
    const float* __restrict__ linW,  const float* __restrict__ linb,
    float* __restrict__ out, char* __restrict__ wsb, int* __restrict__ flags) {
    extern __shared__ char smem[];
    const int w = blockIdx.x, tid = threadIdx.x;
    const int lane = tid & 63, wave = tid >> 6;   // wave 0..3

    // group structure: 4 groups x 64 WGs; group owns 32 batches, WG owns 8 u's.
    const int g = w >> 6;
    const int wl = w & 63;
    const int gbase = g * WPG;
    const int u_base = wl * 8;
    const int mh = wave >> 1;                 // m-half: rows [mh*16, mh*16+16)
    const int bh = wave & 1;                  // b-half within group's 32 batches
    const int u = u_base + mh * 4 + (lane >> 4);
    const unsigned bt = (unsigned)(g * 32 + bh * 16);
    const int b = (int)bt + (lane & 15);
    const unsigned R = (unsigned)(mh * 16 + (lane & 15));   // LDS A row (0..31)
    const unsigned qq = (unsigned)(lane >> 4);
    const unsigned loff = (bt + (unsigned)(lane & 15)) * 16 + qq * 4;

    // ring-slot accessors: slot = step & 15; step -1/-2 wrap to 15/14.
    #define H0S(t) ((u32*)(wsb + O_H0R + (unsigned)((t) & 15) * 131072u))
    #define H1S(t) ((u32*)(wsb + O_H1R + (unsigned)((t) & 15) * 131072u))
    int gen = 0;

    // ================= INIT (group-local) =================
    {   // zero this group's b-slice of h0 slot15, h1 slots 14,15
        const int gtid = wl * NTHR + tid;     // 0..16383 within group
        if (gtid < 12288) {
            const int slot  = gtid >> 12;             // 0..2
            const int rem   = gtid & 4095;
            const int chunk = rem >> 8;
            const int brow  = (rem & 255) >> 3;
            const int q     = rem & 7;
            u64* base = (slot == 0) ? (u64*)(wsb + O_H0R + 15u * 131072u)
                      : (slot == 1) ? (u64*)(wsb + O_H1R + 14u * 131072u)
                                    : (u64*)(wsb + O_H1R + 15u * 131072u);
            llc_store64(base + (size_t)chunk * 1024 + (size_t)(g * 32 + brow) * 8 + q, 0ULL);
        }
    }
    // per-lane bias registers (incl. beff fold); c in registers
    float bzA[4], bzB[4], bzD0[4], bzD0b[4], bzD1[4];
    #pragma unroll
    for (int gg = 0; gg < 4; ++gg) {
        const int gr = gg * H_ + u;
        bzA[gg] = ebih0[gr] + ebhh0[gr];
        bzB[gg] = ebih1[gr] + ebhh1[gr];
        float d0 = dbih0[gr] + dbhh0[gr];
        bzD0[gg] = d0;
        float s = 0.f;
        for (int f = 0; f < 64; ++f) s += dWih0[(size_t)gr * 64 + f] * linb[f];
        bzD0b[gg] = d0 + s;
        bzD1[gg] = dbih1[gr] + dbhh1[gr];
    }
    float c0r = 0.f, c1r = 0.f;

    // encoder weights -> swizzled LDS f16 (32 rows: 8 u's x 4 gates)
    for (int mr = 0; mr < 32; ++mr) {
        const int gr = (mr & 3) * H_ + u_base + (mr >> 2);
        for (int k = tid; k < 576; k += NTHR) {
            float v = (k < 64) ? eWih0[(size_t)gr * 64 + k] : eWhh0[(size_t)gr * H_ + (k - 64)];
            st_w(smem, E0W, 1152, mr, k, v);
        }
        for (int k = tid; k < 1024; k += NTHR) {
            float v = (k < 512) ? eWih1[(size_t)gr * H_ + k] : eWhh1[(size_t)gr * H_ + (k - 512)];
            st_w(smem, E1W, 2048, mr, k, v);
        }
    }
    gbar_arrive(flags, w, ++gen);
    gbar_wait(flags, gbase, gen, false);

    uint4 P[16], Q[16];

    // ================= ENCODER: pipelined, 257 phases (group-local sync) =================
    // phase p: cellA(t=p) || cellB(t=p-1). Both consume h0(p-1) (plane P shared).
    for (int p = 0; p <= T_; ++p) {
        gbar_arrive(flags, w, ++gen);
        f32x4 a = {0,0,0,0}, e = {0,0,0,0};
        if (p < T_) seg_x(smem, E0W, 1152, x, p, bt, R, lane, a);   // pre-wait: x read-only
        gbar_wait(flags, gbase, gen, p > 0 && (p & 15) == 0);
        load_plane(P, H0S(p - 1), loff);    // h0(p-1), written last phase
        if (p >= 1) load_plane(Q, H1S(p - 2), loff);   // h1(p-2), written last phase
        if (p < T_) cons_plane(P, smem, E0W, 1152, 64, R, qq, a);
        if (p >= 1) {
            cons_plane(P, smem, E1W, 2048, 0,   R, qq, e);
            cons_plane(Q, smem, E1W, 2048, 512, R, qq, e);
        }
        if (p < T_)  epilogue_reg(a, bzA, u, b, c0r, H0S(p), lane);
        if (p >= 1)  epilogue_reg(e, bzB, u, b, c1r, H1S(p - 1), lane);
    }

    // ================= TRANSITION: decoder weights -> LDS (WG-local) =================
    __syncthreads();
    for (int mr = 0; mr < 32; ++mr) {
        const int gr = (mr & 3) * H_ + u_base + (mr >> 2);
        const float* wr = dWih0 + (size_t)gr * 64;
        for (int c = tid; c < 512; c += NTHR) {
            float s = 0.f;
            #pragma unroll 8
            for (int f = 0; f < 64; ++f) s += wr[f] * linW[(size_t)f * H_ + c];  // Weff
            st_w(smem, D0W, 2048, mr, c, s);
            st_w(smem, D0W, 2048, mr, 512 + c, dWhh0[(size_t)gr * H_ + c]);
            st_w(smem, D1W, 2048, mr, c,       dWih1[(size_t)gr * H_ + c]);
            st_w(smem, D1W, 2048, mr, 512 + c, dWhh1[(size_t)gr * H_ + c]);
        }
    }
    __syncthreads();

    // ================= DECODER: 512 phases, 1 fresh plane-load per phase =================
    // Register carry: P holds h1(t-1) (loaded in dec0), Q holds h0 (loaded in dec1).
    // Stale-register half is consumed PRE-wait (split-phase). Ring continues from enc.
    for (int t = 0; t < T_; ++t) {
        {   // ---- dec0(t): Weff.h1(t-1) (or x-proj at t=0) + dWhh0.h0(t-1) ----
            gbar_arrive(flags, w, ++gen);
            f32x4 a = {0,0,0,0};
            if (t > 0) {
                cons_plane(Q, smem, D0W, 2048, 512, R, qq, a);   // pre-wait: h0(t-1) in regs
            } else {
                const float* xr = x + ((size_t)b * T_ + (T_ - 1)) * 64;
                #pragma unroll
                for (int gg = 0; gg < 4; ++gg) {
                    const float* wr = dWih0 + (size_t)(gg * H_ + u) * 64;
                    float s = 0.f;
                    for (int f = 0; f < 64; ++f) s += wr[f] * xr[f];
                    a[gg] = s;
                }
            }
            gbar_wait(flags, gbase, gen, t > 0 && (t & 15) == 0);
            if (t > 0) {
                load_plane(P, H1S(t - 1), loff);                 // fresh h1(t-1)
                cons_plane(P, smem, D0W, 2048, 0, R, qq, a);
            } else {
                load_plane(Q, H0S(-1), loff);                    // h0(-1) = enc h0(255)
                cons_plane(Q, smem, D0W, 2048, 512, R, qq, a);
            }
            epilogue_reg(a, (t > 0) ? bzD0b : bzD0, u, b, c0r, H0S(t), lane);
            if (t > 0) linear_out(H1S(t - 1), linW, linb, out, g, wl, tid, t - 1);
        }
        {   // ---- dec1(t): dWih1.h0(t) + dWhh1.h1(t-1) ----
            gbar_arrive(flags, w, ++gen);
            f32x4 e = {0,0,0,0};
            if (t > 0)
                cons_plane(P, smem, D1W, 2048, 512, R, qq, e);   // pre-wait: h1(t-1) in regs
            gbar_wait(flags, gbase, gen, false);
            load_plane(Q, H0S(t), loff);                         // fresh h0(t)
            if (t == 0) {
                load_plane(P, H1S(-1), loff);                    // h1(-1) = enc h1(255)
                cons_plane(P, smem, D1W, 2048, 512, R, qq, e);
            }
            cons_plane(Q, smem, D1W, 2048, 0, R, qq, e);
            epilogue_reg(e, bzD1, u, b, c1r, H1S(t), lane);
        }
    }
    // final output (t=255): dec h1(255) -> slot 15 (this WG's own stores drained by wave)
    asm volatile("s_waitcnt vmcnt(0)" ::: "memory");
    __syncthreads();
    linear_out(H1S(255), linW, linb, out, g, wl, tid, 255);
}

extern "C" void kernel_launch(void* const* d_in, const int* in_sizes, int n_in,
                              void* d_out, int out_size, void* d_ws, size_t ws_size,
                              hipStream_t stream) {
    (void)in_sizes; (void)n_in; (void)out_size; (void)ws_size;
    const float* x     = (const float*)d_in[0];
    const float* eWih0 = (const float*)d_in[1];
    const float* eWhh0 = (const float*)d_in[2];
    const float* ebih0 = (const float*)d_in[3];
    const float* ebhh0 = (const float*)d_in[4];
    const float* eWih1 = (const float*)d_in[5];
    const float* eWhh1 = (const float*)d_in[6];
    const float* ebih1 = (const float*)d_in[7];
    const float* ebhh1 = (const float*)d_in[8];
    const float* dWih0 = (const float*)d_in[9];
    const float* dWhh0 = (const float*)d_in[10];
    const float* dbih0 = (const float*)d_in[11];
    const float* dbhh0 = (const float*)d_in[12];
    const float* dWih1 = (const float*)d_in[13];
    const float* dWhh1 = (const float*)d_in[14];
    const float* dbih1 = (const float*)d_in[15];
    const float* dbhh1 = (const float*)d_in[16];
    const float* linW  = (const float*)d_in[17];
    const float* linb  = (const float*)d_in[18];

    char* wsb  = (char*)d_ws;
    int* flags = (int*)(wsb + O_BAR);

    static const int lds_bytes = 131072;
    hipFuncSetAttribute((const void*)lstm_persist,
                        hipFuncAttributeMaxDynamicSharedMemorySize, lds_bytes);

    hipMemsetAsync(flags, 0, NWG * 64, stream);

    hipLaunchKernelGGL(lstm_persist, dim3(NWG), dim3(NTHR), lds_bytes, stream,
                       x, eWih0, eWhh0, ebih0, ebhh0, eWih1, eWhh1, ebih1, ebhh1,
                       dWih0, dWhh0, dbih0, dbhh0, dWih1, dWhh1, dbih1, dbhh1,
                       linW, linb, (float*)d_out, wsb, flags);
}